// Round 10
// baseline (1848.639 us; speedup 1.0000x reference)
//
#include <hip/hip_runtime.h>
#include <math.h>

// Problem constants: B=16384 samples, DIM=64, WIDTH=256, DD=64, C2=16
#define SB 16      // samples per workgroup

// ws layout (float offsets)
#define OFF_W0T  0            // 5 x (64x256)
#define OFF_W1T  81920        // 5 x (256x256)
#define OFF_W2PT 409600       // 256x2016
#define OFF_W2CT 925696       // 256x1024
#define OFF_W2BT 1187840      // 256x4096
#define OFF_DE   2236416      // 16384x64
#define OFF_DS   3284992      // 16384x64
#define WS_FLOATS 4337600     // ~17.35 MB (base)
#define SCR_PER_BLOCK 8192    // 32 KB H2c+H2b scratch per block (v2 path)

__device__ __forceinline__ float4 f4fma(float a, float4 w, float4 c) {
    c.x = fmaf(a, w.x, c.x); c.y = fmaf(a, w.y, c.y);
    c.z = fmaf(a, w.z, c.z); c.w = fmaf(a, w.w, c.w);
    return c;
}

__device__ __forceinline__ float dot4f(float4 a, float4 b) {
    return fmaf(a.w, b.w, fmaf(a.z, b.z, fmaf(a.y, b.y, a.x * b.x)));
}

__device__ __forceinline__ float4 tanh4b(float4 a, float b) {
    return make_float4(tanhf(a.x + b), tanhf(a.y + b), tanhf(a.z + b), tanhf(a.w + b));
}

// out[c*R + r] = in[r*C + c]   (in: R rows x C cols, row-major)
__global__ void k_transpose(const float* __restrict__ in, float* __restrict__ out, int R, int C) {
    int tid = blockIdx.x * blockDim.x + threadIdx.x;
    if (tid >= R * C) return;
    int c = tid / R, r = tid - c * R;
    out[tid] = in[r * C + c];
}

// ---------------- K1: dE, dS ----------------
__global__ __launch_bounds__(1024, 2) void k1_grads(
    const float* __restrict__ y, const float* __restrict__ ws,
    const float* __restrict__ W0E, const float* __restrict__ b0E,
    const float* __restrict__ W1E, const float* __restrict__ b1E,
    const float* __restrict__ w2E,
    const float* __restrict__ W0S, const float* __restrict__ b0S,
    const float* __restrict__ W1S, const float* __restrict__ b1S,
    const float* __restrict__ w2S,
    float* __restrict__ odE, float* __restrict__ odS)
{
    __shared__ float syT[1024];       // [64][16]
    __shared__ float sH1T[4096];      // [256][16]
    __shared__ float sGT[4096];       // [256][16]  (G2)
    __shared__ float sG1T[4096];      // [256][16]  (G1)

    const int tid = threadIdx.x;
    const int sbase = blockIdx.x * SB;
    {
        int s = tid >> 6, i = tid & 63;
        syT[i * 16 + s] = y[sbase * 64 + tid];
    }
    __syncthreads();

    const int c = tid & 255, sg = tid >> 8, s4 = sg * 4;

    for (int m = 0; m < 2; ++m) {
        const float* w0t = ws + OFF_W0T + m * 16384;
        const float* w1t = ws + OFF_W1T + m * 65536;
        const float* W0 = m ? W0S : W0E;     // natural (256,64)
        const float* W1 = m ? W1S : W1E;     // natural (256,256)
        const float* b0 = m ? b0S : b0E;
        const float* b1 = m ? b1S : b1E;
        const float* w2 = m ? w2S : w2E;
        float* outg = m ? odS : odE;

        // L0: H1 = tanh(y @ W0^T + b0)
        {
            float4 acc = {0, 0, 0, 0};
            #pragma unroll 4
            for (int k = 0; k < 64; ++k)
                acc = f4fma(w0t[k * 256 + c], *(const float4*)(syT + k * 16 + s4), acc);
            *(float4*)(sH1T + c * 16 + s4) = tanh4b(acc, b0[c]);
        }
        __syncthreads();
        // L1: H2; fused G2 = (1-H2^2)*w2
        {
            float4 acc = {0, 0, 0, 0};
            #pragma unroll 4
            for (int k = 0; k < 256; ++k)
                acc = f4fma(w1t[k * 256 + c], *(const float4*)(sH1T + k * 16 + s4), acc);
            float b = b1[c], wv = w2[c];
            float4 h2 = make_float4(tanhf(acc.x + b), tanhf(acc.y + b),
                                    tanhf(acc.z + b), tanhf(acc.w + b));
            *(float4*)(sGT + c * 16 + s4) = make_float4(
                (1.f - h2.x * h2.x) * wv, (1.f - h2.y * h2.y) * wv,
                (1.f - h2.z * h2.z) * wv, (1.f - h2.w * h2.w) * wv);
        }
        __syncthreads();
        // U = G2 @ W1; fused G1 = (1-H1^2)*U
        {
            float4 acc = {0, 0, 0, 0};
            #pragma unroll 4
            for (int j = 0; j < 256; ++j)
                acc = f4fma(W1[j * 256 + c], *(const float4*)(sGT + j * 16 + s4), acc);
            float4 h1 = *(const float4*)(sH1T + c * 16 + s4);
            *(float4*)(sG1T + c * 16 + s4) = make_float4(
                (1.f - h1.x * h1.x) * acc.x, (1.f - h1.y * h1.y) * acc.y,
                (1.f - h1.z * h1.z) * acc.z, (1.f - h1.w * h1.w) * acc.w);
        }
        __syncthreads();
        // dy[i] = sum_k G1[k] * W0[k][i]
        {
            int s = tid >> 6, i = tid & 63;
            float acc = 0.f;
            #pragma unroll 8
            for (int k = 0; k < 256; ++k)
                acc = fmaf(sG1T[k * 16 + s], W0[k * 64 + i], acc);
            outg[sbase * 64 + tid] = acc;
        }
        __syncthreads();
    }
}

// ---------------- K2: pA head + poisson ----------------
__global__ __launch_bounds__(1024, 4) void k2_poisson(
    const float* __restrict__ y, const float* __restrict__ ws,
    const float* __restrict__ b0P, const float* __restrict__ b1P,
    float* __restrict__ dout)
{
    extern __shared__ float smem[];
    float* sa   = smem;            // 16 x 2024. Aliased: H1T @ [0,4096), yT @ [4096,5120)
    float* sH2T = smem + 32384;    // [256][16]
    float* sdE  = sH2T + 4096;     // [s][i]
    float* sdS  = sdE + 1024;

    float* sH1T = sa;
    float* syT  = sa + 4096;

    const int tid = threadIdx.x;
    const int sbase = blockIdx.x * SB;
    const float* gdE = ws + OFF_DE;
    const float* gdS = ws + OFF_DS;

    {
        int s = tid >> 6, i = tid & 63;
        syT[i * 16 + s] = y[sbase * 64 + tid];
        sdE[tid] = gdE[sbase * 64 + tid];
        sdS[tid] = gdS[sbase * 64 + tid];
    }
    __syncthreads();

    const int c  = tid & 255;
    const int sg = tid >> 8;
    const int s4 = sg * 4;

    // P1
    {
        const float* w0t = ws + OFF_W0T + 2 * 16384;
        float4 acc = {0, 0, 0, 0};
        #pragma unroll 4
        for (int k = 0; k < 64; ++k) {
            float w = w0t[k * 256 + c];
            float4 yv = *(const float4*)(syT + k * 16 + s4);
            acc = f4fma(w, yv, acc);
        }
        *(float4*)(sH1T + c * 16 + s4) = tanh4b(acc, b0P[c]);
    }
    __syncthreads();

    // P2
    {
        const float* w1t = ws + OFF_W1T + 2 * 65536;
        float4 acc = {0, 0, 0, 0};
        #pragma unroll 4
        for (int k = 0; k < 256; ++k) {
            float w = w1t[k * 256 + c];
            float4 hv = *(const float4*)(sH1T + k * 16 + s4);
            acc = f4fma(w, hv, acc);
        }
        *(float4*)(sH2T + c * 16 + s4) = tanh4b(acc, b1P[c]);
    }
    __syncthreads();

    // P3: a-GEMM, 4 cols x 8 samples
    {
        const int sg2 = tid >> 9;
        const int s8  = sg2 * 8;
        const int cq  = tid & 511;
        if (cq < 504) {
            const float* wp = ws + OFF_W2PT + 4 * cq;
            float4 acc[8];
            #pragma unroll
            for (int s = 0; s < 8; ++s) acc[s] = make_float4(0.f, 0.f, 0.f, 0.f);
            #pragma unroll 2
            for (int k = 0; k < 256; ++k) {
                float4 hA = *(const float4*)(sH2T + k * 16 + s8);
                float4 hB = *(const float4*)(sH2T + k * 16 + s8 + 4);
                float4 w = *(const float4*)(wp + k * 2016);
                acc[0] = f4fma(hA.x, w, acc[0]);
                acc[1] = f4fma(hA.y, w, acc[1]);
                acc[2] = f4fma(hA.z, w, acc[2]);
                acc[3] = f4fma(hA.w, w, acc[3]);
                acc[4] = f4fma(hB.x, w, acc[4]);
                acc[5] = f4fma(hB.y, w, acc[5]);
                acc[6] = f4fma(hB.z, w, acc[6]);
                acc[7] = f4fma(hB.w, w, acc[7]);
            }
            #pragma unroll
            for (int s = 0; s < 8; ++s)
                *(float4*)(sa + (s8 + s) * 2024 + 4 * cq) = acc[s];
        }
    }
    __syncthreads();

    // P4: gather
    {
        const int s = tid >> 6;
        const int i = tid & 63;
        const int ib = i * (i - 1) / 2;
        const float* ap = sa + s * 2024;
        const float* dep = sdE + s * 64;
        const float* dsp = sdS + s * 64;

        float adE = 0.f, adS = 0.f;
        int trij = 0;
        #pragma unroll 4
        for (int j = 0; j < 64; ++j) {
            int t = (j < i) ? (ib + j) : (trij + i);
            float sel = (j < i) ? 1.f : ((j == i) ? 0.f : -1.f);
            float cc = sel * ap[t];
            adE = fmaf(cc, dep[j], adE);
            adS = fmaf(cc, dsp[j], adS);
            trij += j;
        }

        float de = dep[i], dsv = dsp[i];
        float p0 = de * adS;
        float p1 = de * dsv;
        float p2 = dsv * dsv;
        #pragma unroll
        for (int m = 1; m <= 32; m <<= 1) {
            p0 += __shfl_xor(p0, m);
            p1 += __shfl_xor(p1, m);
            p2 += __shfl_xor(p2, m);
        }
        float inv = 1.f / p2;
        dout[sbase * 64 + tid] = adE + (p0 * dsv - p1 * adS) * inv;
    }
}

// ---------------- K3 v1: proven R9 version (fallback when ws is small) ----------------
__global__ __launch_bounds__(1024, 4) void k3_friction_v1(
    const float* __restrict__ y, const float* __restrict__ ws,
    const float* __restrict__ b0C, const float* __restrict__ b1C,
    const float* __restrict__ b0B, const float* __restrict__ b1B,
    float* __restrict__ dout)
{
    extern __shared__ float smem[];
    float* sYT  = smem;
    float* sBTc = smem + 1024;
    float* sBTb = smem + 5120;
    float* sATc = smem + 9216;
    float* sATb = smem + 13312;
    float* sC   = smem + 9216;
    float* sdE  = smem + 26640;
    float* sdS  = sdE + 1024;
    float* sBdE = sdS + 1024;
    float* sBdS = sBdE + 1024;
    float* sv   = sBdS + 1024;
    float* sq   = sv + 1024;
    float* sScal = sq + 1024;
    float* sr   = sScal + 64;

    const int tid = threadIdx.x;
    const int sbase = blockIdx.x * SB;
    const float* gdE = ws + OFF_DE;
    const float* gdS = ws + OFF_DS;

    {
        int s = tid >> 6, i = tid & 63;
        sYT[i * 16 + s] = y[sbase * 64 + tid];
        sdE[tid] = gdE[sbase * 64 + tid];
        sdS[tid] = gdS[sbase * 64 + tid];
    }
    if (tid < 64) sScal[tid] = 0.f;
    __syncthreads();

    {
        int s = tid >> 6;
        float de = sdE[tid];
        unsafeAtomicAdd(&sScal[s * 4 + 0], de * de);
        unsafeAtomicAdd(&sScal[s * 4 + 1], de * sdS[tid]);
    }

    const int net = tid >> 9;
    const int t9  = tid & 511;
    const int sgf = t9 >> 7;
    const int s4f = sgf * 4;
    const int cp  = t9 & 127;
    const int c0 = 2 * cp, c1 = c0 + 1;
    const float* w0t = ws + OFF_W0T + (3 + net) * 16384;
    const float* w1t = ws + OFF_W1T + (3 + net) * 65536;
    const float* b0v = net ? b0B : b0C;
    const float* b1v = net ? b1B : b1C;
    float* sH1 = net ? sATb : sATc;
    float* sH2 = net ? sBTb : sBTc;

    {
        float4 a0 = {0, 0, 0, 0}, a1 = {0, 0, 0, 0};
        #pragma unroll 4
        for (int k = 0; k < 64; ++k) {
            float4 h = *(const float4*)(sYT + k * 16 + s4f);
            float2 w = *(const float2*)(w0t + k * 256 + c0);
            a0 = f4fma(w.x, h, a0);
            a1 = f4fma(w.y, h, a1);
        }
        *(float4*)(sH1 + c0 * 16 + s4f) = tanh4b(a0, b0v[c0]);
        *(float4*)(sH1 + c1 * 16 + s4f) = tanh4b(a1, b0v[c1]);
    }
    __syncthreads();

    {
        float4 a0 = {0, 0, 0, 0}, a1 = {0, 0, 0, 0};
        #pragma unroll 4
        for (int k = 0; k < 256; ++k) {
            float4 h = *(const float4*)(sH1 + k * 16 + s4f);
            float2 w = *(const float2*)(w1t + k * 256 + c0);
            a0 = f4fma(w.x, h, a0);
            a1 = f4fma(w.y, h, a1);
        }
        *(float4*)(sH2 + c0 * 16 + s4f) = tanh4b(a0, b1v[c0]);
        *(float4*)(sH2 + c1 * 16 + s4f) = tanh4b(a1, b1v[c1]);
    }
    __syncthreads();

    {
        const int sgc = tid >> 8;
        const int s4c = sgc * 4;
        const int cq  = tid & 255;
        const float* w2ct = ws + OFF_W2CT + 4 * cq;
        float4 a0 = {0,0,0,0}, a1 = {0,0,0,0}, a2 = {0,0,0,0}, a3 = {0,0,0,0};
        float4 h = *(const float4*)(sBTc + s4c);
        float4 w = *(const float4*)(w2ct);
        #pragma unroll 2
        for (int k = 0; k < 256; ++k) {
            float4 hn = *(const float4*)(sBTc + (k + 1) * 16 + s4c);
            float4 wn = *(const float4*)(w2ct + (k + 1) * 1024);
            a0 = f4fma(h.x, w, a0);
            a1 = f4fma(h.y, w, a1);
            a2 = f4fma(h.z, w, a2);
            a3 = f4fma(h.w, w, a3);
            h = hn; w = wn;
        }
        const int kC = cq >> 2;
        const int mB = 4 * (cq & 3);
        float* p0 = sC + (s4c + 0) * 1089 + kC * 17 + mB;
        float* p1 = sC + (s4c + 1) * 1089 + kC * 17 + mB;
        float* p2 = sC + (s4c + 2) * 1089 + kC * 17 + mB;
        float* p3 = sC + (s4c + 3) * 1089 + kC * 17 + mB;
        p0[0] = a0.x; p0[1] = a0.y; p0[2] = a0.z; p0[3] = a0.w;
        p1[0] = a1.x; p1[1] = a1.y; p1[2] = a1.z; p1[3] = a1.w;
        p2[0] = a2.x; p2[1] = a2.y; p2[2] = a2.z; p2[3] = a2.w;
        p3[0] = a3.x; p3[1] = a3.y; p3[2] = a3.z; p3[3] = a3.w;
    }
    __syncthreads();

    const int kp = tid >> 4;
    const int i0 = 4 * (tid & 15);
    float4 bm[16];
    #pragma unroll
    for (int s = 0; s < 16; ++s) bm[s] = make_float4(0.f, 0.f, 0.f, 0.f);
    {
        const float* wb = ws + OFF_W2BT + 4 * tid;
        float4 w = *(const float4*)(wb);
        float4 h0 = *(const float4*)(sBTb);
        float4 h1 = *(const float4*)(sBTb + 4);
        float4 h2 = *(const float4*)(sBTb + 8);
        float4 h3 = *(const float4*)(sBTb + 12);
        #pragma unroll 2
        for (int k = 0; k < 256; ++k) {
            float4 wn = *(const float4*)(wb + (k + 1) * 4096);
            float4 g0 = *(const float4*)(sBTb + (k + 1) * 16);
            float4 g1 = *(const float4*)(sBTb + (k + 1) * 16 + 4);
            float4 g2 = *(const float4*)(sBTb + (k + 1) * 16 + 8);
            float4 g3 = *(const float4*)(sBTb + (k + 1) * 16 + 12);
            float hs[16] = {h0.x, h0.y, h0.z, h0.w, h1.x, h1.y, h1.z, h1.w,
                            h2.x, h2.y, h2.z, h2.w, h3.x, h3.y, h3.z, h3.w};
            #pragma unroll
            for (int s = 0; s < 16; ++s) bm[s] = f4fma(hs[s], w, bm[s]);
            w = wn; h0 = g0; h1 = g1; h2 = g2; h3 = g3;
        }
    }
    #pragma unroll
    for (int s = 0; s < 16; ++s) {
        float4 de = *(const float4*)(sdE + s * 64 + i0);
        float4 dsv = *(const float4*)(sdS + s * 64 + i0);
        float pd = dot4f(bm[s], de);
        float ps = dot4f(bm[s], dsv);
        pd += __shfl_xor(pd, 1); ps += __shfl_xor(ps, 1);
        pd += __shfl_xor(pd, 2); ps += __shfl_xor(ps, 2);
        pd += __shfl_xor(pd, 4); ps += __shfl_xor(ps, 4);
        pd += __shfl_xor(pd, 8); ps += __shfl_xor(ps, 8);
        if ((tid & 15) == 0) {
            sBdE[s * 64 + kp] = pd;
            sBdS[s * 64 + kp] = ps;
        }
    }
    __syncthreads();

    {
        int s = tid >> 6;
        float beta = sScal[s * 4 + 1] / sScal[s * 4 + 0];
        sv[tid] = sBdS[tid] - beta * sBdE[tid];
    }
    __syncthreads();
    {
        int s = tid >> 6;
        unsafeAtomicAdd(&sScal[s * 4 + 2], sdE[tid] * sv[tid]);
    }
    __syncthreads();

    #pragma unroll
    for (int s = 0; s < 16; ++s) {
        float4 vv = *(const float4*)(sv + s * 64 + i0);
        float pq = dot4f(bm[s], vv);
        pq += __shfl_xor(pq, 1);
        pq += __shfl_xor(pq, 2);
        pq += __shfl_xor(pq, 4);
        pq += __shfl_xor(pq, 8);
        if ((tid & 15) == 0) sq[s * 64 + kp] = pq;
    }
    __syncthreads();

    if (tid < 256) {
        int s = tid >> 4, m = tid & 15;
        float gamma = sScal[s * 4 + 2] / sScal[s * 4 + 0];
        float r = 0.f;
        #pragma unroll 4
        for (int k = 0; k < 64; ++k) {
            float wv = sq[s * 64 + k] - gamma * sBdE[s * 64 + k];
            r = fmaf(sC[s * 1089 + k * 17 + m], wv, r);
        }
        sr[s * 16 + m] = r;
    }
    __syncthreads();
    {
        int s = tid >> 6, k = tid & 63;
        float o = 0.f;
        #pragma unroll
        for (int m2 = 0; m2 < 16; ++m2)
            o = fmaf(sC[s * 1089 + k * 17 + m2], sr[s * 16 + m2], o);
        int gi = sbase * 64 + tid;
        dout[gi] = dout[gi] + o;
    }
}

// ---------------- K3 v2: scalar-path h broadcast (needs 32 MB extra ws) ----------------
// H2c/H2b spilled to per-block global scratch at end of L1; C-head and Bm read h
// via UNIFORM-ADDRESS loads (no threadIdx in address -> compiler scalarizes to
// s_load; h rides the SMEM/constant path, freeing the LDS pipe entirely in the
// two dominant GEMM loops). C-head remapped to 1 col x 16 samples (W2CT read 1x).
__global__ __launch_bounds__(1024, 4) void k3_friction_v2(
    const float* __restrict__ y, const float* __restrict__ ws,
    const float* __restrict__ b0C, const float* __restrict__ b1C,
    const float* __restrict__ b0B, const float* __restrict__ b1B,
    float* __restrict__ dout, float* __restrict__ gscr)
{
    extern __shared__ float smem[];
    float* sYT  = smem;               // [64][16]
    float* sATc = smem + 9216;        // [256][16] fC H1 (dead after L1)
    float* sATb = smem + 13312;       // [256][16] fB H1 (dead after L1)
    float* sC   = smem + 9216;        // [16][1089] overlaps H1 tiles
    float* sdE  = smem + 26640;
    float* sdS  = sdE + 1024;
    float* sBdE = sdS + 1024;
    float* sBdS = sBdE + 1024;
    float* sv   = sBdS + 1024;
    float* sq   = sv + 1024;
    float* sScal = sq + 1024;
    float* sr   = sScal + 64;

    const int tid = threadIdx.x;
    const int sbase = blockIdx.x * SB;
    const float* gdE = ws + OFF_DE;
    const float* gdS = ws + OFF_DS;
    float* gH2 = gscr + (size_t)blockIdx.x * SCR_PER_BLOCK;  // [net][c][s], 2x4096

    {
        int s = tid >> 6, i = tid & 63;
        sYT[i * 16 + s] = y[sbase * 64 + tid];
        sdE[tid] = gdE[sbase * 64 + tid];
        sdS[tid] = gdS[sbase * 64 + tid];
    }
    if (tid < 64) sScal[tid] = 0.f;
    __syncthreads();

    {
        int s = tid >> 6;
        float de = sdE[tid];
        unsafeAtomicAdd(&sScal[s * 4 + 0], de * de);
        unsafeAtomicAdd(&sScal[s * 4 + 1], de * sdS[tid]);
    }

    const int net = tid >> 9;
    const int t9  = tid & 511;
    const int sgf = t9 >> 7;
    const int s4f = sgf * 4;
    const int cp  = t9 & 127;
    const int c0 = 2 * cp, c1 = c0 + 1;
    const float* w0t = ws + OFF_W0T + (3 + net) * 16384;
    const float* w1t = ws + OFF_W1T + (3 + net) * 65536;
    const float* b0v = net ? b0B : b0C;
    const float* b1v = net ? b1B : b1C;
    float* sH1 = net ? sATb : sATc;

    // L0 (both nets)
    {
        float4 a0 = {0, 0, 0, 0}, a1 = {0, 0, 0, 0};
        #pragma unroll 4
        for (int k = 0; k < 64; ++k) {
            float4 h = *(const float4*)(sYT + k * 16 + s4f);
            float2 w = *(const float2*)(w0t + k * 256 + c0);
            a0 = f4fma(w.x, h, a0);
            a1 = f4fma(w.y, h, a1);
        }
        *(float4*)(sH1 + c0 * 16 + s4f) = tanh4b(a0, b0v[c0]);
        *(float4*)(sH1 + c1 * 16 + s4f) = tanh4b(a1, b0v[c1]);
    }
    __syncthreads();

    // L1 (both nets): H2 -> GLOBAL scratch only
    {
        float4 a0 = {0, 0, 0, 0}, a1 = {0, 0, 0, 0};
        #pragma unroll 4
        for (int k = 0; k < 256; ++k) {
            float4 h = *(const float4*)(sH1 + k * 16 + s4f);
            float2 w = *(const float2*)(w1t + k * 256 + c0);
            a0 = f4fma(w.x, h, a0);
            a1 = f4fma(w.y, h, a1);
        }
        float* gdst = gH2 + net * 4096;
        *(float4*)(gdst + c0 * 16 + s4f) = tanh4b(a0, b1v[c0]);
        *(float4*)(gdst + c1 * 16 + s4f) = tanh4b(a1, b1v[c1]);
    }
    __syncthreads();   // H1 tiles dead; sC writable; gH2 visible (vmcnt drained at barrier)

    // C head: thread = column n=tid (W2CT read once); h via uniform loads from gH2c
    {
        const float* w2ct = ws + OFF_W2CT;       // [k][1024]
        const float* gh = gH2;                   // fC H2, uniform base
        float acc[16];
        #pragma unroll
        for (int s = 0; s < 16; ++s) acc[s] = 0.f;
        #pragma unroll 2
        for (int k = 0; k < 256; ++k) {
            float w = w2ct[k * 1024 + tid];
            float4 h0 = *(const float4*)(gh + k * 16);
            float4 h1 = *(const float4*)(gh + k * 16 + 4);
            float4 h2 = *(const float4*)(gh + k * 16 + 8);
            float4 h3 = *(const float4*)(gh + k * 16 + 12);
            float hs[16] = {h0.x, h0.y, h0.z, h0.w, h1.x, h1.y, h1.z, h1.w,
                            h2.x, h2.y, h2.z, h2.w, h3.x, h3.y, h3.z, h3.w};
            #pragma unroll
            for (int s = 0; s < 16; ++s) acc[s] = fmaf(hs[s], w, acc[s]);
        }
        const int kC = tid >> 4, mC = tid & 15;
        #pragma unroll
        for (int s = 0; s < 16; ++s) sC[s * 1089 + kC * 17 + mC] = acc[s];
    }
    __syncthreads();

    // Bm pass1: w per-lane coalesced, h via uniform loads from gH2b; bm held for pass2
    const int kp = tid >> 4;
    const int i0 = 4 * (tid & 15);
    float4 bm[16];
    #pragma unroll
    for (int s = 0; s < 16; ++s) bm[s] = make_float4(0.f, 0.f, 0.f, 0.f);
    {
        const float* wb = ws + OFF_W2BT + 4 * tid;
        const float* gh = gH2 + 4096;            // fB H2, uniform base
        #pragma unroll 2
        for (int k = 0; k < 256; ++k) {
            float4 w = *(const float4*)(wb + k * 4096);
            float4 h0 = *(const float4*)(gh + k * 16);
            float4 h1 = *(const float4*)(gh + k * 16 + 4);
            float4 h2 = *(const float4*)(gh + k * 16 + 8);
            float4 h3 = *(const float4*)(gh + k * 16 + 12);
            float hs[16] = {h0.x, h0.y, h0.z, h0.w, h1.x, h1.y, h1.z, h1.w,
                            h2.x, h2.y, h2.z, h2.w, h3.x, h3.y, h3.z, h3.w};
            #pragma unroll
            for (int s = 0; s < 16; ++s) bm[s] = f4fma(hs[s], w, bm[s]);
        }
    }
    #pragma unroll
    for (int s = 0; s < 16; ++s) {
        float4 de = *(const float4*)(sdE + s * 64 + i0);
        float4 dsv = *(const float4*)(sdS + s * 64 + i0);
        float pd = dot4f(bm[s], de);
        float ps = dot4f(bm[s], dsv);
        pd += __shfl_xor(pd, 1); ps += __shfl_xor(ps, 1);
        pd += __shfl_xor(pd, 2); ps += __shfl_xor(ps, 2);
        pd += __shfl_xor(pd, 4); ps += __shfl_xor(ps, 4);
        pd += __shfl_xor(pd, 8); ps += __shfl_xor(ps, 8);
        if ((tid & 15) == 0) {
            sBdE[s * 64 + kp] = pd;
            sBdS[s * 64 + kp] = ps;
        }
    }
    __syncthreads();

    {
        int s = tid >> 6;
        float beta = sScal[s * 4 + 1] / sScal[s * 4 + 0];
        sv[tid] = sBdS[tid] - beta * sBdE[tid];
    }
    __syncthreads();
    {
        int s = tid >> 6;
        unsafeAtomicAdd(&sScal[s * 4 + 2], sdE[tid] * sv[tid]);
    }
    __syncthreads();

    #pragma unroll
    for (int s = 0; s < 16; ++s) {
        float4 vv = *(const float4*)(sv + s * 64 + i0);
        float pq = dot4f(bm[s], vv);
        pq += __shfl_xor(pq, 1);
        pq += __shfl_xor(pq, 2);
        pq += __shfl_xor(pq, 4);
        pq += __shfl_xor(pq, 8);
        if ((tid & 15) == 0) sq[s * 64 + kp] = pq;
    }
    __syncthreads();

    if (tid < 256) {
        int s = tid >> 4, m = tid & 15;
        float gamma = sScal[s * 4 + 2] / sScal[s * 4 + 0];
        float r = 0.f;
        #pragma unroll 4
        for (int k = 0; k < 64; ++k) {
            float wv = sq[s * 64 + k] - gamma * sBdE[s * 64 + k];
            r = fmaf(sC[s * 1089 + k * 17 + m], wv, r);
        }
        sr[s * 16 + m] = r;
    }
    __syncthreads();
    {
        int s = tid >> 6, k = tid & 63;
        float o = 0.f;
        #pragma unroll
        for (int m2 = 0; m2 < 16; ++m2)
            o = fmaf(sC[s * 1089 + k * 17 + m2], sr[s * 16 + m2], o);
        int gi = sbase * 64 + tid;
        dout[gi] = dout[gi] + o;
    }
}

extern "C" void kernel_launch(void* const* d_in, const int* in_sizes, int n_in,
                              void* d_out, int out_size, void* d_ws, size_t ws_size,
                              hipStream_t stream)
{
    (void)in_sizes; (void)n_in; (void)out_size;
    const float* y = (const float*)d_in[1];
    const float* W0[5]; const float* b0[5]; const float* W1[5]; const float* b1[5]; const float* W2[5];
    for (int m = 0; m < 5; ++m) {
        int base = 2 + m * 5;
        W0[m] = (const float*)d_in[base + 0];
        b0[m] = (const float*)d_in[base + 1];
        W1[m] = (const float*)d_in[base + 2];
        b1[m] = (const float*)d_in[base + 3];
        W2[m] = (const float*)d_in[base + 4];
    }
    float* ws = (float*)d_ws;
    float* dout = (float*)d_out;
    if (ws_size < (size_t)WS_FLOATS * sizeof(float)) return;
    const bool big_ws =
        ws_size >= ((size_t)WS_FLOATS + (size_t)1024 * SCR_PER_BLOCK) * sizeof(float);

    for (int m = 0; m < 5; ++m) {
        hipLaunchKernelGGL(k_transpose, dim3((256 * 64 + 255) / 256), dim3(256), 0, stream,
                           W0[m], ws + OFF_W0T + m * 16384, 256, 64);
        hipLaunchKernelGGL(k_transpose, dim3((256 * 256 + 255) / 256), dim3(256), 0, stream,
                           W1[m], ws + OFF_W1T + m * 65536, 256, 256);
    }
    hipLaunchKernelGGL(k_transpose, dim3((2016 * 256 + 255) / 256), dim3(256), 0, stream,
                       W2[2], ws + OFF_W2PT, 2016, 256);
    hipLaunchKernelGGL(k_transpose, dim3((1024 * 256 + 255) / 256), dim3(256), 0, stream,
                       W2[3], ws + OFF_W2CT, 1024, 256);
    hipLaunchKernelGGL(k_transpose, dim3((4096 * 256 + 255) / 256), dim3(256), 0, stream,
                       W2[4], ws + OFF_W2BT, 4096, 256);

    hipLaunchKernelGGL(k1_grads, dim3(1024), dim3(1024), 0, stream,
                       y, ws,
                       W0[0], b0[0], W1[0], b1[0], W2[0],
                       W0[1], b0[1], W1[1], b1[1], W2[1],
                       ws + OFF_DE, ws + OFF_DS);

    const int k2_smem = 154112;
    hipFuncSetAttribute((const void*)k2_poisson, hipFuncAttributeMaxDynamicSharedMemorySize, k2_smem);
    hipLaunchKernelGGL(k2_poisson, dim3(1024), dim3(1024), k2_smem, stream,
                       y, ws, b0[2], b1[2], dout);

    const int k3_smem = 132416;
    if (big_ws) {
        hipFuncSetAttribute((const void*)k3_friction_v2, hipFuncAttributeMaxDynamicSharedMemorySize, k3_smem);
        hipLaunchKernelGGL(k3_friction_v2, dim3(1024), dim3(1024), k3_smem, stream,
                           y, ws, b0[3], b1[3], b0[4], b1[4], dout, ws + WS_FLOATS);
    } else {
        hipFuncSetAttribute((const void*)k3_friction_v1, hipFuncAttributeMaxDynamicSharedMemorySize, k3_smem);
        hipLaunchKernelGGL(k3_friction_v1, dim3(1024), dim3(1024), k3_smem, stream,
                           y, ws, b0[3], b1[3], b0[4], b1[4], dout);
    }
}

// Round 11
// 1349.884 us; speedup vs baseline: 1.3695x; 1.3695x over previous
//
#include <hip/hip_runtime.h>
#include <math.h>

// Problem constants: B=16384 samples, DIM=64, WIDTH=256, DD=64, C2=16
#define SB 16      // samples per workgroup

// ws layout (float offsets)
#define OFF_W0T  0            // 5 x (64x256)
#define OFF_W1T  81920        // 5 x (256x256)
#define OFF_W2PT 409600       // 256x2016
#define OFF_W2CT 925696       // 256x1024
#define OFF_W2BT 1187840      // 256x4096
#define OFF_DE   2236416      // 16384x64
#define OFF_DS   3284992      // 16384x64
#define WS_FLOATS 4337600     // ~17.35 MB

__device__ __forceinline__ float4 f4fma(float a, float4 w, float4 c) {
    c.x = fmaf(a, w.x, c.x); c.y = fmaf(a, w.y, c.y);
    c.z = fmaf(a, w.z, c.z); c.w = fmaf(a, w.w, c.w);
    return c;
}

__device__ __forceinline__ float dot4f(float4 a, float4 b) {
    return fmaf(a.w, b.w, fmaf(a.z, b.z, fmaf(a.y, b.y, a.x * b.x)));
}

__device__ __forceinline__ float4 tanh4b(float4 a, float b) {
    return make_float4(tanhf(a.x + b), tanhf(a.y + b), tanhf(a.z + b), tanhf(a.w + b));
}

// ---------------- merged transpose: all 13 weight matrices in one launch ----------------
// Segment map (flat output index t):
//  [0, 81920)          5 x W0 (in 256x64)   -> ws + OFF_W0T + m*16384
//  [81920, 409600)     5 x W1 (in 256x256)  -> ws + OFF_W1T + m*65536
//  [409600, 925696)    W2P   (in 2016x256)  -> ws + OFF_W2PT
//  [925696, 1187840)   W2C   (in 1024x256)  -> ws + OFF_W2CT
//  [1187840, 2236416)  W2B   (in 4096x256)  -> ws + OFF_W2BT
__global__ __launch_bounds__(1024) void k_transpose_all(
    float* __restrict__ ws,
    const float* __restrict__ W0a, const float* __restrict__ W0b, const float* __restrict__ W0c,
    const float* __restrict__ W0d, const float* __restrict__ W0e,
    const float* __restrict__ W1a, const float* __restrict__ W1b, const float* __restrict__ W1c,
    const float* __restrict__ W1d, const float* __restrict__ W1e,
    const float* __restrict__ W2p, const float* __restrict__ W2c, const float* __restrict__ W2b)
{
    int t = blockIdx.x * blockDim.x + threadIdx.x;
    if (t >= 2236416) return;
    const float* in;
    int o, R, C;
    float* out;
    if (t < 81920) {
        int m = t >> 14; o = t & 16383;
        const float* W0s[5] = {W0a, W0b, W0c, W0d, W0e};
        in = W0s[m]; out = ws + OFF_W0T + m * 16384; R = 256; C = 64;
    } else if (t < 409600) {
        int t2 = t - 81920;
        int m = t2 >> 16; o = t2 & 65535;
        const float* W1s[5] = {W1a, W1b, W1c, W1d, W1e};
        in = W1s[m]; out = ws + OFF_W1T + m * 65536; R = 256; C = 256;
    } else if (t < 925696) {
        o = t - 409600; in = W2p; out = ws + OFF_W2PT; R = 2016; C = 256;
    } else if (t < 1187840) {
        o = t - 925696; in = W2c; out = ws + OFF_W2CT; R = 1024; C = 256;
    } else {
        o = t - 1187840; in = W2b; out = ws + OFF_W2BT; R = 4096; C = 256;
    }
    int c = o / R, r = o - c * R;
    out[o] = in[r * C + c];
}

// ---------------- K1: dE, dS ----------------
__global__ __launch_bounds__(1024, 2) void k1_grads(
    const float* __restrict__ y, const float* __restrict__ ws,
    const float* __restrict__ W0E, const float* __restrict__ b0E,
    const float* __restrict__ W1E, const float* __restrict__ b1E,
    const float* __restrict__ w2E,
    const float* __restrict__ W0S, const float* __restrict__ b0S,
    const float* __restrict__ W1S, const float* __restrict__ b1S,
    const float* __restrict__ w2S,
    float* __restrict__ odE, float* __restrict__ odS)
{
    __shared__ float syT[1024];       // [64][16]
    __shared__ float sH1T[4096];      // [256][16]
    __shared__ float sGT[4096];       // [256][16]  (G2)
    __shared__ float sG1T[4096];      // [256][16]  (G1)

    const int tid = threadIdx.x;
    const int sbase = blockIdx.x * SB;
    {
        int s = tid >> 6, i = tid & 63;
        syT[i * 16 + s] = y[sbase * 64 + tid];
    }
    __syncthreads();

    const int c = tid & 255, sg = tid >> 8, s4 = sg * 4;

    for (int m = 0; m < 2; ++m) {
        const float* w0t = ws + OFF_W0T + m * 16384;
        const float* w1t = ws + OFF_W1T + m * 65536;
        const float* W0 = m ? W0S : W0E;     // natural (256,64)
        const float* W1 = m ? W1S : W1E;     // natural (256,256)
        const float* b0 = m ? b0S : b0E;
        const float* b1 = m ? b1S : b1E;
        const float* w2 = m ? w2S : w2E;
        float* outg = m ? odS : odE;

        // L0: H1 = tanh(y @ W0^T + b0)
        {
            float4 acc = {0, 0, 0, 0};
            #pragma unroll 4
            for (int k = 0; k < 64; ++k)
                acc = f4fma(w0t[k * 256 + c], *(const float4*)(syT + k * 16 + s4), acc);
            *(float4*)(sH1T + c * 16 + s4) = tanh4b(acc, b0[c]);
        }
        __syncthreads();
        // L1: H2; fused G2 = (1-H2^2)*w2
        {
            float4 acc = {0, 0, 0, 0};
            #pragma unroll 4
            for (int k = 0; k < 256; ++k)
                acc = f4fma(w1t[k * 256 + c], *(const float4*)(sH1T + k * 16 + s4), acc);
            float b = b1[c], wv = w2[c];
            float4 h2 = make_float4(tanhf(acc.x + b), tanhf(acc.y + b),
                                    tanhf(acc.z + b), tanhf(acc.w + b));
            *(float4*)(sGT + c * 16 + s4) = make_float4(
                (1.f - h2.x * h2.x) * wv, (1.f - h2.y * h2.y) * wv,
                (1.f - h2.z * h2.z) * wv, (1.f - h2.w * h2.w) * wv);
        }
        __syncthreads();
        // U = G2 @ W1; fused G1 = (1-H1^2)*U
        {
            float4 acc = {0, 0, 0, 0};
            #pragma unroll 4
            for (int j = 0; j < 256; ++j)
                acc = f4fma(W1[j * 256 + c], *(const float4*)(sGT + j * 16 + s4), acc);
            float4 h1 = *(const float4*)(sH1T + c * 16 + s4);
            *(float4*)(sG1T + c * 16 + s4) = make_float4(
                (1.f - h1.x * h1.x) * acc.x, (1.f - h1.y * h1.y) * acc.y,
                (1.f - h1.z * h1.z) * acc.z, (1.f - h1.w * h1.w) * acc.w);
        }
        __syncthreads();
        // dy[i] = sum_k G1[k] * W0[k][i]
        {
            int s = tid >> 6, i = tid & 63;
            float acc = 0.f;
            #pragma unroll 8
            for (int k = 0; k < 256; ++k)
                acc = fmaf(sG1T[k * 16 + s], W0[k * 64 + i], acc);
            outg[sbase * 64 + tid] = acc;
        }
        __syncthreads();
    }
}

// ---------------- K2: pA head + poisson ----------------
// P3 retiled: thread = 2 cols x 16 samples -> W2PT read ONCE per block (2 MB).
__global__ __launch_bounds__(1024, 4) void k2_poisson(
    const float* __restrict__ y, const float* __restrict__ ws,
    const float* __restrict__ b0P, const float* __restrict__ b1P,
    float* __restrict__ dout)
{
    extern __shared__ float smem[];
    float* sa   = smem;            // 16 x 2024. Aliased: H1T @ [0,4096), yT @ [4096,5120)
    float* sH2T = smem + 32384;    // [256][16]
    float* sdE  = sH2T + 4096;     // [s][i]
    float* sdS  = sdE + 1024;

    float* sH1T = sa;
    float* syT  = sa + 4096;

    const int tid = threadIdx.x;
    const int sbase = blockIdx.x * SB;
    const float* gdE = ws + OFF_DE;
    const float* gdS = ws + OFF_DS;

    {
        int s = tid >> 6, i = tid & 63;
        syT[i * 16 + s] = y[sbase * 64 + tid];
        sdE[tid] = gdE[sbase * 64 + tid];
        sdS[tid] = gdS[sbase * 64 + tid];
    }
    __syncthreads();

    const int c  = tid & 255;
    const int sg = tid >> 8;
    const int s4 = sg * 4;

    // P1
    {
        const float* w0t = ws + OFF_W0T + 2 * 16384;
        float4 acc = {0, 0, 0, 0};
        #pragma unroll 4
        for (int k = 0; k < 64; ++k) {
            float w = w0t[k * 256 + c];
            float4 yv = *(const float4*)(syT + k * 16 + s4);
            acc = f4fma(w, yv, acc);
        }
        *(float4*)(sH1T + c * 16 + s4) = tanh4b(acc, b0P[c]);
    }
    __syncthreads();

    // P2
    {
        const float* w1t = ws + OFF_W1T + 2 * 65536;
        float4 acc = {0, 0, 0, 0};
        #pragma unroll 4
        for (int k = 0; k < 256; ++k) {
            float w = w1t[k * 256 + c];
            float4 hv = *(const float4*)(sH1T + k * 16 + s4);
            acc = f4fma(w, hv, acc);
        }
        *(float4*)(sH2T + c * 16 + s4) = tanh4b(acc, b1P[c]);
    }
    __syncthreads();   // H1T/yT regions dead; sa fully writable

    // P3: a-GEMM, thread = 2 cols x 16 samples (full weight dedup)
    {
        const int cn = tid;                 // cols 2cn, 2cn+1
        if (cn < 1008) {
            const float* wp = ws + OFF_W2PT + 2 * cn;
            float a0[16], a1[16];
            #pragma unroll
            for (int s = 0; s < 16; ++s) { a0[s] = 0.f; a1[s] = 0.f; }
            #pragma unroll 2
            for (int k = 0; k < 256; ++k) {
                float4 h0 = *(const float4*)(sH2T + k * 16);
                float4 h1 = *(const float4*)(sH2T + k * 16 + 4);
                float4 h2 = *(const float4*)(sH2T + k * 16 + 8);
                float4 h3 = *(const float4*)(sH2T + k * 16 + 12);
                float2 w = *(const float2*)(wp + k * 2016);
                float hs[16] = {h0.x, h0.y, h0.z, h0.w, h1.x, h1.y, h1.z, h1.w,
                                h2.x, h2.y, h2.z, h2.w, h3.x, h3.y, h3.z, h3.w};
                #pragma unroll
                for (int s = 0; s < 16; ++s) {
                    a0[s] = fmaf(hs[s], w.x, a0[s]);
                    a1[s] = fmaf(hs[s], w.y, a1[s]);
                }
            }
            #pragma unroll
            for (int s = 0; s < 16; ++s) {
                sa[s * 2024 + 2 * cn]     = a0[s];
                sa[s * 2024 + 2 * cn + 1] = a1[s];
            }
        }
    }
    __syncthreads();

    // P4: gather
    {
        const int s = tid >> 6;
        const int i = tid & 63;
        const int ib = i * (i - 1) / 2;
        const float* ap = sa + s * 2024;
        const float* dep = sdE + s * 64;
        const float* dsp = sdS + s * 64;

        float adE = 0.f, adS = 0.f;
        int trij = 0;
        #pragma unroll 4
        for (int j = 0; j < 64; ++j) {
            int t = (j < i) ? (ib + j) : (trij + i);
            float sel = (j < i) ? 1.f : ((j == i) ? 0.f : -1.f);
            float cc = sel * ap[t];
            adE = fmaf(cc, dep[j], adE);
            adS = fmaf(cc, dsp[j], adS);
            trij += j;
        }

        float de = dep[i], dsv = dsp[i];
        float p0 = de * adS;
        float p1 = de * dsv;
        float p2 = dsv * dsv;
        #pragma unroll
        for (int m = 1; m <= 32; m <<= 1) {
            p0 += __shfl_xor(p0, m);
            p1 += __shfl_xor(p1, m);
            p2 += __shfl_xor(p2, m);
        }
        float inv = 1.f / p2;
        dout[sbase * 64 + tid] = adE + (p0 * dsv - p1 * adS) * inv;
    }
}

// ---------------- K3: fC/fB heads + friction ----------------
// R9-v1 structure; C-head swapped to the R5-proven full-dedup mapping
// (thread = 1 col x 16 samples -> W2CT read once per block, 1 MB vs 4 MB).
__global__ __launch_bounds__(1024, 4) void k3_friction(
    const float* __restrict__ y, const float* __restrict__ ws,
    const float* __restrict__ b0C, const float* __restrict__ b1C,
    const float* __restrict__ b0B, const float* __restrict__ b1B,
    float* __restrict__ dout)
{
    extern __shared__ float smem[];
    float* sYT  = smem;
    float* sBTc = smem + 1024;
    float* sBTb = smem + 5120;
    float* sATc = smem + 9216;
    float* sATb = smem + 13312;
    float* sC   = smem + 9216;        // [16][1089] overlaps H1 tiles
    float* sdE  = smem + 26640;
    float* sdS  = sdE + 1024;
    float* sBdE = sdS + 1024;
    float* sBdS = sBdE + 1024;
    float* sv   = sBdS + 1024;
    float* sq   = sv + 1024;
    float* sScal = sq + 1024;
    float* sr   = sScal + 64;

    const int tid = threadIdx.x;
    const int sbase = blockIdx.x * SB;
    const float* gdE = ws + OFF_DE;
    const float* gdS = ws + OFF_DS;

    {
        int s = tid >> 6, i = tid & 63;
        sYT[i * 16 + s] = y[sbase * 64 + tid];
        sdE[tid] = gdE[sbase * 64 + tid];
        sdS[tid] = gdS[sbase * 64 + tid];
    }
    if (tid < 64) sScal[tid] = 0.f;
    __syncthreads();

    {
        int s = tid >> 6;
        float de = sdE[tid];
        unsafeAtomicAdd(&sScal[s * 4 + 0], de * de);
        unsafeAtomicAdd(&sScal[s * 4 + 1], de * sdS[tid]);
    }

    const int net = tid >> 9;
    const int t9  = tid & 511;
    const int sgf = t9 >> 7;
    const int s4f = sgf * 4;
    const int cp  = t9 & 127;
    const int c0 = 2 * cp, c1 = c0 + 1;
    const float* w0t = ws + OFF_W0T + (3 + net) * 16384;
    const float* w1t = ws + OFF_W1T + (3 + net) * 65536;
    const float* b0v = net ? b0B : b0C;
    const float* b1v = net ? b1B : b1C;
    float* sH1 = net ? sATb : sATc;
    float* sH2 = net ? sBTb : sBTc;

    // L0 (both nets)
    {
        float4 a0 = {0, 0, 0, 0}, a1 = {0, 0, 0, 0};
        #pragma unroll 4
        for (int k = 0; k < 64; ++k) {
            float4 h = *(const float4*)(sYT + k * 16 + s4f);
            float2 w = *(const float2*)(w0t + k * 256 + c0);
            a0 = f4fma(w.x, h, a0);
            a1 = f4fma(w.y, h, a1);
        }
        *(float4*)(sH1 + c0 * 16 + s4f) = tanh4b(a0, b0v[c0]);
        *(float4*)(sH1 + c1 * 16 + s4f) = tanh4b(a1, b0v[c1]);
    }
    __syncthreads();

    // L1 (both nets)
    {
        float4 a0 = {0, 0, 0, 0}, a1 = {0, 0, 0, 0};
        #pragma unroll 4
        for (int k = 0; k < 256; ++k) {
            float4 h = *(const float4*)(sH1 + k * 16 + s4f);
            float2 w = *(const float2*)(w1t + k * 256 + c0);
            a0 = f4fma(w.x, h, a0);
            a1 = f4fma(w.y, h, a1);
        }
        *(float4*)(sH2 + c0 * 16 + s4f) = tanh4b(a0, b1v[c0]);
        *(float4*)(sH2 + c1 * 16 + s4f) = tanh4b(a1, b1v[c1]);
    }
    __syncthreads();   // H1 tiles dead; sC writable

    // C head: full dedup, thread = one column n=tid, 16 samples (R5-proven)
    {
        const float* w2ct = ws + OFF_W2CT;
        float acc[16];
        #pragma unroll
        for (int s = 0; s < 16; ++s) acc[s] = 0.f;
        #pragma unroll 2
        for (int k = 0; k < 256; ++k) {
            float w = w2ct[k * 1024 + tid];
            float4 h0 = *(const float4*)(sBTc + k * 16);
            float4 h1 = *(const float4*)(sBTc + k * 16 + 4);
            float4 h2 = *(const float4*)(sBTc + k * 16 + 8);
            float4 h3 = *(const float4*)(sBTc + k * 16 + 12);
            float hs[16] = {h0.x, h0.y, h0.z, h0.w, h1.x, h1.y, h1.z, h1.w,
                            h2.x, h2.y, h2.z, h2.w, h3.x, h3.y, h3.z, h3.w};
            #pragma unroll
            for (int s = 0; s < 16; ++s) acc[s] = fmaf(hs[s], w, acc[s]);
        }
        const int kC = tid >> 4, mC = tid & 15;
        #pragma unroll
        for (int s = 0; s < 16; ++s) sC[s * 1089 + kC * 17 + mC] = acc[s];
    }
    __syncthreads();

    // Bm pass1: bm[16] float4 held for pass2, software-pipelined
    const int kp = tid >> 4;
    const int i0 = 4 * (tid & 15);
    float4 bm[16];
    #pragma unroll
    for (int s = 0; s < 16; ++s) bm[s] = make_float4(0.f, 0.f, 0.f, 0.f);
    {
        const float* wb = ws + OFF_W2BT + 4 * tid;
        float4 w = *(const float4*)(wb);
        float4 h0 = *(const float4*)(sBTb);
        float4 h1 = *(const float4*)(sBTb + 4);
        float4 h2 = *(const float4*)(sBTb + 8);
        float4 h3 = *(const float4*)(sBTb + 12);
        #pragma unroll 2
        for (int k = 0; k < 256; ++k) {
            float4 wn = *(const float4*)(wb + (k + 1) * 4096);
            float4 g0 = *(const float4*)(sBTb + (k + 1) * 16);
            float4 g1 = *(const float4*)(sBTb + (k + 1) * 16 + 4);
            float4 g2 = *(const float4*)(sBTb + (k + 1) * 16 + 8);
            float4 g3 = *(const float4*)(sBTb + (k + 1) * 16 + 12);
            float hs[16] = {h0.x, h0.y, h0.z, h0.w, h1.x, h1.y, h1.z, h1.w,
                            h2.x, h2.y, h2.z, h2.w, h3.x, h3.y, h3.z, h3.w};
            #pragma unroll
            for (int s = 0; s < 16; ++s) bm[s] = f4fma(hs[s], w, bm[s]);
            w = wn; h0 = g0; h1 = g1; h2 = g2; h3 = g3;
        }
    }
    #pragma unroll
    for (int s = 0; s < 16; ++s) {
        float4 de = *(const float4*)(sdE + s * 64 + i0);
        float4 dsv = *(const float4*)(sdS + s * 64 + i0);
        float pd = dot4f(bm[s], de);
        float ps = dot4f(bm[s], dsv);
        pd += __shfl_xor(pd, 1); ps += __shfl_xor(ps, 1);
        pd += __shfl_xor(pd, 2); ps += __shfl_xor(ps, 2);
        pd += __shfl_xor(pd, 4); ps += __shfl_xor(ps, 4);
        pd += __shfl_xor(pd, 8); ps += __shfl_xor(ps, 8);
        if ((tid & 15) == 0) {
            sBdE[s * 64 + kp] = pd;
            sBdS[s * 64 + kp] = ps;
        }
    }
    __syncthreads();

    {
        int s = tid >> 6;
        float beta = sScal[s * 4 + 1] / sScal[s * 4 + 0];
        sv[tid] = sBdS[tid] - beta * sBdE[tid];
    }
    __syncthreads();
    {
        int s = tid >> 6;
        unsafeAtomicAdd(&sScal[s * 4 + 2], sdE[tid] * sv[tid]);
    }
    __syncthreads();

    #pragma unroll
    for (int s = 0; s < 16; ++s) {
        float4 vv = *(const float4*)(sv + s * 64 + i0);
        float pq = dot4f(bm[s], vv);
        pq += __shfl_xor(pq, 1);
        pq += __shfl_xor(pq, 2);
        pq += __shfl_xor(pq, 4);
        pq += __shfl_xor(pq, 8);
        if ((tid & 15) == 0) sq[s * 64 + kp] = pq;
    }
    __syncthreads();

    if (tid < 256) {
        int s = tid >> 4, m = tid & 15;
        float gamma = sScal[s * 4 + 2] / sScal[s * 4 + 0];
        float r = 0.f;
        #pragma unroll 4
        for (int k = 0; k < 64; ++k) {
            float wv = sq[s * 64 + k] - gamma * sBdE[s * 64 + k];
            r = fmaf(sC[s * 1089 + k * 17 + m], wv, r);
        }
        sr[s * 16 + m] = r;
    }
    __syncthreads();
    {
        int s = tid >> 6, k = tid & 63;
        float o = 0.f;
        #pragma unroll
        for (int m2 = 0; m2 < 16; ++m2)
            o = fmaf(sC[s * 1089 + k * 17 + m2], sr[s * 16 + m2], o);
        int gi = sbase * 64 + tid;
        dout[gi] = dout[gi] + o;
    }
}

extern "C" void kernel_launch(void* const* d_in, const int* in_sizes, int n_in,
                              void* d_out, int out_size, void* d_ws, size_t ws_size,
                              hipStream_t stream)
{
    (void)in_sizes; (void)n_in; (void)out_size;
    const float* y = (const float*)d_in[1];
    const float* W0[5]; const float* b0[5]; const float* W1[5]; const float* b1[5]; const float* W2[5];
    for (int m = 0; m < 5; ++m) {
        int base = 2 + m * 5;
        W0[m] = (const float*)d_in[base + 0];
        b0[m] = (const float*)d_in[base + 1];
        W1[m] = (const float*)d_in[base + 2];
        b1[m] = (const float*)d_in[base + 3];
        W2[m] = (const float*)d_in[base + 4];
    }
    float* ws = (float*)d_ws;
    float* dout = (float*)d_out;
    if (ws_size < (size_t)WS_FLOATS * sizeof(float)) return;

    hipLaunchKernelGGL(k_transpose_all, dim3((2236416 + 1023) / 1024), dim3(1024), 0, stream,
                       ws,
                       W0[0], W0[1], W0[2], W0[3], W0[4],
                       W1[0], W1[1], W1[2], W1[3], W1[4],
                       W2[2], W2[3], W2[4]);

    hipLaunchKernelGGL(k1_grads, dim3(1024), dim3(1024), 0, stream,
                       y, ws,
                       W0[0], b0[0], W1[0], b1[0], W2[0],
                       W0[1], b0[1], W1[1], b1[1], W2[1],
                       ws + OFF_DE, ws + OFF_DS);

    const int k2_smem = 154112;
    hipFuncSetAttribute((const void*)k2_poisson, hipFuncAttributeMaxDynamicSharedMemorySize, k2_smem);
    hipLaunchKernelGGL(k2_poisson, dim3(1024), dim3(1024), k2_smem, stream,
                       y, ws, b0[2], b1[2], dout);

    const int k3_smem = 132416;
    hipFuncSetAttribute((const void*)k3_friction, hipFuncAttributeMaxDynamicSharedMemorySize, k3_smem);
    hipLaunchKernelGGL(k3_friction, dim3(1024), dim3(1024), k3_smem, stream,
                       y, ws, b0[3], b1[3], b0[4], b1[4], dout);
}

// Round 12
// 1141.735 us; speedup vs baseline: 1.6191x; 1.1823x over previous
//
#include <hip/hip_runtime.h>
#include <math.h>

// Problem constants: B=16384 samples, DIM=64, WIDTH=256, DD=64, C2=16
#define SB 16      // samples per workgroup

// ws layout (float offsets)
#define OFF_W0T  0            // 5 x (64x256)
#define OFF_W1T  81920        // 5 x (256x256)
#define OFF_W2PT 409600       // 256x2016
#define OFF_W2CT 925696       // 256x1024
#define OFF_W2BT 1187840      // 256x4096
#define OFF_DE   2236416      // 16384x64
#define OFF_DS   3284992      // 16384x64
#define WS_FLOATS 4337600     // ~17.35 MB (base)
// Packed bf16 W2B fragments (hi then lo), 1048576 ushorts each = 4 MB total
#define NPACK 1048576
#define WS2_FLOATS (WS_FLOATS + NPACK / 2 * 2)   // + 1M floats

typedef __attribute__((ext_vector_type(8))) short bf16x8;
typedef __attribute__((ext_vector_type(4))) float f32x4;

__device__ __forceinline__ float4 f4fma(float a, float4 w, float4 c) {
    c.x = fmaf(a, w.x, c.x); c.y = fmaf(a, w.y, c.y);
    c.z = fmaf(a, w.z, c.z); c.w = fmaf(a, w.w, c.w);
    return c;
}

__device__ __forceinline__ float dot4f(float4 a, float4 b) {
    return fmaf(a.w, b.w, fmaf(a.z, b.z, fmaf(a.y, b.y, a.x * b.x)));
}

__device__ __forceinline__ float4 tanh4b(float4 a, float b) {
    return make_float4(tanhf(a.x + b), tanhf(a.y + b), tanhf(a.z + b), tanhf(a.w + b));
}

// fp32 -> bf16 hi (RNE) + bf16 lo (RNE of remainder)
__device__ __forceinline__ void bf16split(float x, unsigned short& hi, unsigned short& lo) {
    unsigned b = __float_as_uint(x);
    unsigned h = (b + 0x7FFFu + ((b >> 16) & 1u)) >> 16;
    hi = (unsigned short)h;
    float r = x - __uint_as_float(h << 16);
    unsigned rb = __float_as_uint(r);
    lo = (unsigned short)((rb + 0x7FFFu + ((rb >> 16) & 1u)) >> 16);
}

// ---------------- merged transpose + optional W2B bf16 packing ----------------
//  [0, 81920)            5 x W0 -> W0T
//  [81920, 409600)       5 x W1 -> W1T
//  [409600, 925696)      W2P -> W2PT
//  [925696, 1187840)     W2C -> W2CT
//  [1187840, 2236416)    W2B -> W2BT
//  [2236416, 3284992)    W2B -> packed bf16 hi/lo fragments (only if big grid)
__global__ __launch_bounds__(1024) void k_transpose_all(
    float* __restrict__ ws,
    const float* __restrict__ W0a, const float* __restrict__ W0b, const float* __restrict__ W0c,
    const float* __restrict__ W0d, const float* __restrict__ W0e,
    const float* __restrict__ W1a, const float* __restrict__ W1b, const float* __restrict__ W1c,
    const float* __restrict__ W1d, const float* __restrict__ W1e,
    const float* __restrict__ W2p, const float* __restrict__ W2c, const float* __restrict__ W2b)
{
    int t = blockIdx.x * blockDim.x + threadIdx.x;
    if (t >= 2236416) {
        if (t >= 2236416 + NPACK) return;
        // pack W2B element for MFMA B-fragment: e = ((tt*8 + c)*64 + lane)*8 + j
        int e = t - 2236416;
        int j = e & 7, lane = (e >> 3) & 63, c = (e >> 9) & 7, tt = e >> 12;
        int k = c * 32 + ((lane >> 4) & 3) * 8 + j;
        int n = tt * 16 + (lane & 15);
        unsigned short hi, lo;
        bf16split(W2b[n * 256 + k], hi, lo);
        unsigned short* BH = (unsigned short*)(ws + WS_FLOATS);
        BH[e] = hi;
        BH[NPACK + e] = lo;
        return;
    }
    const float* in;
    int o, R, C;
    float* out;
    if (t < 81920) {
        int m = t >> 14; o = t & 16383;
        const float* W0s[5] = {W0a, W0b, W0c, W0d, W0e};
        in = W0s[m]; out = ws + OFF_W0T + m * 16384; R = 256; C = 64;
    } else if (t < 409600) {
        int t2 = t - 81920;
        int m = t2 >> 16; o = t2 & 65535;
        const float* W1s[5] = {W1a, W1b, W1c, W1d, W1e};
        in = W1s[m]; out = ws + OFF_W1T + m * 65536; R = 256; C = 256;
    } else if (t < 925696) {
        o = t - 409600; in = W2p; out = ws + OFF_W2PT; R = 2016; C = 256;
    } else if (t < 1187840) {
        o = t - 925696; in = W2c; out = ws + OFF_W2CT; R = 1024; C = 256;
    } else {
        o = t - 1187840; in = W2b; out = ws + OFF_W2BT; R = 4096; C = 256;
    }
    int c = o / R, r = o - c * R;
    out[o] = in[r * C + c];
}

// ---------------- K1: dE, dS ----------------
__global__ __launch_bounds__(1024, 2) void k1_grads(
    const float* __restrict__ y, const float* __restrict__ ws,
    const float* __restrict__ W0E, const float* __restrict__ b0E,
    const float* __restrict__ W1E, const float* __restrict__ b1E,
    const float* __restrict__ w2E,
    const float* __restrict__ W0S, const float* __restrict__ b0S,
    const float* __restrict__ W1S, const float* __restrict__ b1S,
    const float* __restrict__ w2S,
    float* __restrict__ odE, float* __restrict__ odS)
{
    __shared__ float syT[1024];       // [64][16]
    __shared__ float sH1T[4096];      // [256][16]
    __shared__ float sGT[4096];       // [256][16]  (G2)
    __shared__ float sG1T[4096];      // [256][16]  (G1)

    const int tid = threadIdx.x;
    const int sbase = blockIdx.x * SB;
    {
        int s = tid >> 6, i = tid & 63;
        syT[i * 16 + s] = y[sbase * 64 + tid];
    }
    __syncthreads();

    const int c = tid & 255, sg = tid >> 8, s4 = sg * 4;

    for (int m = 0; m < 2; ++m) {
        const float* w0t = ws + OFF_W0T + m * 16384;
        const float* w1t = ws + OFF_W1T + m * 65536;
        const float* W0 = m ? W0S : W0E;     // natural (256,64)
        const float* W1 = m ? W1S : W1E;     // natural (256,256)
        const float* b0 = m ? b0S : b0E;
        const float* b1 = m ? b1S : b1E;
        const float* w2 = m ? w2S : w2E;
        float* outg = m ? odS : odE;

        {
            float4 acc = {0, 0, 0, 0};
            #pragma unroll 4
            for (int k = 0; k < 64; ++k)
                acc = f4fma(w0t[k * 256 + c], *(const float4*)(syT + k * 16 + s4), acc);
            *(float4*)(sH1T + c * 16 + s4) = tanh4b(acc, b0[c]);
        }
        __syncthreads();
        {
            float4 acc = {0, 0, 0, 0};
            #pragma unroll 4
            for (int k = 0; k < 256; ++k)
                acc = f4fma(w1t[k * 256 + c], *(const float4*)(sH1T + k * 16 + s4), acc);
            float b = b1[c], wv = w2[c];
            float4 h2 = make_float4(tanhf(acc.x + b), tanhf(acc.y + b),
                                    tanhf(acc.z + b), tanhf(acc.w + b));
            *(float4*)(sGT + c * 16 + s4) = make_float4(
                (1.f - h2.x * h2.x) * wv, (1.f - h2.y * h2.y) * wv,
                (1.f - h2.z * h2.z) * wv, (1.f - h2.w * h2.w) * wv);
        }
        __syncthreads();
        {
            float4 acc = {0, 0, 0, 0};
            #pragma unroll 4
            for (int j = 0; j < 256; ++j)
                acc = f4fma(W1[j * 256 + c], *(const float4*)(sGT + j * 16 + s4), acc);
            float4 h1 = *(const float4*)(sH1T + c * 16 + s4);
            *(float4*)(sG1T + c * 16 + s4) = make_float4(
                (1.f - h1.x * h1.x) * acc.x, (1.f - h1.y * h1.y) * acc.y,
                (1.f - h1.z * h1.z) * acc.z, (1.f - h1.w * h1.w) * acc.w);
        }
        __syncthreads();
        {
            int s = tid >> 6, i = tid & 63;
            float acc = 0.f;
            #pragma unroll 8
            for (int k = 0; k < 256; ++k)
                acc = fmaf(sG1T[k * 16 + s], W0[k * 64 + i], acc);
            outg[sbase * 64 + tid] = acc;
        }
        __syncthreads();
    }
}

// ---------------- K2: pA head + poisson ----------------
__global__ __launch_bounds__(1024, 4) void k2_poisson(
    const float* __restrict__ y, const float* __restrict__ ws,
    const float* __restrict__ b0P, const float* __restrict__ b1P,
    float* __restrict__ dout)
{
    extern __shared__ float smem[];
    float* sa   = smem;            // 16 x 2024. Aliased: H1T @ [0,4096), yT @ [4096,5120)
    float* sH2T = smem + 32384;    // [256][16]
    float* sdE  = sH2T + 4096;     // [s][i]
    float* sdS  = sdE + 1024;

    float* sH1T = sa;
    float* syT  = sa + 4096;

    const int tid = threadIdx.x;
    const int sbase = blockIdx.x * SB;
    const float* gdE = ws + OFF_DE;
    const float* gdS = ws + OFF_DS;

    {
        int s = tid >> 6, i = tid & 63;
        syT[i * 16 + s] = y[sbase * 64 + tid];
        sdE[tid] = gdE[sbase * 64 + tid];
        sdS[tid] = gdS[sbase * 64 + tid];
    }
    __syncthreads();

    const int c  = tid & 255;
    const int sg = tid >> 8;
    const int s4 = sg * 4;

    // P1
    {
        const float* w0t = ws + OFF_W0T + 2 * 16384;
        float4 acc = {0, 0, 0, 0};
        #pragma unroll 4
        for (int k = 0; k < 64; ++k) {
            float w = w0t[k * 256 + c];
            float4 yv = *(const float4*)(syT + k * 16 + s4);
            acc = f4fma(w, yv, acc);
        }
        *(float4*)(sH1T + c * 16 + s4) = tanh4b(acc, b0P[c]);
    }
    __syncthreads();

    // P2
    {
        const float* w1t = ws + OFF_W1T + 2 * 65536;
        float4 acc = {0, 0, 0, 0};
        #pragma unroll 4
        for (int k = 0; k < 256; ++k) {
            float w = w1t[k * 256 + c];
            float4 hv = *(const float4*)(sH1T + k * 16 + s4);
            acc = f4fma(w, hv, acc);
        }
        *(float4*)(sH2T + c * 16 + s4) = tanh4b(acc, b1P[c]);
    }
    __syncthreads();

    // P3: a-GEMM, thread = 2 cols x 16 samples
    {
        const int cn = tid;
        if (cn < 1008) {
            const float* wp = ws + OFF_W2PT + 2 * cn;
            float a0[16], a1[16];
            #pragma unroll
            for (int s = 0; s < 16; ++s) { a0[s] = 0.f; a1[s] = 0.f; }
            #pragma unroll 2
            for (int k = 0; k < 256; ++k) {
                float4 h0 = *(const float4*)(sH2T + k * 16);
                float4 h1 = *(const float4*)(sH2T + k * 16 + 4);
                float4 h2 = *(const float4*)(sH2T + k * 16 + 8);
                float4 h3 = *(const float4*)(sH2T + k * 16 + 12);
                float2 w = *(const float2*)(wp + k * 2016);
                float hs[16] = {h0.x, h0.y, h0.z, h0.w, h1.x, h1.y, h1.z, h1.w,
                                h2.x, h2.y, h2.z, h2.w, h3.x, h3.y, h3.z, h3.w};
                #pragma unroll
                for (int s = 0; s < 16; ++s) {
                    a0[s] = fmaf(hs[s], w.x, a0[s]);
                    a1[s] = fmaf(hs[s], w.y, a1[s]);
                }
            }
            #pragma unroll
            for (int s = 0; s < 16; ++s) {
                sa[s * 2024 + 2 * cn]     = a0[s];
                sa[s * 2024 + 2 * cn + 1] = a1[s];
            }
        }
    }
    __syncthreads();

    // P4: gather
    {
        const int s = tid >> 6;
        const int i = tid & 63;
        const int ib = i * (i - 1) / 2;
        const float* ap = sa + s * 2024;
        const float* dep = sdE + s * 64;
        const float* dsp = sdS + s * 64;

        float adE = 0.f, adS = 0.f;
        int trij = 0;
        #pragma unroll 4
        for (int j = 0; j < 64; ++j) {
            int t = (j < i) ? (ib + j) : (trij + i);
            float sel = (j < i) ? 1.f : ((j == i) ? 0.f : -1.f);
            float cc = sel * ap[t];
            adE = fmaf(cc, dep[j], adE);
            adS = fmaf(cc, dsp[j], adS);
            trij += j;
        }

        float de = dep[i], dsv = dsp[i];
        float p0 = de * adS;
        float p1 = de * dsv;
        float p2 = dsv * dsv;
        #pragma unroll
        for (int m = 1; m <= 32; m <<= 1) {
            p0 += __shfl_xor(p0, m);
            p1 += __shfl_xor(p1, m);
            p2 += __shfl_xor(p2, m);
        }
        float inv = 1.f / p2;
        dout[sbase * 64 + tid] = adE + (p0 * dsv - p1 * adS) * inv;
    }
}

// ---------------- K3 v1: proven R11 version (fallback) ----------------
__global__ __launch_bounds__(1024, 4) void k3_friction_v1(
    const float* __restrict__ y, const float* __restrict__ ws,
    const float* __restrict__ b0C, const float* __restrict__ b1C,
    const float* __restrict__ b0B, const float* __restrict__ b1B,
    float* __restrict__ dout)
{
    extern __shared__ float smem[];
    float* sYT  = smem;
    float* sBTc = smem + 1024;
    float* sBTb = smem + 5120;
    float* sATc = smem + 9216;
    float* sATb = smem + 13312;
    float* sC   = smem + 9216;
    float* sdE  = smem + 26640;
    float* sdS  = sdE + 1024;
    float* sBdE = sdS + 1024;
    float* sBdS = sBdE + 1024;
    float* sv   = sBdS + 1024;
    float* sq   = sv + 1024;
    float* sScal = sq + 1024;
    float* sr   = sScal + 64;

    const int tid = threadIdx.x;
    const int sbase = blockIdx.x * SB;
    const float* gdE = ws + OFF_DE;
    const float* gdS = ws + OFF_DS;

    {
        int s = tid >> 6, i = tid & 63;
        sYT[i * 16 + s] = y[sbase * 64 + tid];
        sdE[tid] = gdE[sbase * 64 + tid];
        sdS[tid] = gdS[sbase * 64 + tid];
    }
    if (tid < 64) sScal[tid] = 0.f;
    __syncthreads();

    {
        int s = tid >> 6;
        float de = sdE[tid];
        unsafeAtomicAdd(&sScal[s * 4 + 0], de * de);
        unsafeAtomicAdd(&sScal[s * 4 + 1], de * sdS[tid]);
    }

    const int net = tid >> 9;
    const int t9  = tid & 511;
    const int sgf = t9 >> 7;
    const int s4f = sgf * 4;
    const int cp  = t9 & 127;
    const int c0 = 2 * cp, c1 = c0 + 1;
    const float* w0t = ws + OFF_W0T + (3 + net) * 16384;
    const float* w1t = ws + OFF_W1T + (3 + net) * 65536;
    const float* b0v = net ? b0B : b0C;
    const float* b1v = net ? b1B : b1C;
    float* sH1 = net ? sATb : sATc;
    float* sH2 = net ? sBTb : sBTc;

    {
        float4 a0 = {0, 0, 0, 0}, a1 = {0, 0, 0, 0};
        #pragma unroll 4
        for (int k = 0; k < 64; ++k) {
            float4 h = *(const float4*)(sYT + k * 16 + s4f);
            float2 w = *(const float2*)(w0t + k * 256 + c0);
            a0 = f4fma(w.x, h, a0);
            a1 = f4fma(w.y, h, a1);
        }
        *(float4*)(sH1 + c0 * 16 + s4f) = tanh4b(a0, b0v[c0]);
        *(float4*)(sH1 + c1 * 16 + s4f) = tanh4b(a1, b0v[c1]);
    }
    __syncthreads();

    {
        float4 a0 = {0, 0, 0, 0}, a1 = {0, 0, 0, 0};
        #pragma unroll 4
        for (int k = 0; k < 256; ++k) {
            float4 h = *(const float4*)(sH1 + k * 16 + s4f);
            float2 w = *(const float2*)(w1t + k * 256 + c0);
            a0 = f4fma(w.x, h, a0);
            a1 = f4fma(w.y, h, a1);
        }
        *(float4*)(sH2 + c0 * 16 + s4f) = tanh4b(a0, b1v[c0]);
        *(float4*)(sH2 + c1 * 16 + s4f) = tanh4b(a1, b1v[c1]);
    }
    __syncthreads();

    {
        const float* w2ct = ws + OFF_W2CT;
        float acc[16];
        #pragma unroll
        for (int s = 0; s < 16; ++s) acc[s] = 0.f;
        #pragma unroll 2
        for (int k = 0; k < 256; ++k) {
            float w = w2ct[k * 1024 + tid];
            float4 h0 = *(const float4*)(sBTc + k * 16);
            float4 h1 = *(const float4*)(sBTc + k * 16 + 4);
            float4 h2 = *(const float4*)(sBTc + k * 16 + 8);
            float4 h3 = *(const float4*)(sBTc + k * 16 + 12);
            float hs[16] = {h0.x, h0.y, h0.z, h0.w, h1.x, h1.y, h1.z, h1.w,
                            h2.x, h2.y, h2.z, h2.w, h3.x, h3.y, h3.z, h3.w};
            #pragma unroll
            for (int s = 0; s < 16; ++s) acc[s] = fmaf(hs[s], w, acc[s]);
        }
        const int kC = tid >> 4, mC = tid & 15;
        #pragma unroll
        for (int s = 0; s < 16; ++s) sC[s * 1089 + kC * 17 + mC] = acc[s];
    }
    __syncthreads();

    const int kp = tid >> 4;
    const int i0 = 4 * (tid & 15);
    float4 bm[16];
    #pragma unroll
    for (int s = 0; s < 16; ++s) bm[s] = make_float4(0.f, 0.f, 0.f, 0.f);
    {
        const float* wb = ws + OFF_W2BT + 4 * tid;
        float4 w = *(const float4*)(wb);
        float4 h0 = *(const float4*)(sBTb);
        float4 h1 = *(const float4*)(sBTb + 4);
        float4 h2 = *(const float4*)(sBTb + 8);
        float4 h3 = *(const float4*)(sBTb + 12);
        #pragma unroll 2
        for (int k = 0; k < 256; ++k) {
            float4 wn = *(const float4*)(wb + (k + 1) * 4096);
            float4 g0 = *(const float4*)(sBTb + (k + 1) * 16);
            float4 g1 = *(const float4*)(sBTb + (k + 1) * 16 + 4);
            float4 g2 = *(const float4*)(sBTb + (k + 1) * 16 + 8);
            float4 g3 = *(const float4*)(sBTb + (k + 1) * 16 + 12);
            float hs[16] = {h0.x, h0.y, h0.z, h0.w, h1.x, h1.y, h1.z, h1.w,
                            h2.x, h2.y, h2.z, h2.w, h3.x, h3.y, h3.z, h3.w};
            #pragma unroll
            for (int s = 0; s < 16; ++s) bm[s] = f4fma(hs[s], w, bm[s]);
            w = wn; h0 = g0; h1 = g1; h2 = g2; h3 = g3;
        }
    }
    #pragma unroll
    for (int s = 0; s < 16; ++s) {
        float4 de = *(const float4*)(sdE + s * 64 + i0);
        float4 dsv = *(const float4*)(sdS + s * 64 + i0);
        float pd = dot4f(bm[s], de);
        float ps = dot4f(bm[s], dsv);
        pd += __shfl_xor(pd, 1); ps += __shfl_xor(ps, 1);
        pd += __shfl_xor(pd, 2); ps += __shfl_xor(ps, 2);
        pd += __shfl_xor(pd, 4); ps += __shfl_xor(ps, 4);
        pd += __shfl_xor(pd, 8); ps += __shfl_xor(ps, 8);
        if ((tid & 15) == 0) {
            sBdE[s * 64 + kp] = pd;
            sBdS[s * 64 + kp] = ps;
        }
    }
    __syncthreads();

    {
        int s = tid >> 6;
        float beta = sScal[s * 4 + 1] / sScal[s * 4 + 0];
        sv[tid] = sBdS[tid] - beta * sBdE[tid];
    }
    __syncthreads();
    {
        int s = tid >> 6;
        unsafeAtomicAdd(&sScal[s * 4 + 2], sdE[tid] * sv[tid]);
    }
    __syncthreads();

    #pragma unroll
    for (int s = 0; s < 16; ++s) {
        float4 vv = *(const float4*)(sv + s * 64 + i0);
        float pq = dot4f(bm[s], vv);
        pq += __shfl_xor(pq, 1);
        pq += __shfl_xor(pq, 2);
        pq += __shfl_xor(pq, 4);
        pq += __shfl_xor(pq, 8);
        if ((tid & 15) == 0) sq[s * 64 + kp] = pq;
    }
    __syncthreads();

    if (tid < 256) {
        int s = tid >> 4, m = tid & 15;
        float gamma = sScal[s * 4 + 2] / sScal[s * 4 + 0];
        float r = 0.f;
        #pragma unroll 4
        for (int k = 0; k < 64; ++k) {
            float wv = sq[s * 64 + k] - gamma * sBdE[s * 64 + k];
            r = fmaf(sC[s * 1089 + k * 17 + m], wv, r);
        }
        sr[s * 16 + m] = r;
    }
    __syncthreads();
    {
        int s = tid >> 6, k = tid & 63;
        float o = 0.f;
        #pragma unroll
        for (int m2 = 0; m2 < 16; ++m2)
            o = fmaf(sC[s * 1089 + k * 17 + m2], sr[s * 16 + m2], o);
        int gi = sbase * 64 + tid;
        dout[gi] = dout[gi] + o;
    }
}

// ---------------- K3 mf: Bm via split-bf16 MFMA ----------------
// Bm GEMM (16x4096x256) = 3x mfma_f32_16x16x32_bf16 per (c,t): D = Ah*Bh + Al*Bh + Ah*Bl.
// A (h for fB) packed bf16 hi/lo into LDS at L1; B (W2B) pre-packed in ws.
// acc[16] f32x4 per thread holds the wave's 16 n-tiles -> full Bm stays in
// registers for both dot passes (no recompute). Everything else = v1.
__global__ __launch_bounds__(1024, 4) void k3_friction_mf(
    const float* __restrict__ y, const float* __restrict__ ws,
    const float* __restrict__ b0C, const float* __restrict__ b1C,
    const float* __restrict__ b0B, const float* __restrict__ b1B,
    float* __restrict__ dout)
{
    extern __shared__ float smem[];
    float* sYT  = smem;                               // [64][16]
    float* sBTc = smem + 1024;                        // [256][16] fC H2 (fp32)
    unsigned short* sAh = (unsigned short*)(smem + 5120);   // A-pack hi: 4096 ushort (8KB)
    unsigned short* sAl = (unsigned short*)(smem + 7168);   // A-pack lo: 4096 ushort (8KB)
    float* sATc = smem + 9216;                        // fC H1 (dead after L1)
    float* sATb = smem + 13312;                       // fB H1 (dead after L1)
    float* sC   = smem + 9216;                        // [16][1089] overlaps H1 tiles
    float* sdE  = smem + 26640;
    float* sdS  = sdE + 1024;
    float* sBdE = sdS + 1024;
    float* sBdS = sBdE + 1024;
    float* sv   = sBdS + 1024;
    float* sq   = sv + 1024;
    float* sScal = sq + 1024;
    float* sr   = sScal + 64;

    const int tid = threadIdx.x;
    const int sbase = blockIdx.x * SB;
    const float* gdE = ws + OFF_DE;
    const float* gdS = ws + OFF_DS;

    {
        int s = tid >> 6, i = tid & 63;
        sYT[i * 16 + s] = y[sbase * 64 + tid];
        sdE[tid] = gdE[sbase * 64 + tid];
        sdS[tid] = gdS[sbase * 64 + tid];
    }
    if (tid < 64) sScal[tid] = 0.f;
    __syncthreads();

    {
        int s = tid >> 6;
        float de = sdE[tid];
        unsafeAtomicAdd(&sScal[s * 4 + 0], de * de);
        unsafeAtomicAdd(&sScal[s * 4 + 1], de * sdS[tid]);
    }

    const int net = tid >> 9;
    const int t9  = tid & 511;
    const int sgf = t9 >> 7;
    const int s4f = sgf * 4;
    const int cp  = t9 & 127;
    const int c0 = 2 * cp, c1 = c0 + 1;
    const float* w0t = ws + OFF_W0T + (3 + net) * 16384;
    const float* w1t = ws + OFF_W1T + (3 + net) * 65536;
    const float* b0v = net ? b0B : b0C;
    const float* b1v = net ? b1B : b1C;
    float* sH1 = net ? sATb : sATc;

    // L0 (both nets)
    {
        float4 a0 = {0, 0, 0, 0}, a1 = {0, 0, 0, 0};
        #pragma unroll 4
        for (int k = 0; k < 64; ++k) {
            float4 h = *(const float4*)(sYT + k * 16 + s4f);
            float2 w = *(const float2*)(w0t + k * 256 + c0);
            a0 = f4fma(w.x, h, a0);
            a1 = f4fma(w.y, h, a1);
        }
        *(float4*)(sH1 + c0 * 16 + s4f) = tanh4b(a0, b0v[c0]);
        *(float4*)(sH1 + c1 * 16 + s4f) = tanh4b(a1, b0v[c1]);
    }
    __syncthreads();

    // L1 (both nets): net0 -> sBTc fp32; net1 -> A-pack bf16 hi/lo
    {
        float4 a0 = {0, 0, 0, 0}, a1 = {0, 0, 0, 0};
        #pragma unroll 4
        for (int k = 0; k < 256; ++k) {
            float4 h = *(const float4*)(sH1 + k * 16 + s4f);
            float2 w = *(const float2*)(w1t + k * 256 + c0);
            a0 = f4fma(w.x, h, a0);
            a1 = f4fma(w.y, h, a1);
        }
        float4 h2a = tanh4b(a0, b1v[c0]);
        float4 h2b = tanh4b(a1, b1v[c1]);
        if (net == 0) {
            *(float4*)(sBTc + c0 * 16 + s4f) = h2a;
            *(float4*)(sBTc + c1 * 16 + s4f) = h2b;
        } else {
            // A-pack: element (sample s, k=col): idx = ((k>>5)*64 + ((s&15)|(((k>>3)&3)<<4)))*8 + (k&7)
            const int cblk = c0 >> 5, j0 = c0 & 7;
            const int lbase = ((c0 >> 3) & 3) << 4;
            float va[2][4] = {{h2a.x, h2a.y, h2a.z, h2a.w}, {h2b.x, h2b.y, h2b.z, h2b.w}};
            #pragma unroll
            for (int q = 0; q < 4; ++q) {
                int lb = ((s4f + q) & 15) | lbase;
                int base = (cblk * 64 + lb) * 8 + j0;
                unsigned short hi0, lo0, hi1, lo1;
                bf16split(va[0][q], hi0, lo0);
                bf16split(va[1][q], hi1, lo1);
                sAh[base] = hi0; sAh[base + 1] = hi1;
                sAl[base] = lo0; sAl[base + 1] = lo1;
            }
        }
    }
    __syncthreads();

    // C head (fp32 VALU, unchanged)
    {
        const float* w2ct = ws + OFF_W2CT;
        float acc[16];
        #pragma unroll
        for (int s = 0; s < 16; ++s) acc[s] = 0.f;
        #pragma unroll 2
        for (int k = 0; k < 256; ++k) {
            float w = w2ct[k * 1024 + tid];
            float4 h0 = *(const float4*)(sBTc + k * 16);
            float4 h1 = *(const float4*)(sBTc + k * 16 + 4);
            float4 h2 = *(const float4*)(sBTc + k * 16 + 8);
            float4 h3 = *(const float4*)(sBTc + k * 16 + 12);
            float hs[16] = {h0.x, h0.y, h0.z, h0.w, h1.x, h1.y, h1.z, h1.w,
                            h2.x, h2.y, h2.z, h2.w, h3.x, h3.y, h3.z, h3.w};
            #pragma unroll
            for (int s = 0; s < 16; ++s) acc[s] = fmaf(hs[s], w, acc[s]);
        }
        const int kC = tid >> 4, mC = tid & 15;
        #pragma unroll
        for (int s = 0; s < 16; ++s) sC[s * 1089 + kC * 17 + mC] = acc[s];
    }
    __syncthreads();

    // ===== Bm via MFMA: wave w owns n-tiles t = 16w..16w+15 =====
    const int wv = tid >> 6;          // wave 0..15
    const int l  = tid & 63;          // lane
    f32x4 acc[16];
    #pragma unroll
    for (int t0 = 0; t0 < 16; ++t0) acc[t0] = (f32x4){0.f, 0.f, 0.f, 0.f};
    {
        const unsigned short* BH = (const unsigned short*)(ws + WS_FLOATS);
        const unsigned short* BL = BH + NPACK;
        #pragma unroll 1
        for (int cb = 0; cb < 8; ++cb) {
            bf16x8 Ah = *(const bf16x8*)(sAh + (cb * 64 + l) * 8);
            bf16x8 Al = *(const bf16x8*)(sAl + (cb * 64 + l) * 8);
            const unsigned short* bh = BH + ((wv * 16 * 8 + cb) * 64 + l) * 8;
            const unsigned short* bl = BL + ((wv * 16 * 8 + cb) * 64 + l) * 8;
            #pragma unroll
            for (int t0 = 0; t0 < 16; ++t0) {
                bf16x8 Bh = *(const bf16x8*)(bh + t0 * 4096);
                bf16x8 Bl = *(const bf16x8*)(bl + t0 * 4096);
                acc[t0] = __builtin_amdgcn_mfma_f32_16x16x32_bf16(Ah, Bh, acc[t0], 0, 0, 0);
                acc[t0] = __builtin_amdgcn_mfma_f32_16x16x32_bf16(Al, Bh, acc[t0], 0, 0, 0);
                acc[t0] = __builtin_amdgcn_mfma_f32_16x16x32_bf16(Ah, Bl, acc[t0], 0, 0, 0);
            }
        }
    }
    // dots: lane l, reg r -> sample s=(l>>4)*4+r, n=16t+(l&15), i=n&63, k'=t>>2=4w+g
    #pragma unroll
    for (int g = 0; g < 4; ++g) {
        float pd[4] = {0, 0, 0, 0}, ps[4] = {0, 0, 0, 0};
        #pragma unroll
        for (int tt = 0; tt < 4; ++tt) {
            int i = 16 * tt + (l & 15);
            #pragma unroll
            for (int r = 0; r < 4; ++r) {
                int s = (l >> 4) * 4 + r;
                float d = acc[g * 4 + tt][r];
                pd[r] = fmaf(d, sdE[s * 64 + i], pd[r]);
                ps[r] = fmaf(d, sdS[s * 64 + i], ps[r]);
            }
        }
        #pragma unroll
        for (int m = 1; m <= 8; m <<= 1) {
            #pragma unroll
            for (int r = 0; r < 4; ++r) {
                pd[r] += __shfl_xor(pd[r], m);
                ps[r] += __shfl_xor(ps[r], m);
            }
        }
        if ((l & 15) == 0) {
            int kpr = 4 * wv + g;
            #pragma unroll
            for (int r = 0; r < 4; ++r) {
                int s = (l >> 4) * 4 + r;
                sBdE[s * 64 + kpr] = pd[r];
                sBdS[s * 64 + kpr] = ps[r];
            }
        }
    }
    __syncthreads();

    {
        int s = tid >> 6;
        float beta = sScal[s * 4 + 1] / sScal[s * 4 + 0];
        sv[tid] = sBdS[tid] - beta * sBdE[tid];
    }
    __syncthreads();
    {
        int s = tid >> 6;
        unsafeAtomicAdd(&sScal[s * 4 + 2], sdE[tid] * sv[tid]);
    }
    __syncthreads();

    // pass2: q = Bm @ v from acc registers
    #pragma unroll
    for (int g = 0; g < 4; ++g) {
        float pq[4] = {0, 0, 0, 0};
        #pragma unroll
        for (int tt = 0; tt < 4; ++tt) {
            int i = 16 * tt + (l & 15);
            #pragma unroll
            for (int r = 0; r < 4; ++r) {
                int s = (l >> 4) * 4 + r;
                pq[r] = fmaf(acc[g * 4 + tt][r], sv[s * 64 + i], pq[r]);
            }
        }
        #pragma unroll
        for (int m = 1; m <= 8; m <<= 1) {
            #pragma unroll
            for (int r = 0; r < 4; ++r) pq[r] += __shfl_xor(pq[r], m);
        }
        if ((l & 15) == 0) {
            int kpr = 4 * wv + g;
            #pragma unroll
            for (int r = 0; r < 4; ++r) sq[((l >> 4) * 4 + r) * 64 + kpr] = pq[r];
        }
    }
    __syncthreads();

    if (tid < 256) {
        int s = tid >> 4, m = tid & 15;
        float gamma = sScal[s * 4 + 2] / sScal[s * 4 + 0];
        float r = 0.f;
        #pragma unroll 4
        for (int k = 0; k < 64; ++k) {
            float wvv = sq[s * 64 + k] - gamma * sBdE[s * 64 + k];
            r = fmaf(sC[s * 1089 + k * 17 + m], wvv, r);
        }
        sr[s * 16 + m] = r;
    }
    __syncthreads();
    {
        int s = tid >> 6, k = tid & 63;
        float o = 0.f;
        #pragma unroll
        for (int m2 = 0; m2 < 16; ++m2)
            o = fmaf(sC[s * 1089 + k * 17 + m2], sr[s * 16 + m2], o);
        int gi = sbase * 64 + tid;
        dout[gi] = dout[gi] + o;
    }
}

extern "C" void kernel_launch(void* const* d_in, const int* in_sizes, int n_in,
                              void* d_out, int out_size, void* d_ws, size_t ws_size,
                              hipStream_t stream)
{
    (void)in_sizes; (void)n_in; (void)out_size;
    const float* y = (const float*)d_in[1];
    const float* W0[5]; const float* b0[5]; const float* W1[5]; const float* b1[5]; const float* W2[5];
    for (int m = 0; m < 5; ++m) {
        int base = 2 + m * 5;
        W0[m] = (const float*)d_in[base + 0];
        b0[m] = (const float*)d_in[base + 1];
        W1[m] = (const float*)d_in[base + 2];
        b1[m] = (const float*)d_in[base + 3];
        W2[m] = (const float*)d_in[base + 4];
    }
    float* ws = (float*)d_ws;
    float* dout = (float*)d_out;
    if (ws_size < (size_t)WS_FLOATS * sizeof(float)) return;
    const bool big_ws = ws_size >= (size_t)WS2_FLOATS * sizeof(float);

    const int ntr = big_ws ? (2236416 + NPACK) : 2236416;
    hipLaunchKernelGGL(k_transpose_all, dim3((ntr + 1023) / 1024), dim3(1024), 0, stream,
                       ws,
                       W0[0], W0[1], W0[2], W0[3], W0[4],
                       W1[0], W1[1], W1[2], W1[3], W1[4],
                       W2[2], W2[3], W2[4]);

    hipLaunchKernelGGL(k1_grads, dim3(1024), dim3(1024), 0, stream,
                       y, ws,
                       W0[0], b0[0], W1[0], b1[0], W2[0],
                       W0[1], b0[1], W1[1], b1[1], W2[1],
                       ws + OFF_DE, ws + OFF_DS);

    const int k2_smem = 154112;
    hipFuncSetAttribute((const void*)k2_poisson, hipFuncAttributeMaxDynamicSharedMemorySize, k2_smem);
    hipLaunchKernelGGL(k2_poisson, dim3(1024), dim3(1024), k2_smem, stream,
                       y, ws, b0[2], b1[2], dout);

    const int k3_smem = 132416;
    if (big_ws) {
        hipFuncSetAttribute((const void*)k3_friction_mf, hipFuncAttributeMaxDynamicSharedMemorySize, k3_smem);
        hipLaunchKernelGGL(k3_friction_mf, dim3(1024), dim3(1024), k3_smem, stream,
                           y, ws, b0[3], b1[3], b0[4], b1[4], dout);
    } else {
        hipFuncSetAttribute((const void*)k3_friction_v1, hipFuncAttributeMaxDynamicSharedMemorySize, k3_smem);
        hipLaunchKernelGGL(k3_friction_v1, dim3(1024), dim3(1024), k3_smem, stream,
                           y, ws, b0[3], b1[3], b0[4], b1[4], dout);
    }
}

// Round 13
// 850.078 us; speedup vs baseline: 2.1747x; 1.3431x over previous
//
#include <hip/hip_runtime.h>
#include <math.h>

// Problem constants: B=16384 samples, DIM=64, WIDTH=256, DD=64, C2=16
#define SB 16      // samples per workgroup

// ws layout (float offsets)
#define OFF_W0T  0            // 5 x (64x256)
#define OFF_W1T  81920        // 5 x (256x256)
#define OFF_W2PT 409600       // 256x2016
#define OFF_W2CT 925696       // 256x1024
#define OFF_W2BT 1187840      // 256x4096
#define OFF_DE   2236416      // 16384x64
#define OFF_DS   3284992      // 16384x64
#define WS_FLOATS 4337600     // ~17.35 MB (base)
// Packed bf16 fragments (hi block then lo block), after WS_FLOATS:
#define NPACK  1048576        // W2B: 64 ktiles... (4096 cols = 256 ntiles x 8 cb x 64 x 8)
#define NPACKC 262144         // W2C: 64 ntiles
#define NPACKP 524288         // W2P padded to 2048 cols: 128 ntiles
#define WS3_FLOATS (WS_FLOATS + NPACK + NPACKC + NPACKP)   // packs take e ushorts*2 = e floats each

typedef __attribute__((ext_vector_type(8))) short bf16x8;
typedef __attribute__((ext_vector_type(4))) float f32x4;

__device__ __forceinline__ float4 f4fma(float a, float4 w, float4 c) {
    c.x = fmaf(a, w.x, c.x); c.y = fmaf(a, w.y, c.y);
    c.z = fmaf(a, w.z, c.z); c.w = fmaf(a, w.w, c.w);
    return c;
}

__device__ __forceinline__ float4 tanh4b(float4 a, float b) {
    return make_float4(tanhf(a.x + b), tanhf(a.y + b), tanhf(a.z + b), tanhf(a.w + b));
}

// fp32 -> bf16 hi (RNE) + bf16 lo (RNE of remainder)
__device__ __forceinline__ void bf16split(float x, unsigned short& hi, unsigned short& lo) {
    unsigned b = __float_as_uint(x);
    unsigned h = (b + 0x7FFFu + ((b >> 16) & 1u)) >> 16;
    hi = (unsigned short)h;
    float r = x - __uint_as_float(h << 16);
    unsigned rb = __float_as_uint(r);
    lo = (unsigned short)((rb + 0x7FFFu + ((rb >> 16) & 1u)) >> 16);
}

// ---------------- merged transpose + bf16 fragment packing ----------------
__global__ __launch_bounds__(1024) void k_transpose_all(
    float* __restrict__ ws,
    const float* __restrict__ W0a, const float* __restrict__ W0b, const float* __restrict__ W0c,
    const float* __restrict__ W0d, const float* __restrict__ W0e,
    const float* __restrict__ W1a, const float* __restrict__ W1b, const float* __restrict__ W1c,
    const float* __restrict__ W1d, const float* __restrict__ W1e,
    const float* __restrict__ W2p, const float* __restrict__ W2c, const float* __restrict__ W2b)
{
    int t = blockIdx.x * blockDim.x + threadIdx.x;
    if (t >= 2236416) {
        int e = t - 2236416;
        unsigned short* PK = (unsigned short*)(ws + WS_FLOATS);
        if (e < NPACK) {
            // W2B fragment: e = ((tt*8 + c)*64 + lane)*8 + j
            int j = e & 7, lane = (e >> 3) & 63, c = (e >> 9) & 7, tt = e >> 12;
            int k = c * 32 + ((lane >> 4) & 3) * 8 + j;
            int n = tt * 16 + (lane & 15);
            unsigned short hi, lo;
            bf16split(W2b[n * 256 + k], hi, lo);
            PK[e] = hi; PK[NPACK + e] = lo;
        } else if (e < NPACK + NPACKC) {
            int e2 = e - NPACK;
            unsigned short* PC = PK + 2 * NPACK;
            int j = e2 & 7, lane = (e2 >> 3) & 63, c = (e2 >> 9) & 7, tt = e2 >> 12;  // tt<64
            int k = c * 32 + ((lane >> 4) & 3) * 8 + j;
            int n = tt * 16 + (lane & 15);
            unsigned short hi, lo;
            bf16split(W2c[n * 256 + k], hi, lo);
            PC[e2] = hi; PC[NPACKC + e2] = lo;
        } else if (e < NPACK + NPACKC + NPACKP) {
            int e2 = e - NPACK - NPACKC;
            unsigned short* PP = PK + 2 * NPACK + 2 * NPACKC;
            int j = e2 & 7, lane = (e2 >> 3) & 63, c = (e2 >> 9) & 7, tt = e2 >> 12;  // tt<128
            int k = c * 32 + ((lane >> 4) & 3) * 8 + j;
            int n = tt * 16 + (lane & 15);
            float v = (n < 2016) ? W2p[n * 256 + k] : 0.f;
            unsigned short hi, lo;
            bf16split(v, hi, lo);
            PP[e2] = hi; PP[NPACKP + e2] = lo;
        }
        return;
    }
    const float* in;
    int o, R, C;
    float* out;
    if (t < 81920) {
        int m = t >> 14; o = t & 16383;
        const float* W0s[5] = {W0a, W0b, W0c, W0d, W0e};
        in = W0s[m]; out = ws + OFF_W0T + m * 16384; R = 256; C = 64;
    } else if (t < 409600) {
        int t2 = t - 81920;
        int m = t2 >> 16; o = t2 & 65535;
        const float* W1s[5] = {W1a, W1b, W1c, W1d, W1e};
        in = W1s[m]; out = ws + OFF_W1T + m * 65536; R = 256; C = 256;
    } else if (t < 925696) {
        o = t - 409600; in = W2p; out = ws + OFF_W2PT; R = 2016; C = 256;
    } else if (t < 1187840) {
        o = t - 925696; in = W2c; out = ws + OFF_W2CT; R = 1024; C = 256;
    } else {
        o = t - 1187840; in = W2b; out = ws + OFF_W2BT; R = 4096; C = 256;
    }
    int c = o / R, r = o - c * R;
    out[o] = in[r * C + c];
}

// ---------------- K1: dE, dS ----------------
__global__ __launch_bounds__(1024, 2) void k1_grads(
    const float* __restrict__ y, const float* __restrict__ ws,
    const float* __restrict__ W0E, const float* __restrict__ b0E,
    const float* __restrict__ W1E, const float* __restrict__ b1E,
    const float* __restrict__ w2E,
    const float* __restrict__ W0S, const float* __restrict__ b0S,
    const float* __restrict__ W1S, const float* __restrict__ b1S,
    const float* __restrict__ w2S,
    float* __restrict__ odE, float* __restrict__ odS)
{
    __shared__ float syT[1024];
    __shared__ float sH1T[4096];
    __shared__ float sGT[4096];
    __shared__ float sG1T[4096];

    const int tid = threadIdx.x;
    const int sbase = blockIdx.x * SB;
    {
        int s = tid >> 6, i = tid & 63;
        syT[i * 16 + s] = y[sbase * 64 + tid];
    }
    __syncthreads();

    const int c = tid & 255, sg = tid >> 8, s4 = sg * 4;

    for (int m = 0; m < 2; ++m) {
        const float* w0t = ws + OFF_W0T + m * 16384;
        const float* w1t = ws + OFF_W1T + m * 65536;
        const float* W0 = m ? W0S : W0E;
        const float* W1 = m ? W1S : W1E;
        const float* b0 = m ? b0S : b0E;
        const float* b1 = m ? b1S : b1E;
        const float* w2 = m ? w2S : w2E;
        float* outg = m ? odS : odE;

        {
            float4 acc = {0, 0, 0, 0};
            #pragma unroll 4
            for (int k = 0; k < 64; ++k)
                acc = f4fma(w0t[k * 256 + c], *(const float4*)(syT + k * 16 + s4), acc);
            *(float4*)(sH1T + c * 16 + s4) = tanh4b(acc, b0[c]);
        }
        __syncthreads();
        {
            float4 acc = {0, 0, 0, 0};
            #pragma unroll 4
            for (int k = 0; k < 256; ++k)
                acc = f4fma(w1t[k * 256 + c], *(const float4*)(sH1T + k * 16 + s4), acc);
            float b = b1[c], wv = w2[c];
            float4 h2 = make_float4(tanhf(acc.x + b), tanhf(acc.y + b),
                                    tanhf(acc.z + b), tanhf(acc.w + b));
            *(float4*)(sGT + c * 16 + s4) = make_float4(
                (1.f - h2.x * h2.x) * wv, (1.f - h2.y * h2.y) * wv,
                (1.f - h2.z * h2.z) * wv, (1.f - h2.w * h2.w) * wv);
        }
        __syncthreads();
        {
            float4 acc = {0, 0, 0, 0};
            #pragma unroll 4
            for (int j = 0; j < 256; ++j)
                acc = f4fma(W1[j * 256 + c], *(const float4*)(sGT + j * 16 + s4), acc);
            float4 h1 = *(const float4*)(sH1T + c * 16 + s4);
            *(float4*)(sG1T + c * 16 + s4) = make_float4(
                (1.f - h1.x * h1.x) * acc.x, (1.f - h1.y * h1.y) * acc.y,
                (1.f - h1.z * h1.z) * acc.z, (1.f - h1.w * h1.w) * acc.w);
        }
        __syncthreads();
        {
            int s = tid >> 6, i = tid & 63;
            float acc = 0.f;
            #pragma unroll 8
            for (int k = 0; k < 256; ++k)
                acc = fmaf(sG1T[k * 16 + s], W0[k * 64 + i], acc);
            outg[sbase * 64 + tid] = acc;
        }
        __syncthreads();
    }
}

// ---------------- K2 v1: proven R12 version (fallback) ----------------
__global__ __launch_bounds__(1024, 4) void k2_poisson_v1(
    const float* __restrict__ y, const float* __restrict__ ws,
    const float* __restrict__ b0P, const float* __restrict__ b1P,
    float* __restrict__ dout)
{
    extern __shared__ float smem[];
    float* sa   = smem;
    float* sH2T = smem + 32384;
    float* sdE  = sH2T + 4096;
    float* sdS  = sdE + 1024;
    float* sH1T = sa;
    float* syT  = sa + 4096;

    const int tid = threadIdx.x;
    const int sbase = blockIdx.x * SB;
    const float* gdE = ws + OFF_DE;
    const float* gdS = ws + OFF_DS;

    {
        int s = tid >> 6, i = tid & 63;
        syT[i * 16 + s] = y[sbase * 64 + tid];
        sdE[tid] = gdE[sbase * 64 + tid];
        sdS[tid] = gdS[sbase * 64 + tid];
    }
    __syncthreads();

    const int c  = tid & 255;
    const int sg = tid >> 8;
    const int s4 = sg * 4;

    {
        const float* w0t = ws + OFF_W0T + 2 * 16384;
        float4 acc = {0, 0, 0, 0};
        #pragma unroll 4
        for (int k = 0; k < 64; ++k) {
            float w = w0t[k * 256 + c];
            float4 yv = *(const float4*)(syT + k * 16 + s4);
            acc = f4fma(w, yv, acc);
        }
        *(float4*)(sH1T + c * 16 + s4) = tanh4b(acc, b0P[c]);
    }
    __syncthreads();

    {
        const float* w1t = ws + OFF_W1T + 2 * 65536;
        float4 acc = {0, 0, 0, 0};
        #pragma unroll 4
        for (int k = 0; k < 256; ++k) {
            float w = w1t[k * 256 + c];
            float4 hv = *(const float4*)(sH1T + k * 16 + s4);
            acc = f4fma(w, hv, acc);
        }
        *(float4*)(sH2T + c * 16 + s4) = tanh4b(acc, b1P[c]);
    }
    __syncthreads();

    {
        const int cn = tid;
        if (cn < 1008) {
            const float* wp = ws + OFF_W2PT + 2 * cn;
            float a0[16], a1[16];
            #pragma unroll
            for (int s = 0; s < 16; ++s) { a0[s] = 0.f; a1[s] = 0.f; }
            #pragma unroll 2
            for (int k = 0; k < 256; ++k) {
                float4 h0 = *(const float4*)(sH2T + k * 16);
                float4 h1 = *(const float4*)(sH2T + k * 16 + 4);
                float4 h2 = *(const float4*)(sH2T + k * 16 + 8);
                float4 h3 = *(const float4*)(sH2T + k * 16 + 12);
                float2 w = *(const float2*)(wp + k * 2016);
                float hs[16] = {h0.x, h0.y, h0.z, h0.w, h1.x, h1.y, h1.z, h1.w,
                                h2.x, h2.y, h2.z, h2.w, h3.x, h3.y, h3.z, h3.w};
                #pragma unroll
                for (int s = 0; s < 16; ++s) {
                    a0[s] = fmaf(hs[s], w.x, a0[s]);
                    a1[s] = fmaf(hs[s], w.y, a1[s]);
                }
            }
            #pragma unroll
            for (int s = 0; s < 16; ++s) {
                sa[s * 2024 + 2 * cn]     = a0[s];
                sa[s * 2024 + 2 * cn + 1] = a1[s];
            }
        }
    }
    __syncthreads();

    {
        const int s = tid >> 6;
        const int i = tid & 63;
        const int ib = i * (i - 1) / 2;
        const float* ap = sa + s * 2024;
        const float* dep = sdE + s * 64;
        const float* dsp = sdS + s * 64;

        float adE = 0.f, adS = 0.f;
        int trij = 0;
        #pragma unroll 4
        for (int j = 0; j < 64; ++j) {
            int t = (j < i) ? (ib + j) : (trij + i);
            float sel = (j < i) ? 1.f : ((j == i) ? 0.f : -1.f);
            float cc = sel * ap[t];
            adE = fmaf(cc, dep[j], adE);
            adS = fmaf(cc, dsp[j], adS);
            trij += j;
        }

        float de = dep[i], dsv = dsp[i];
        float p0 = de * adS;
        float p1 = de * dsv;
        float p2 = dsv * dsv;
        #pragma unroll
        for (int m = 1; m <= 32; m <<= 1) {
            p0 += __shfl_xor(p0, m);
            p1 += __shfl_xor(p1, m);
            p2 += __shfl_xor(p2, m);
        }
        float inv = 1.f / p2;
        dout[sbase * 64 + tid] = adE + (p0 * dsv - p1 * adS) * inv;
    }
}

// ---------------- K2 mf: a-GEMM via split-bf16 MFMA ----------------
__global__ __launch_bounds__(1024, 4) void k2_poisson_mf(
    const float* __restrict__ y, const float* __restrict__ ws,
    const float* __restrict__ b0P, const float* __restrict__ b1P,
    float* __restrict__ dout)
{
    extern __shared__ float smem[];
    float* sa   = smem;                                   // 16 x 2024
    unsigned short* sAh = (unsigned short*)(smem + 32384); // A-pack hi (4096 ushorts)
    unsigned short* sAl = (unsigned short*)(smem + 34432); // A-pack lo
    float* sdE  = smem + 36480;
    float* sdS  = sdE + 1024;
    float* sH1T = sa;            // alias
    float* syT  = sa + 4096;     // alias

    const int tid = threadIdx.x;
    const int sbase = blockIdx.x * SB;
    const float* gdE = ws + OFF_DE;
    const float* gdS = ws + OFF_DS;

    {
        int s = tid >> 6, i = tid & 63;
        syT[i * 16 + s] = y[sbase * 64 + tid];
        sdE[tid] = gdE[sbase * 64 + tid];
        sdS[tid] = gdS[sbase * 64 + tid];
    }
    __syncthreads();

    const int c  = tid & 255;
    const int sg = tid >> 8;
    const int s4 = sg * 4;

    // P1
    {
        const float* w0t = ws + OFF_W0T + 2 * 16384;
        float4 acc = {0, 0, 0, 0};
        #pragma unroll 4
        for (int k = 0; k < 64; ++k) {
            float w = w0t[k * 256 + c];
            float4 yv = *(const float4*)(syT + k * 16 + s4);
            acc = f4fma(w, yv, acc);
        }
        *(float4*)(sH1T + c * 16 + s4) = tanh4b(acc, b0P[c]);
    }
    __syncthreads();

    // P2: H2 -> packed bf16 hi/lo A-fragments (verified layout)
    {
        const float* w1t = ws + OFF_W1T + 2 * 65536;
        float4 acc = {0, 0, 0, 0};
        #pragma unroll 4
        for (int k = 0; k < 256; ++k) {
            float w = w1t[k * 256 + c];
            float4 hv = *(const float4*)(sH1T + k * 16 + s4);
            acc = f4fma(w, hv, acc);
        }
        float4 h2 = tanh4b(acc, b1P[c]);
        const int cblk = c >> 5, j0 = c & 7;
        const int lbase = ((c >> 3) & 3) << 4;
        float va[4] = {h2.x, h2.y, h2.z, h2.w};
        #pragma unroll
        for (int q = 0; q < 4; ++q) {
            int lb = ((s4 + q) & 15) | lbase;
            int base = (cblk * 64 + lb) * 8 + j0;
            unsigned short hi, lo;
            bf16split(va[q], hi, lo);
            sAh[base] = hi;
            sAl[base] = lo;
        }
    }
    __syncthreads();   // syT/H1T dead; sa writable

    // P3: a-GEMM via MFMA. 128 n-tiles (2048 padded cols), wave wv owns 8.
    {
        const unsigned short* PP = (const unsigned short*)(ws + WS_FLOATS) + 2 * NPACK + 2 * NPACKC;
        const unsigned short* PH = PP;
        const unsigned short* PL = PP + NPACKP;
        const int wv = tid >> 6, l = tid & 63;
        f32x4 accp[8];
        #pragma unroll
        for (int t0 = 0; t0 < 8; ++t0) accp[t0] = (f32x4){0.f, 0.f, 0.f, 0.f};
        #pragma unroll 1
        for (int cb = 0; cb < 8; ++cb) {
            bf16x8 Ah = *(const bf16x8*)(sAh + (cb * 64 + l) * 8);
            bf16x8 Al = *(const bf16x8*)(sAl + (cb * 64 + l) * 8);
            #pragma unroll
            for (int t0 = 0; t0 < 8; ++t0) {
                int t = 8 * wv + t0;
                const unsigned short* bh = PH + ((t * 8 + cb) * 64 + l) * 8;
                const unsigned short* bl = PL + ((t * 8 + cb) * 64 + l) * 8;
                bf16x8 Bh = *(const bf16x8*)(bh);
                bf16x8 Bl = *(const bf16x8*)(bl);
                accp[t0] = __builtin_amdgcn_mfma_f32_16x16x32_bf16(Ah, Bh, accp[t0], 0, 0, 0);
                accp[t0] = __builtin_amdgcn_mfma_f32_16x16x32_bf16(Al, Bh, accp[t0], 0, 0, 0);
                accp[t0] = __builtin_amdgcn_mfma_f32_16x16x32_bf16(Ah, Bl, accp[t0], 0, 0, 0);
            }
        }
        #pragma unroll
        for (int t0 = 0; t0 < 8; ++t0) {
            int n = (8 * wv + t0) * 16 + (l & 15);
            if (n < 2016) {
                #pragma unroll
                for (int r = 0; r < 4; ++r)
                    sa[((l >> 4) * 4 + r) * 2024 + n] = accp[t0][r];
            }
        }
    }
    __syncthreads();

    // P4: gather
    {
        const int s = tid >> 6;
        const int i = tid & 63;
        const int ib = i * (i - 1) / 2;
        const float* ap = sa + s * 2024;
        const float* dep = sdE + s * 64;
        const float* dsp = sdS + s * 64;

        float adE = 0.f, adS = 0.f;
        int trij = 0;
        #pragma unroll 4
        for (int j = 0; j < 64; ++j) {
            int t = (j < i) ? (ib + j) : (trij + i);
            float sel = (j < i) ? 1.f : ((j == i) ? 0.f : -1.f);
            float cc = sel * ap[t];
            adE = fmaf(cc, dep[j], adE);
            adS = fmaf(cc, dsp[j], adS);
            trij += j;
        }

        float de = dep[i], dsv = dsp[i];
        float p0 = de * adS;
        float p1 = de * dsv;
        float p2 = dsv * dsv;
        #pragma unroll
        for (int m = 1; m <= 32; m <<= 1) {
            p0 += __shfl_xor(p0, m);
            p1 += __shfl_xor(p1, m);
            p2 += __shfl_xor(p2, m);
        }
        float inv = 1.f / p2;
        dout[sbase * 64 + tid] = adE + (p0 * dsv - p1 * adS) * inv;
    }
}

// ---------------- K3 mf2: Bm AND C via split-bf16 MFMA ----------------
__global__ __launch_bounds__(1024, 4) void k3_friction_mf2(
    const float* __restrict__ y, const float* __restrict__ ws,
    const float* __restrict__ b0C, const float* __restrict__ b1C,
    const float* __restrict__ b0B, const float* __restrict__ b1B,
    float* __restrict__ dout)
{
    extern __shared__ float smem[];
    float* sYT = smem;                                      // [64][16]
    unsigned short* sAhc = (unsigned short*)(smem + 1024);  // fC A-pack hi
    unsigned short* sAlc = (unsigned short*)(smem + 3072);  // fC A-pack lo
    unsigned short* sAhb = (unsigned short*)(smem + 5120);  // fB A-pack hi
    unsigned short* sAlb = (unsigned short*)(smem + 7168);  // fB A-pack lo
    float* sATc = smem + 9216;                              // fC H1 (dead after L1)
    float* sATb = smem + 13312;                             // fB H1 (dead after L1)
    float* sC   = smem + 9216;                              // [16][1089] overlaps H1
    float* sdE  = smem + 26640;
    float* sdS  = sdE + 1024;
    float* sBdE = sdS + 1024;
    float* sBdS = sBdE + 1024;
    float* sv   = sBdS + 1024;
    float* sq   = sv + 1024;
    float* sScal = sq + 1024;
    float* sr   = sScal + 64;

    const int tid = threadIdx.x;
    const int sbase = blockIdx.x * SB;
    const float* gdE = ws + OFF_DE;
    const float* gdS = ws + OFF_DS;

    {
        int s = tid >> 6, i = tid & 63;
        sYT[i * 16 + s] = y[sbase * 64 + tid];
        sdE[tid] = gdE[sbase * 64 + tid];
        sdS[tid] = gdS[sbase * 64 + tid];
    }
    if (tid < 64) sScal[tid] = 0.f;
    __syncthreads();

    {
        int s = tid >> 6;
        float de = sdE[tid];
        unsafeAtomicAdd(&sScal[s * 4 + 0], de * de);
        unsafeAtomicAdd(&sScal[s * 4 + 1], de * sdS[tid]);
    }

    const int net = tid >> 9;
    const int t9  = tid & 511;
    const int sgf = t9 >> 7;
    const int s4f = sgf * 4;
    const int cp  = t9 & 127;
    const int c0 = 2 * cp, c1 = c0 + 1;
    const float* w0t = ws + OFF_W0T + (3 + net) * 16384;
    const float* w1t = ws + OFF_W1T + (3 + net) * 65536;
    const float* b0v = net ? b0B : b0C;
    const float* b1v = net ? b1B : b1C;
    float* sH1 = net ? sATb : sATc;
    unsigned short* pH = net ? sAhb : sAhc;
    unsigned short* pL = net ? sAlb : sAlc;

    // L0 (both nets)
    {
        float4 a0 = {0, 0, 0, 0}, a1 = {0, 0, 0, 0};
        #pragma unroll 4
        for (int k = 0; k < 64; ++k) {
            float4 h = *(const float4*)(sYT + k * 16 + s4f);
            float2 w = *(const float2*)(w0t + k * 256 + c0);
            a0 = f4fma(w.x, h, a0);
            a1 = f4fma(w.y, h, a1);
        }
        *(float4*)(sH1 + c0 * 16 + s4f) = tanh4b(a0, b0v[c0]);
        *(float4*)(sH1 + c1 * 16 + s4f) = tanh4b(a1, b0v[c1]);
    }
    __syncthreads();

    // L1 (both nets): H2 -> packed bf16 hi/lo A-fragments
    {
        float4 a0 = {0, 0, 0, 0}, a1 = {0, 0, 0, 0};
        #pragma unroll 4
        for (int k = 0; k < 256; ++k) {
            float4 h = *(const float4*)(sH1 + k * 16 + s4f);
            float2 w = *(const float2*)(w1t + k * 256 + c0);
            a0 = f4fma(w.x, h, a0);
            a1 = f4fma(w.y, h, a1);
        }
        float4 h2a = tanh4b(a0, b1v[c0]);
        float4 h2b = tanh4b(a1, b1v[c1]);
        const int cblk = c0 >> 5, j0 = c0 & 7;
        const int lbase = ((c0 >> 3) & 3) << 4;
        float va[2][4] = {{h2a.x, h2a.y, h2a.z, h2a.w}, {h2b.x, h2b.y, h2b.z, h2b.w}};
        #pragma unroll
        for (int q = 0; q < 4; ++q) {
            int lb = ((s4f + q) & 15) | lbase;
            int base = (cblk * 64 + lb) * 8 + j0;
            unsigned short hi0, lo0, hi1, lo1;
            bf16split(va[0][q], hi0, lo0);
            bf16split(va[1][q], hi1, lo1);
            pH[base] = hi0; pH[base + 1] = hi1;
            pL[base] = lo0; pL[base + 1] = lo1;
        }
    }
    __syncthreads();   // H1 tiles dead; sC writable

    const int wv = tid >> 6;          // wave 0..15
    const int l  = tid & 63;          // lane

    // ===== C head via MFMA: wave owns n-tiles 4wv..4wv+3 (64 tiles = 1024 cols) =====
    {
        const unsigned short* PC = (const unsigned short*)(ws + WS_FLOATS) + 2 * NPACK;
        const unsigned short* CH = PC;
        const unsigned short* CL = PC + NPACKC;
        f32x4 accc[4];
        #pragma unroll
        for (int t0 = 0; t0 < 4; ++t0) accc[t0] = (f32x4){0.f, 0.f, 0.f, 0.f};
        #pragma unroll 1
        for (int cb = 0; cb < 8; ++cb) {
            bf16x8 Ah = *(const bf16x8*)(sAhc + (cb * 64 + l) * 8);
            bf16x8 Al = *(const bf16x8*)(sAlc + (cb * 64 + l) * 8);
            #pragma unroll
            for (int t0 = 0; t0 < 4; ++t0) {
                int t = 4 * wv + t0;
                bf16x8 Bh = *(const bf16x8*)(CH + ((t * 8 + cb) * 64 + l) * 8);
                bf16x8 Bl = *(const bf16x8*)(CL + ((t * 8 + cb) * 64 + l) * 8);
                accc[t0] = __builtin_amdgcn_mfma_f32_16x16x32_bf16(Ah, Bh, accc[t0], 0, 0, 0);
                accc[t0] = __builtin_amdgcn_mfma_f32_16x16x32_bf16(Al, Bh, accc[t0], 0, 0, 0);
                accc[t0] = __builtin_amdgcn_mfma_f32_16x16x32_bf16(Ah, Bl, accc[t0], 0, 0, 0);
            }
        }
        // n = t*16 + (l&15) -> kC = t, mC = l&15; s = (l>>4)*4 + r
        #pragma unroll
        for (int t0 = 0; t0 < 4; ++t0) {
            int t = 4 * wv + t0;
            #pragma unroll
            for (int r = 0; r < 4; ++r)
                sC[((l >> 4) * 4 + r) * 1089 + t * 17 + (l & 15)] = accc[t0][r];
        }
    }

    // ===== Bm via MFMA: wave owns n-tiles 16wv..16wv+15 =====
    f32x4 acc[16];
    #pragma unroll
    for (int t0 = 0; t0 < 16; ++t0) acc[t0] = (f32x4){0.f, 0.f, 0.f, 0.f};
    {
        const unsigned short* BH = (const unsigned short*)(ws + WS_FLOATS);
        const unsigned short* BL = BH + NPACK;
        #pragma unroll 1
        for (int cb = 0; cb < 8; ++cb) {
            bf16x8 Ah = *(const bf16x8*)(sAhb + (cb * 64 + l) * 8);
            bf16x8 Al = *(const bf16x8*)(sAlb + (cb * 64 + l) * 8);
            const unsigned short* bh = BH + ((wv * 16 * 8 + cb) * 64 + l) * 8;
            const unsigned short* bl = BL + ((wv * 16 * 8 + cb) * 64 + l) * 8;
            #pragma unroll
            for (int t0 = 0; t0 < 16; ++t0) {
                bf16x8 Bh = *(const bf16x8*)(bh + t0 * 4096);
                bf16x8 Bl = *(const bf16x8*)(bl + t0 * 4096);
                acc[t0] = __builtin_amdgcn_mfma_f32_16x16x32_bf16(Ah, Bh, acc[t0], 0, 0, 0);
                acc[t0] = __builtin_amdgcn_mfma_f32_16x16x32_bf16(Al, Bh, acc[t0], 0, 0, 0);
                acc[t0] = __builtin_amdgcn_mfma_f32_16x16x32_bf16(Ah, Bl, acc[t0], 0, 0, 0);
            }
        }
    }
    // dots: lane l, reg r -> sample s=(l>>4)*4+r, n=16t+(l&15), i=n&63, k'=4wv+g
    #pragma unroll
    for (int g = 0; g < 4; ++g) {
        float pd[4] = {0, 0, 0, 0}, ps[4] = {0, 0, 0, 0};
        #pragma unroll
        for (int tt = 0; tt < 4; ++tt) {
            int i = 16 * tt + (l & 15);
            #pragma unroll
            for (int r = 0; r < 4; ++r) {
                int s = (l >> 4) * 4 + r;
                float d = acc[g * 4 + tt][r];
                pd[r] = fmaf(d, sdE[s * 64 + i], pd[r]);
                ps[r] = fmaf(d, sdS[s * 64 + i], ps[r]);
            }
        }
        #pragma unroll
        for (int m = 1; m <= 8; m <<= 1) {
            #pragma unroll
            for (int r = 0; r < 4; ++r) {
                pd[r] += __shfl_xor(pd[r], m);
                ps[r] += __shfl_xor(ps[r], m);
            }
        }
        if ((l & 15) == 0) {
            int kpr = 4 * wv + g;
            #pragma unroll
            for (int r = 0; r < 4; ++r) {
                int s = (l >> 4) * 4 + r;
                sBdE[s * 64 + kpr] = pd[r];
                sBdS[s * 64 + kpr] = ps[r];
            }
        }
    }
    __syncthreads();

    {
        int s = tid >> 6;
        float beta = sScal[s * 4 + 1] / sScal[s * 4 + 0];
        sv[tid] = sBdS[tid] - beta * sBdE[tid];
    }
    __syncthreads();
    {
        int s = tid >> 6;
        unsafeAtomicAdd(&sScal[s * 4 + 2], sdE[tid] * sv[tid]);
    }
    __syncthreads();

    // pass2: q = Bm @ v from acc registers
    #pragma unroll
    for (int g = 0; g < 4; ++g) {
        float pq[4] = {0, 0, 0, 0};
        #pragma unroll
        for (int tt = 0; tt < 4; ++tt) {
            int i = 16 * tt + (l & 15);
            #pragma unroll
            for (int r = 0; r < 4; ++r) {
                int s = (l >> 4) * 4 + r;
                pq[r] = fmaf(acc[g * 4 + tt][r], sv[s * 64 + i], pq[r]);
            }
        }
        #pragma unroll
        for (int m = 1; m <= 8; m <<= 1) {
            #pragma unroll
            for (int r = 0; r < 4; ++r) pq[r] += __shfl_xor(pq[r], m);
        }
        if ((l & 15) == 0) {
            int kpr = 4 * wv + g;
            #pragma unroll
            for (int r = 0; r < 4; ++r) sq[((l >> 4) * 4 + r) * 64 + kpr] = pq[r];
        }
    }
    __syncthreads();

    if (tid < 256) {
        int s = tid >> 4, m = tid & 15;
        float gamma = sScal[s * 4 + 2] / sScal[s * 4 + 0];
        float r = 0.f;
        #pragma unroll 4
        for (int k = 0; k < 64; ++k) {
            float wvv = sq[s * 64 + k] - gamma * sBdE[s * 64 + k];
            r = fmaf(sC[s * 1089 + k * 17 + m], wvv, r);
        }
        sr[s * 16 + m] = r;
    }
    __syncthreads();
    {
        int s = tid >> 6, k = tid & 63;
        float o = 0.f;
        #pragma unroll
        for (int m2 = 0; m2 < 16; ++m2)
            o = fmaf(sC[s * 1089 + k * 17 + m2], sr[s * 16 + m2], o);
        int gi = sbase * 64 + tid;
        dout[gi] = dout[gi] + o;
    }
}

// ---------------- K3 v1: proven R11 fp32 version (fallback) ----------------
__global__ __launch_bounds__(1024, 4) void k3_friction_v1(
    const float* __restrict__ y, const float* __restrict__ ws,
    const float* __restrict__ b0C, const float* __restrict__ b1C,
    const float* __restrict__ b0B, const float* __restrict__ b1B,
    float* __restrict__ dout)
{
    extern __shared__ float smem[];
    float* sYT  = smem;
    float* sBTc = smem + 1024;
    float* sBTb = smem + 5120;
    float* sATc = smem + 9216;
    float* sATb = smem + 13312;
    float* sC   = smem + 9216;
    float* sdE  = smem + 26640;
    float* sdS  = sdE + 1024;
    float* sBdE = sdS + 1024;
    float* sBdS = sBdE + 1024;
    float* sv   = sBdS + 1024;
    float* sq   = sv + 1024;
    float* sScal = sq + 1024;
    float* sr   = sScal + 64;

    const int tid = threadIdx.x;
    const int sbase = blockIdx.x * SB;
    const float* gdE = ws + OFF_DE;
    const float* gdS = ws + OFF_DS;

    {
        int s = tid >> 6, i = tid & 63;
        sYT[i * 16 + s] = y[sbase * 64 + tid];
        sdE[tid] = gdE[sbase * 64 + tid];
        sdS[tid] = gdS[sbase * 64 + tid];
    }
    if (tid < 64) sScal[tid] = 0.f;
    __syncthreads();

    {
        int s = tid >> 6;
        float de = sdE[tid];
        unsafeAtomicAdd(&sScal[s * 4 + 0], de * de);
        unsafeAtomicAdd(&sScal[s * 4 + 1], de * sdS[tid]);
    }

    const int net = tid >> 9;
    const int t9  = tid & 511;
    const int sgf = t9 >> 7;
    const int s4f = sgf * 4;
    const int cp  = t9 & 127;
    const int c0 = 2 * cp, c1 = c0 + 1;
    const float* w0t = ws + OFF_W0T + (3 + net) * 16384;
    const float* w1t = ws + OFF_W1T + (3 + net) * 65536;
    const float* b0v = net ? b0B : b0C;
    const float* b1v = net ? b1B : b1C;
    float* sH1 = net ? sATb : sATc;
    float* sH2 = net ? sBTb : sBTc;

    {
        float4 a0 = {0, 0, 0, 0}, a1 = {0, 0, 0, 0};
        #pragma unroll 4
        for (int k = 0; k < 64; ++k) {
            float4 h = *(const float4*)(sYT + k * 16 + s4f);
            float2 w = *(const float2*)(w0t + k * 256 + c0);
            a0 = f4fma(w.x, h, a0);
            a1 = f4fma(w.y, h, a1);
        }
        *(float4*)(sH1 + c0 * 16 + s4f) = tanh4b(a0, b0v[c0]);
        *(float4*)(sH1 + c1 * 16 + s4f) = tanh4b(a1, b0v[c1]);
    }
    __syncthreads();

    {
        float4 a0 = {0, 0, 0, 0}, a1 = {0, 0, 0, 0};
        #pragma unroll 4
        for (int k = 0; k < 256; ++k) {
            float4 h = *(const float4*)(sH1 + k * 16 + s4f);
            float2 w = *(const float2*)(w1t + k * 256 + c0);
            a0 = f4fma(w.x, h, a0);
            a1 = f4fma(w.y, h, a1);
        }
        *(float4*)(sH2 + c0 * 16 + s4f) = tanh4b(a0, b1v[c0]);
        *(float4*)(sH2 + c1 * 16 + s4f) = tanh4b(a1, b1v[c1]);
    }
    __syncthreads();

    {
        const float* w2ct = ws + OFF_W2CT;
        float acc[16];
        #pragma unroll
        for (int s = 0; s < 16; ++s) acc[s] = 0.f;
        #pragma unroll 2
        for (int k = 0; k < 256; ++k) {
            float w = w2ct[k * 1024 + tid];
            float4 h0 = *(const float4*)(sBTc + k * 16);
            float4 h1 = *(const float4*)(sBTc + k * 16 + 4);
            float4 h2 = *(const float4*)(sBTc + k * 16 + 8);
            float4 h3 = *(const float4*)(sBTc + k * 16 + 12);
            float hs[16] = {h0.x, h0.y, h0.z, h0.w, h1.x, h1.y, h1.z, h1.w,
                            h2.x, h2.y, h2.z, h2.w, h3.x, h3.y, h3.z, h3.w};
            #pragma unroll
            for (int s = 0; s < 16; ++s) acc[s] = fmaf(hs[s], w, acc[s]);
        }
        const int kC = tid >> 4, mC = tid & 15;
        #pragma unroll
        for (int s = 0; s < 16; ++s) sC[s * 1089 + kC * 17 + mC] = acc[s];
    }
    __syncthreads();

    const int kp = tid >> 4;
    const int i0 = 4 * (tid & 15);
    float4 bm[16];
    #pragma unroll
    for (int s = 0; s < 16; ++s) bm[s] = make_float4(0.f, 0.f, 0.f, 0.f);
    {
        const float* wb = ws + OFF_W2BT + 4 * tid;
        float4 w = *(const float4*)(wb);
        float4 h0 = *(const float4*)(sBTb);
        float4 h1 = *(const float4*)(sBTb + 4);
        float4 h2 = *(const float4*)(sBTb + 8);
        float4 h3 = *(const float4*)(sBTb + 12);
        #pragma unroll 2
        for (int k = 0; k < 256; ++k) {
            float4 wn = *(const float4*)(wb + (k + 1) * 4096);
            float4 g0 = *(const float4*)(sBTb + (k + 1) * 16);
            float4 g1 = *(const float4*)(sBTb + (k + 1) * 16 + 4);
            float4 g2 = *(const float4*)(sBTb + (k + 1) * 16 + 8);
            float4 g3 = *(const float4*)(sBTb + (k + 1) * 16 + 12);
            float hs[16] = {h0.x, h0.y, h0.z, h0.w, h1.x, h1.y, h1.z, h1.w,
                            h2.x, h2.y, h2.z, h2.w, h3.x, h3.y, h3.z, h3.w};
            #pragma unroll
            for (int s = 0; s < 16; ++s) {
                bm[s].x = fmaf(hs[s], w.x, bm[s].x);
                bm[s].y = fmaf(hs[s], w.y, bm[s].y);
                bm[s].z = fmaf(hs[s], w.z, bm[s].z);
                bm[s].w = fmaf(hs[s], w.w, bm[s].w);
            }
            w = wn; h0 = g0; h1 = g1; h2 = g2; h3 = g3;
        }
    }
    #pragma unroll
    for (int s = 0; s < 16; ++s) {
        float4 de = *(const float4*)(sdE + s * 64 + i0);
        float4 dsv = *(const float4*)(sdS + s * 64 + i0);
        float pd = fmaf(bm[s].w, de.w, fmaf(bm[s].z, de.z, fmaf(bm[s].y, de.y, bm[s].x * de.x)));
        float ps = fmaf(bm[s].w, dsv.w, fmaf(bm[s].z, dsv.z, fmaf(bm[s].y, dsv.y, bm[s].x * dsv.x)));
        pd += __shfl_xor(pd, 1); ps += __shfl_xor(ps, 1);
        pd += __shfl_xor(pd, 2); ps += __shfl_xor(ps, 2);
        pd += __shfl_xor(pd, 4); ps += __shfl_xor(ps, 4);
        pd += __shfl_xor(pd, 8); ps += __shfl_xor(ps, 8);
        if ((tid & 15) == 0) {
            sBdE[s * 64 + kp] = pd;
            sBdS[s * 64 + kp] = ps;
        }
    }
    __syncthreads();

    {
        int s = tid >> 6;
        float beta = sScal[s * 4 + 1] / sScal[s * 4 + 0];
        sv[tid] = sBdS[tid] - beta * sBdE[tid];
    }
    __syncthreads();
    {
        int s = tid >> 6;
        unsafeAtomicAdd(&sScal[s * 4 + 2], sdE[tid] * sv[tid]);
    }
    __syncthreads();

    #pragma unroll
    for (int s = 0; s < 16; ++s) {
        float4 vv = *(const float4*)(sv + s * 64 + i0);
        float pq = fmaf(bm[s].w, vv.w, fmaf(bm[s].z, vv.z, fmaf(bm[s].y, vv.y, bm[s].x * vv.x)));
        pq += __shfl_xor(pq, 1);
        pq += __shfl_xor(pq, 2);
        pq += __shfl_xor(pq, 4);
        pq += __shfl_xor(pq, 8);
        if ((tid & 15) == 0) sq[s * 64 + kp] = pq;
    }
    __syncthreads();

    if (tid < 256) {
        int s = tid >> 4, m = tid & 15;
        float gamma = sScal[s * 4 + 2] / sScal[s * 4 + 0];
        float r = 0.f;
        #pragma unroll 4
        for (int k = 0; k < 64; ++k) {
            float wv = sq[s * 64 + k] - gamma * sBdE[s * 64 + k];
            r = fmaf(sC[s * 1089 + k * 17 + m], wv, r);
        }
        sr[s * 16 + m] = r;
    }
    __syncthreads();
    {
        int s = tid >> 6, k = tid & 63;
        float o = 0.f;
        #pragma unroll
        for (int m2 = 0; m2 < 16; ++m2)
            o = fmaf(sC[s * 1089 + k * 17 + m2], sr[s * 16 + m2], o);
        int gi = sbase * 64 + tid;
        dout[gi] = dout[gi] + o;
    }
}

extern "C" void kernel_launch(void* const* d_in, const int* in_sizes, int n_in,
                              void* d_out, int out_size, void* d_ws, size_t ws_size,
                              hipStream_t stream)
{
    (void)in_sizes; (void)n_in; (void)out_size;
    const float* y = (const float*)d_in[1];
    const float* W0[5]; const float* b0[5]; const float* W1[5]; const float* b1[5]; const float* W2[5];
    for (int m = 0; m < 5; ++m) {
        int base = 2 + m * 5;
        W0[m] = (const float*)d_in[base + 0];
        b0[m] = (const float*)d_in[base + 1];
        W1[m] = (const float*)d_in[base + 2];
        b1[m] = (const float*)d_in[base + 3];
        W2[m] = (const float*)d_in[base + 4];
    }
    float* ws = (float*)d_ws;
    float* dout = (float*)d_out;
    if (ws_size < (size_t)WS_FLOATS * sizeof(float)) return;
    const bool big_ws = ws_size >= (size_t)WS3_FLOATS * sizeof(float);

    const int ntr = big_ws ? (2236416 + NPACK + NPACKC + NPACKP) : 2236416;
    hipLaunchKernelGGL(k_transpose_all, dim3((ntr + 1023) / 1024), dim3(1024), 0, stream,
                       ws,
                       W0[0], W0[1], W0[2], W0[3], W0[4],
                       W1[0], W1[1], W1[2], W1[3], W1[4],
                       W2[2], W2[3], W2[4]);

    hipLaunchKernelGGL(k1_grads, dim3(1024), dim3(1024), 0, stream,
                       y, ws,
                       W0[0], b0[0], W1[0], b1[0], W2[0],
                       W0[1], b0[1], W1[1], b1[1], W2[1],
                       ws + OFF_DE, ws + OFF_DS);

    const int k2_smem = 154112;
    const int k3_smem = 132416;
    if (big_ws) {
        hipFuncSetAttribute((const void*)k2_poisson_mf, hipFuncAttributeMaxDynamicSharedMemorySize, k2_smem);
        hipLaunchKernelGGL(k2_poisson_mf, dim3(1024), dim3(1024), k2_smem, stream,
                           y, ws, b0[2], b1[2], dout);
        hipFuncSetAttribute((const void*)k3_friction_mf2, hipFuncAttributeMaxDynamicSharedMemorySize, k3_smem);
        hipLaunchKernelGGL(k3_friction_mf2, dim3(1024), dim3(1024), k3_smem, stream,
                           y, ws, b0[3], b1[3], b0[4], b1[4], dout);
    } else {
        hipFuncSetAttribute((const void*)k2_poisson_v1, hipFuncAttributeMaxDynamicSharedMemorySize, k2_smem);
        hipLaunchKernelGGL(k2_poisson_v1, dim3(1024), dim3(1024), k2_smem, stream,
                           y, ws, b0[2], b1[2], dout);
        hipFuncSetAttribute((const void*)k3_friction_v1, hipFuncAttributeMaxDynamicSharedMemorySize, k3_smem);
        hipLaunchKernelGGL(k3_friction_v1, dim3(1024), dim3(1024), k3_smem, stream,
                           y, ws, b0[3], b1[3], b0[4], b1[4], dout);
    }
}

// Round 14
// 681.866 us; speedup vs baseline: 2.7111x; 1.2467x over previous
//
#include <hip/hip_runtime.h>
#include <math.h>

// Problem constants: B=16384 samples, DIM=64, WIDTH=256, DD=64, C2=16
#define SB 16      // samples per workgroup

// ws layout (float offsets)
#define OFF_W0T  0            // 5 x (64x256)
#define OFF_W1T  81920        // 5 x (256x256)
#define OFF_W2PT 409600       // 256x2016 (fallback only)
#define OFF_W2CT 925696       // 256x1024 (fallback only)
#define OFF_W2BT 1187840      // 256x4096 (fallback only)
#define OFF_DE   2236416      // 16384x64
#define OFF_DS   3284992      // 16384x64
#define WS_FLOATS 4337600     // ~17.35 MB (base)
// Packed bf16 fragments (hi block then lo block), after WS_FLOATS:
#define NPACK  1048576        // W2B
#define NPACKC 262144         // W2C
#define NPACKP 524288         // W2P padded to 2048 cols
#define WS3_FLOATS (WS_FLOATS + NPACK + NPACKC + NPACKP)
// k1 packs: per net [P0:16384 | P1:65536 | PU:65536 | PD:16384] x 2 nets
#define NK1 327680
#define WS4_FLOATS (WS3_FLOATS + NK1)

typedef __attribute__((ext_vector_type(8))) short bf16x8;
typedef __attribute__((ext_vector_type(4))) float f32x4;

__device__ __forceinline__ float4 f4fma(float a, float4 w, float4 c) {
    c.x = fmaf(a, w.x, c.x); c.y = fmaf(a, w.y, c.y);
    c.z = fmaf(a, w.z, c.z); c.w = fmaf(a, w.w, c.w);
    return c;
}

__device__ __forceinline__ float4 tanh4b(float4 a, float b) {
    return make_float4(tanhf(a.x + b), tanhf(a.y + b), tanhf(a.z + b), tanhf(a.w + b));
}

// fp32 -> bf16 hi (RNE) + bf16 lo (RNE of remainder)
__device__ __forceinline__ void bf16split(float x, unsigned short& hi, unsigned short& lo) {
    unsigned b = __float_as_uint(x);
    unsigned h = (b + 0x7FFFu + ((b >> 16) & 1u)) >> 16;
    hi = (unsigned short)h;
    float r = x - __uint_as_float(h << 16);
    unsigned rb = __float_as_uint(r);
    lo = (unsigned short)((rb + 0x7FFFu + ((rb >> 16) & 1u)) >> 16);
}

#define MFMA3(acc, Ah, Al, Bh, Bl)                                            \
    acc = __builtin_amdgcn_mfma_f32_16x16x32_bf16(Ah, Bh, acc, 0, 0, 0);      \
    acc = __builtin_amdgcn_mfma_f32_16x16x32_bf16(Al, Bh, acc, 0, 0, 0);      \
    acc = __builtin_amdgcn_mfma_f32_16x16x32_bf16(Ah, Bl, acc, 0, 0, 0);

// ---------------- merged transpose + bf16 fragment packing ----------------
__global__ __launch_bounds__(1024) void k_transpose_all(
    float* __restrict__ ws, int skipmid,
    const float* __restrict__ W0a, const float* __restrict__ W0b, const float* __restrict__ W0c,
    const float* __restrict__ W0d, const float* __restrict__ W0e,
    const float* __restrict__ W1a, const float* __restrict__ W1b, const float* __restrict__ W1c,
    const float* __restrict__ W1d, const float* __restrict__ W1e,
    const float* __restrict__ W2p, const float* __restrict__ W2c, const float* __restrict__ W2b)
{
    int t = blockIdx.x * blockDim.x + threadIdx.x;
    if (t >= 2236416) {
        int e = t - 2236416;
        unsigned short* PK = (unsigned short*)(ws + WS_FLOATS);
        if (e < NPACK) {
            int j = e & 7, lane = (e >> 3) & 63, c = (e >> 9) & 7, tt = e >> 12;
            int k = c * 32 + ((lane >> 4) & 3) * 8 + j;
            int n = tt * 16 + (lane & 15);
            unsigned short hi, lo;
            bf16split(W2b[n * 256 + k], hi, lo);
            PK[e] = hi; PK[NPACK + e] = lo;
        } else if (e < NPACK + NPACKC) {
            int e2 = e - NPACK;
            unsigned short* PC = PK + 2 * NPACK;
            int j = e2 & 7, lane = (e2 >> 3) & 63, c = (e2 >> 9) & 7, tt = e2 >> 12;
            int k = c * 32 + ((lane >> 4) & 3) * 8 + j;
            int n = tt * 16 + (lane & 15);
            unsigned short hi, lo;
            bf16split(W2c[n * 256 + k], hi, lo);
            PC[e2] = hi; PC[NPACKC + e2] = lo;
        } else if (e < NPACK + NPACKC + NPACKP) {
            int e2 = e - NPACK - NPACKC;
            unsigned short* PP = PK + 2 * NPACK + 2 * NPACKC;
            int j = e2 & 7, lane = (e2 >> 3) & 63, c = (e2 >> 9) & 7, tt = e2 >> 12;
            int k = c * 32 + ((lane >> 4) & 3) * 8 + j;
            int n = tt * 16 + (lane & 15);
            float v = (n < 2016) ? W2p[n * 256 + k] : 0.f;
            unsigned short hi, lo;
            bf16split(v, hi, lo);
            PP[e2] = hi; PP[NPACKP + e2] = lo;
        } else if (e < NPACK + NPACKC + NPACKP + NK1) {
            int e2 = e - NPACK - NPACKC - NPACKP;
            unsigned short* PQ = PK + 2 * (NPACK + NPACKC + NPACKP);
            int net = e2 / 163840;
            int r = e2 - net * 163840;
            const float* W0m = net ? W0b : W0a;
            const float* W1m = net ? W1b : W1a;
            float v;
            if (r < 16384) {          // P0: M[n=c][k=i] = W0[c][i], 16 tiles, CB=2
                int j = r & 7, lane = (r >> 3) & 63, cb = (r >> 9) & 1, tt = r >> 10;
                int k = cb * 32 + ((lane >> 4) & 3) * 8 + j;
                int n = tt * 16 + (lane & 15);
                v = W0m[n * 64 + k];
            } else if (r < 81920) {   // P1: M[n=c][k=j] = W1[c][j], 16 tiles, CB=8
                int r2 = r - 16384;
                int j = r2 & 7, lane = (r2 >> 3) & 63, cb = (r2 >> 9) & 7, tt = r2 >> 12;
                int k = cb * 32 + ((lane >> 4) & 3) * 8 + j;
                int n = tt * 16 + (lane & 15);
                v = W1m[n * 256 + k];
            } else if (r < 147456) {  // PU: M[n=kout][k=j] = W1[j][kout], 16 tiles, CB=8
                int r2 = r - 81920;
                int j = r2 & 7, lane = (r2 >> 3) & 63, cb = (r2 >> 9) & 7, tt = r2 >> 12;
                int k = cb * 32 + ((lane >> 4) & 3) * 8 + j;
                int n = tt * 16 + (lane & 15);
                v = W1m[k * 256 + n];
            } else {                  // PD: M[n=i][k=c] = W0[c][i], 4 tiles, CB=8
                int r2 = r - 147456;
                int j = r2 & 7, lane = (r2 >> 3) & 63, cb = (r2 >> 9) & 7, tt = r2 >> 12;
                int k = cb * 32 + ((lane >> 4) & 3) * 8 + j;
                int n = tt * 16 + (lane & 15);
                v = W0m[k * 64 + n];
            }
            unsigned short hi, lo;
            bf16split(v, hi, lo);
            PQ[e2] = hi; PQ[NK1 + e2] = lo;
        }
        return;
    }
    if (skipmid && t >= 409600) return;   // fp32 W2?T only needed by fallback path
    const float* in;
    int o, R, C;
    float* out;
    if (t < 81920) {
        int m = t >> 14; o = t & 16383;
        const float* W0s[5] = {W0a, W0b, W0c, W0d, W0e};
        in = W0s[m]; out = ws + OFF_W0T + m * 16384; R = 256; C = 64;
    } else if (t < 409600) {
        int t2 = t - 81920;
        int m = t2 >> 16; o = t2 & 65535;
        const float* W1s[5] = {W1a, W1b, W1c, W1d, W1e};
        in = W1s[m]; out = ws + OFF_W1T + m * 65536; R = 256; C = 256;
    } else if (t < 925696) {
        o = t - 409600; in = W2p; out = ws + OFF_W2PT; R = 2016; C = 256;
    } else if (t < 1187840) {
        o = t - 925696; in = W2c; out = ws + OFF_W2CT; R = 1024; C = 256;
    } else {
        o = t - 1187840; in = W2b; out = ws + OFF_W2BT; R = 4096; C = 256;
    }
    int c = o / R, r = o - c * R;
    out[o] = in[r * C + c];
}

// ---------------- K1 fp32 (fallback) ----------------
__global__ __launch_bounds__(1024, 2) void k1_grads(
    const float* __restrict__ y, const float* __restrict__ ws,
    const float* __restrict__ W0E, const float* __restrict__ b0E,
    const float* __restrict__ W1E, const float* __restrict__ b1E,
    const float* __restrict__ w2E,
    const float* __restrict__ W0S, const float* __restrict__ b0S,
    const float* __restrict__ W1S, const float* __restrict__ b1S,
    const float* __restrict__ w2S,
    float* __restrict__ odE, float* __restrict__ odS)
{
    __shared__ float syT[1024];
    __shared__ float sH1T[4096];
    __shared__ float sGT[4096];
    __shared__ float sG1T[4096];

    const int tid = threadIdx.x;
    const int sbase = blockIdx.x * SB;
    {
        int s = tid >> 6, i = tid & 63;
        syT[i * 16 + s] = y[sbase * 64 + tid];
    }
    __syncthreads();

    const int c = tid & 255, sg = tid >> 8, s4 = sg * 4;

    for (int m = 0; m < 2; ++m) {
        const float* w0t = ws + OFF_W0T + m * 16384;
        const float* w1t = ws + OFF_W1T + m * 65536;
        const float* W0 = m ? W0S : W0E;
        const float* W1 = m ? W1S : W1E;
        const float* b0 = m ? b0S : b0E;
        const float* b1 = m ? b1S : b1E;
        const float* w2 = m ? w2S : w2E;
        float* outg = m ? odS : odE;

        {
            float4 acc = {0, 0, 0, 0};
            #pragma unroll 4
            for (int k = 0; k < 64; ++k)
                acc = f4fma(w0t[k * 256 + c], *(const float4*)(syT + k * 16 + s4), acc);
            *(float4*)(sH1T + c * 16 + s4) = tanh4b(acc, b0[c]);
        }
        __syncthreads();
        {
            float4 acc = {0, 0, 0, 0};
            #pragma unroll 4
            for (int k = 0; k < 256; ++k)
                acc = f4fma(w1t[k * 256 + c], *(const float4*)(sH1T + k * 16 + s4), acc);
            float b = b1[c], wv = w2[c];
            float4 h2 = make_float4(tanhf(acc.x + b), tanhf(acc.y + b),
                                    tanhf(acc.z + b), tanhf(acc.w + b));
            *(float4*)(sGT + c * 16 + s4) = make_float4(
                (1.f - h2.x * h2.x) * wv, (1.f - h2.y * h2.y) * wv,
                (1.f - h2.z * h2.z) * wv, (1.f - h2.w * h2.w) * wv);
        }
        __syncthreads();
        {
            float4 acc = {0, 0, 0, 0};
            #pragma unroll 4
            for (int j = 0; j < 256; ++j)
                acc = f4fma(W1[j * 256 + c], *(const float4*)(sGT + j * 16 + s4), acc);
            float4 h1 = *(const float4*)(sH1T + c * 16 + s4);
            *(float4*)(sG1T + c * 16 + s4) = make_float4(
                (1.f - h1.x * h1.x) * acc.x, (1.f - h1.y * h1.y) * acc.y,
                (1.f - h1.z * h1.z) * acc.z, (1.f - h1.w * h1.w) * acc.w);
        }
        __syncthreads();
        {
            int s = tid >> 6, i = tid & 63;
            float acc = 0.f;
            #pragma unroll 8
            for (int k = 0; k < 256; ++k)
                acc = fmaf(sG1T[k * 16 + s], W0[k * 64 + i], acc);
            outg[sbase * 64 + tid] = acc;
        }
        __syncthreads();
    }
}

// ---------------- K1 mf: all four GEMM passes via split-bf16 MFMA ----------------
__global__ __launch_bounds__(1024, 2) void k1_grads_mf(
    const float* __restrict__ y, const float* __restrict__ ws,
    const float* __restrict__ b0E, const float* __restrict__ b1E, const float* __restrict__ w2E,
    const float* __restrict__ b0S, const float* __restrict__ b1S, const float* __restrict__ w2S,
    float* __restrict__ odE, float* __restrict__ odS)
{
    __shared__ float sH1f[4352];                 // [256][17]
    __shared__ unsigned short yAh[1024], yAl[1024];
    __shared__ unsigned short bAh[4096], bAl[4096];   // G2A
    __shared__ unsigned short bBh[4096], bBl[4096];   // H1A then G1A
    __shared__ float sPart[4352];                // [16][272]

    const int tid = threadIdx.x;
    const int sbase = blockIdx.x * SB;
    const int wv = tid >> 6, l = tid & 63;

    // pack y into A-fragment (K=64, 2 cb)
    {
        int s = tid >> 6, k = tid & 63;
        unsigned short hi, lo;
        bf16split(y[sbase * 64 + tid], hi, lo);
        int addr = ((k >> 5) * 64 + (s | (((k >> 3) & 3) << 4))) * 8 + (k & 7);
        yAh[addr] = hi; yAl[addr] = lo;
    }
    __syncthreads();

    const unsigned short* K1H = (const unsigned short*)(ws + WS3_FLOATS);
    const unsigned short* K1L = K1H + NK1;

    for (int m = 0; m < 2; ++m) {
        const float* b0 = m ? b0S : b0E;
        const float* b1 = m ? b1S : b1E;
        const float* w2 = m ? w2S : w2E;
        float* outg = m ? odS : odE;
        const int pbase = m * 163840;

        // ---- L0: H1 = tanh(y @ W0^T + b0); wave owns 16-col tile wv ----
        {
            const unsigned short* PH = K1H + pbase;
            const unsigned short* PL = K1L + pbase;
            f32x4 acc = {0.f, 0.f, 0.f, 0.f};
            #pragma unroll
            for (int cb = 0; cb < 2; ++cb) {
                bf16x8 Ah = *(const bf16x8*)(yAh + (cb * 64 + l) * 8);
                bf16x8 Al = *(const bf16x8*)(yAl + (cb * 64 + l) * 8);
                bf16x8 Bh = *(const bf16x8*)(PH + ((wv * 2 + cb) * 64 + l) * 8);
                bf16x8 Bl = *(const bf16x8*)(PL + ((wv * 2 + cb) * 64 + l) * 8);
                MFMA3(acc, Ah, Al, Bh, Bl);
            }
            int c = 16 * wv + (l & 15);
            float bb = b0[c];
            const int cblk = c >> 5, j0 = c & 7;
            const int lb2 = ((c >> 3) & 3) << 4;
            #pragma unroll
            for (int r = 0; r < 4; ++r) {
                int s = (l >> 4) * 4 + r;
                float h1 = tanhf(acc[r] + bb);
                sH1f[c * 17 + s] = h1;
                unsigned short hi, lo;
                bf16split(h1, hi, lo);
                int base = (cblk * 64 + (s | lb2)) * 8 + j0;
                bBh[base] = hi; bBl[base] = lo;
            }
        }
        __syncthreads();

        // ---- L1: H2 = tanh(H1 @ W1^T + b1); G2 = (1-H2^2)*w2 -> bA ----
        {
            const unsigned short* PH = K1H + pbase + 16384;
            const unsigned short* PL = K1L + pbase + 16384;
            f32x4 acc = {0.f, 0.f, 0.f, 0.f};
            #pragma unroll 1
            for (int cb = 0; cb < 8; ++cb) {
                bf16x8 Ah = *(const bf16x8*)(bBh + (cb * 64 + l) * 8);
                bf16x8 Al = *(const bf16x8*)(bBl + (cb * 64 + l) * 8);
                bf16x8 Bh = *(const bf16x8*)(PH + ((wv * 8 + cb) * 64 + l) * 8);
                bf16x8 Bl = *(const bf16x8*)(PL + ((wv * 8 + cb) * 64 + l) * 8);
                MFMA3(acc, Ah, Al, Bh, Bl);
            }
            int c = 16 * wv + (l & 15);
            float bb = b1[c], wvv = w2[c];
            const int cblk = c >> 5, j0 = c & 7;
            const int lb2 = ((c >> 3) & 3) << 4;
            #pragma unroll
            for (int r = 0; r < 4; ++r) {
                int s = (l >> 4) * 4 + r;
                float h2 = tanhf(acc[r] + bb);
                float g2 = (1.f - h2 * h2) * wvv;
                unsigned short hi, lo;
                bf16split(g2, hi, lo);
                int base = (cblk * 64 + (s | lb2)) * 8 + j0;
                bAh[base] = hi; bAl[base] = lo;
            }
        }
        __syncthreads();

        // ---- U: U = G2 @ W1 (natural); G1 = (1-H1^2)*U -> bB ----
        {
            const unsigned short* PH = K1H + pbase + 81920;
            const unsigned short* PL = K1L + pbase + 81920;
            f32x4 acc = {0.f, 0.f, 0.f, 0.f};
            #pragma unroll 1
            for (int cb = 0; cb < 8; ++cb) {
                bf16x8 Ah = *(const bf16x8*)(bAh + (cb * 64 + l) * 8);
                bf16x8 Al = *(const bf16x8*)(bAl + (cb * 64 + l) * 8);
                bf16x8 Bh = *(const bf16x8*)(PH + ((wv * 8 + cb) * 64 + l) * 8);
                bf16x8 Bl = *(const bf16x8*)(PL + ((wv * 8 + cb) * 64 + l) * 8);
                MFMA3(acc, Ah, Al, Bh, Bl);
            }
            int c = 16 * wv + (l & 15);        // c = k_out
            const int cblk = c >> 5, j0 = c & 7;
            const int lb2 = ((c >> 3) & 3) << 4;
            #pragma unroll
            for (int r = 0; r < 4; ++r) {
                int s = (l >> 4) * 4 + r;
                float h1 = sH1f[c * 17 + s];
                float g1 = (1.f - h1 * h1) * acc[r];
                unsigned short hi, lo;
                bf16split(g1, hi, lo);
                int base = (cblk * 64 + (s | lb2)) * 8 + j0;
                bBh[base] = hi; bBl[base] = lo;
            }
        }
        __syncthreads();

        // ---- dE: dy = G1 @ W0 (natural); 4 n-tiles x 4-way K-split ----
        {
            const unsigned short* PH = K1H + pbase + 147456;
            const unsigned short* PL = K1L + pbase + 147456;
            const int t = wv & 3, kh = wv >> 2;
            f32x4 acc = {0.f, 0.f, 0.f, 0.f};
            #pragma unroll
            for (int q = 0; q < 2; ++q) {
                int cb = 2 * kh + q;
                bf16x8 Ah = *(const bf16x8*)(bBh + (cb * 64 + l) * 8);
                bf16x8 Al = *(const bf16x8*)(bBl + (cb * 64 + l) * 8);
                bf16x8 Bh = *(const bf16x8*)(PH + ((t * 8 + cb) * 64 + l) * 8);
                bf16x8 Bl = *(const bf16x8*)(PL + ((t * 8 + cb) * 64 + l) * 8);
                MFMA3(acc, Ah, Al, Bh, Bl);
            }
            #pragma unroll
            for (int r = 0; r < 4; ++r)
                sPart[(kh * 4 + t) * 272 + (l & 15) * 17 + ((l >> 4) * 4 + r)] = acc[r];
        }
        __syncthreads();
        // reduce partials and store
        {
            int s = tid >> 6, i = tid & 63;
            float v = 0.f;
            #pragma unroll
            for (int kh = 0; kh < 4; ++kh)
                v += sPart[(kh * 4 + (i >> 4)) * 272 + (i & 15) * 17 + s];
            outg[sbase * 64 + tid] = v;
        }
        __syncthreads();
    }
}

// ---------------- K2 v1 (fallback) ----------------
__global__ __launch_bounds__(1024, 4) void k2_poisson_v1(
    const float* __restrict__ y, const float* __restrict__ ws,
    const float* __restrict__ b0P, const float* __restrict__ b1P,
    float* __restrict__ dout)
{
    extern __shared__ float smem[];
    float* sa   = smem;
    float* sH2T = smem + 32384;
    float* sdE  = sH2T + 4096;
    float* sdS  = sdE + 1024;
    float* sH1T = sa;
    float* syT  = sa + 4096;

    const int tid = threadIdx.x;
    const int sbase = blockIdx.x * SB;
    const float* gdE = ws + OFF_DE;
    const float* gdS = ws + OFF_DS;

    {
        int s = tid >> 6, i = tid & 63;
        syT[i * 16 + s] = y[sbase * 64 + tid];
        sdE[tid] = gdE[sbase * 64 + tid];
        sdS[tid] = gdS[sbase * 64 + tid];
    }
    __syncthreads();

    const int c  = tid & 255;
    const int sg = tid >> 8;
    const int s4 = sg * 4;

    {
        const float* w0t = ws + OFF_W0T + 2 * 16384;
        float4 acc = {0, 0, 0, 0};
        #pragma unroll 4
        for (int k = 0; k < 64; ++k) {
            float w = w0t[k * 256 + c];
            float4 yv = *(const float4*)(syT + k * 16 + s4);
            acc = f4fma(w, yv, acc);
        }
        *(float4*)(sH1T + c * 16 + s4) = tanh4b(acc, b0P[c]);
    }
    __syncthreads();

    {
        const float* w1t = ws + OFF_W1T + 2 * 65536;
        float4 acc = {0, 0, 0, 0};
        #pragma unroll 4
        for (int k = 0; k < 256; ++k) {
            float w = w1t[k * 256 + c];
            float4 hv = *(const float4*)(sH1T + k * 16 + s4);
            acc = f4fma(w, hv, acc);
        }
        *(float4*)(sH2T + c * 16 + s4) = tanh4b(acc, b1P[c]);
    }
    __syncthreads();

    {
        const int cn = tid;
        if (cn < 1008) {
            const float* wp = ws + OFF_W2PT + 2 * cn;
            float a0[16], a1[16];
            #pragma unroll
            for (int s = 0; s < 16; ++s) { a0[s] = 0.f; a1[s] = 0.f; }
            #pragma unroll 2
            for (int k = 0; k < 256; ++k) {
                float4 h0 = *(const float4*)(sH2T + k * 16);
                float4 h1 = *(const float4*)(sH2T + k * 16 + 4);
                float4 h2 = *(const float4*)(sH2T + k * 16 + 8);
                float4 h3 = *(const float4*)(sH2T + k * 16 + 12);
                float2 w = *(const float2*)(wp + k * 2016);
                float hs[16] = {h0.x, h0.y, h0.z, h0.w, h1.x, h1.y, h1.z, h1.w,
                                h2.x, h2.y, h2.z, h2.w, h3.x, h3.y, h3.z, h3.w};
                #pragma unroll
                for (int s = 0; s < 16; ++s) {
                    a0[s] = fmaf(hs[s], w.x, a0[s]);
                    a1[s] = fmaf(hs[s], w.y, a1[s]);
                }
            }
            #pragma unroll
            for (int s = 0; s < 16; ++s) {
                sa[s * 2024 + 2 * cn]     = a0[s];
                sa[s * 2024 + 2 * cn + 1] = a1[s];
            }
        }
    }
    __syncthreads();

    {
        const int s = tid >> 6;
        const int i = tid & 63;
        const int ib = i * (i - 1) / 2;
        const float* ap = sa + s * 2024;
        const float* dep = sdE + s * 64;
        const float* dsp = sdS + s * 64;

        float adE = 0.f, adS = 0.f;
        int trij = 0;
        #pragma unroll 4
        for (int j = 0; j < 64; ++j) {
            int t = (j < i) ? (ib + j) : (trij + i);
            float sel = (j < i) ? 1.f : ((j == i) ? 0.f : -1.f);
            float cc = sel * ap[t];
            adE = fmaf(cc, dep[j], adE);
            adS = fmaf(cc, dsp[j], adS);
            trij += j;
        }

        float de = dep[i], dsv = dsp[i];
        float p0 = de * adS;
        float p1 = de * dsv;
        float p2 = dsv * dsv;
        #pragma unroll
        for (int m = 1; m <= 32; m <<= 1) {
            p0 += __shfl_xor(p0, m);
            p1 += __shfl_xor(p1, m);
            p2 += __shfl_xor(p2, m);
        }
        float inv = 1.f / p2;
        dout[sbase * 64 + tid] = adE + (p0 * dsv - p1 * adS) * inv;
    }
}

// ---------------- K2 mf: a-GEMM via split-bf16 MFMA ----------------
__global__ __launch_bounds__(1024, 4) void k2_poisson_mf(
    const float* __restrict__ y, const float* __restrict__ ws,
    const float* __restrict__ b0P, const float* __restrict__ b1P,
    float* __restrict__ dout)
{
    extern __shared__ float smem[];
    float* sa   = smem;                                   // 16 x 2024
    unsigned short* sAh = (unsigned short*)(smem + 32384);
    unsigned short* sAl = (unsigned short*)(smem + 34432);
    float* sdE  = smem + 36480;
    float* sdS  = sdE + 1024;
    float* sH1T = sa;
    float* syT  = sa + 4096;

    const int tid = threadIdx.x;
    const int sbase = blockIdx.x * SB;
    const float* gdE = ws + OFF_DE;
    const float* gdS = ws + OFF_DS;

    {
        int s = tid >> 6, i = tid & 63;
        syT[i * 16 + s] = y[sbase * 64 + tid];
        sdE[tid] = gdE[sbase * 64 + tid];
        sdS[tid] = gdS[sbase * 64 + tid];
    }
    __syncthreads();

    const int c  = tid & 255;
    const int sg = tid >> 8;
    const int s4 = sg * 4;

    {
        const float* w0t = ws + OFF_W0T + 2 * 16384;
        float4 acc = {0, 0, 0, 0};
        #pragma unroll 4
        for (int k = 0; k < 64; ++k) {
            float w = w0t[k * 256 + c];
            float4 yv = *(const float4*)(syT + k * 16 + s4);
            acc = f4fma(w, yv, acc);
        }
        *(float4*)(sH1T + c * 16 + s4) = tanh4b(acc, b0P[c]);
    }
    __syncthreads();

    {
        const float* w1t = ws + OFF_W1T + 2 * 65536;
        float4 acc = {0, 0, 0, 0};
        #pragma unroll 4
        for (int k = 0; k < 256; ++k) {
            float w = w1t[k * 256 + c];
            float4 hv = *(const float4*)(sH1T + k * 16 + s4);
            acc = f4fma(w, hv, acc);
        }
        float4 h2 = tanh4b(acc, b1P[c]);
        const int cblk = c >> 5, j0 = c & 7;
        const int lbase = ((c >> 3) & 3) << 4;
        float va[4] = {h2.x, h2.y, h2.z, h2.w};
        #pragma unroll
        for (int q = 0; q < 4; ++q) {
            int lb = ((s4 + q) & 15) | lbase;
            int base = (cblk * 64 + lb) * 8 + j0;
            unsigned short hi, lo;
            bf16split(va[q], hi, lo);
            sAh[base] = hi;
            sAl[base] = lo;
        }
    }
    __syncthreads();

    {
        const unsigned short* PP = (const unsigned short*)(ws + WS_FLOATS) + 2 * NPACK + 2 * NPACKC;
        const unsigned short* PH = PP;
        const unsigned short* PL = PP + NPACKP;
        const int wv = tid >> 6, l = tid & 63;
        f32x4 accp[8];
        #pragma unroll
        for (int t0 = 0; t0 < 8; ++t0) accp[t0] = (f32x4){0.f, 0.f, 0.f, 0.f};
        #pragma unroll 1
        for (int cb = 0; cb < 8; ++cb) {
            bf16x8 Ah = *(const bf16x8*)(sAh + (cb * 64 + l) * 8);
            bf16x8 Al = *(const bf16x8*)(sAl + (cb * 64 + l) * 8);
            #pragma unroll
            for (int t0 = 0; t0 < 8; ++t0) {
                int t = 8 * wv + t0;
                bf16x8 Bh = *(const bf16x8*)(PH + ((t * 8 + cb) * 64 + l) * 8);
                bf16x8 Bl = *(const bf16x8*)(PL + ((t * 8 + cb) * 64 + l) * 8);
                MFMA3(accp[t0], Ah, Al, Bh, Bl);
            }
        }
        #pragma unroll
        for (int t0 = 0; t0 < 8; ++t0) {
            int n = (8 * wv + t0) * 16 + (l & 15);
            if (n < 2016) {
                #pragma unroll
                for (int r = 0; r < 4; ++r)
                    sa[((l >> 4) * 4 + r) * 2024 + n] = accp[t0][r];
            }
        }
    }
    __syncthreads();

    {
        const int s = tid >> 6;
        const int i = tid & 63;
        const int ib = i * (i - 1) / 2;
        const float* ap = sa + s * 2024;
        const float* dep = sdE + s * 64;
        const float* dsp = sdS + s * 64;

        float adE = 0.f, adS = 0.f;
        int trij = 0;
        #pragma unroll 4
        for (int j = 0; j < 64; ++j) {
            int t = (j < i) ? (ib + j) : (trij + i);
            float sel = (j < i) ? 1.f : ((j == i) ? 0.f : -1.f);
            float cc = sel * ap[t];
            adE = fmaf(cc, dep[j], adE);
            adS = fmaf(cc, dsp[j], adS);
            trij += j;
        }

        float de = dep[i], dsv = dsp[i];
        float p0 = de * adS;
        float p1 = de * dsv;
        float p2 = dsv * dsv;
        #pragma unroll
        for (int m = 1; m <= 32; m <<= 1) {
            p0 += __shfl_xor(p0, m);
            p1 += __shfl_xor(p1, m);
            p2 += __shfl_xor(p2, m);
        }
        float inv = 1.f / p2;
        dout[sbase * 64 + tid] = adE + (p0 * dsv - p1 * adS) * inv;
    }
}

// ---------------- K3 mf2: Bm AND C via split-bf16 MFMA ----------------
__global__ __launch_bounds__(1024, 4) void k3_friction_mf2(
    const float* __restrict__ y, const float* __restrict__ ws,
    const float* __restrict__ b0C, const float* __restrict__ b1C,
    const float* __restrict__ b0B, const float* __restrict__ b1B,
    float* __restrict__ dout)
{
    extern __shared__ float smem[];
    float* sYT = smem;
    unsigned short* sAhc = (unsigned short*)(smem + 1024);
    unsigned short* sAlc = (unsigned short*)(smem + 3072);
    unsigned short* sAhb = (unsigned short*)(smem + 5120);
    unsigned short* sAlb = (unsigned short*)(smem + 7168);
    float* sATc = smem + 9216;
    float* sATb = smem + 13312;
    float* sC   = smem + 9216;
    float* sdE  = smem + 26640;
    float* sdS  = sdE + 1024;
    float* sBdE = sdS + 1024;
    float* sBdS = sBdE + 1024;
    float* sv   = sBdS + 1024;
    float* sq   = sv + 1024;
    float* sScal = sq + 1024;
    float* sr   = sScal + 64;

    const int tid = threadIdx.x;
    const int sbase = blockIdx.x * SB;
    const float* gdE = ws + OFF_DE;
    const float* gdS = ws + OFF_DS;

    {
        int s = tid >> 6, i = tid & 63;
        sYT[i * 16 + s] = y[sbase * 64 + tid];
        sdE[tid] = gdE[sbase * 64 + tid];
        sdS[tid] = gdS[sbase * 64 + tid];
    }
    if (tid < 64) sScal[tid] = 0.f;
    __syncthreads();

    {
        int s = tid >> 6;
        float de = sdE[tid];
        unsafeAtomicAdd(&sScal[s * 4 + 0], de * de);
        unsafeAtomicAdd(&sScal[s * 4 + 1], de * sdS[tid]);
    }

    const int net = tid >> 9;
    const int t9  = tid & 511;
    const int sgf = t9 >> 7;
    const int s4f = sgf * 4;
    const int cp  = t9 & 127;
    const int c0 = 2 * cp, c1 = c0 + 1;
    const float* w0t = ws + OFF_W0T + (3 + net) * 16384;
    const float* w1t = ws + OFF_W1T + (3 + net) * 65536;
    const float* b0v = net ? b0B : b0C;
    const float* b1v = net ? b1B : b1C;
    float* sH1 = net ? sATb : sATc;
    unsigned short* pH = net ? sAhb : sAhc;
    unsigned short* pL = net ? sAlb : sAlc;

    {
        float4 a0 = {0, 0, 0, 0}, a1 = {0, 0, 0, 0};
        #pragma unroll 4
        for (int k = 0; k < 64; ++k) {
            float4 h = *(const float4*)(sYT + k * 16 + s4f);
            float2 w = *(const float2*)(w0t + k * 256 + c0);
            a0 = f4fma(w.x, h, a0);
            a1 = f4fma(w.y, h, a1);
        }
        *(float4*)(sH1 + c0 * 16 + s4f) = tanh4b(a0, b0v[c0]);
        *(float4*)(sH1 + c1 * 16 + s4f) = tanh4b(a1, b0v[c1]);
    }
    __syncthreads();

    {
        float4 a0 = {0, 0, 0, 0}, a1 = {0, 0, 0, 0};
        #pragma unroll 4
        for (int k = 0; k < 256; ++k) {
            float4 h = *(const float4*)(sH1 + k * 16 + s4f);
            float2 w = *(const float2*)(w1t + k * 256 + c0);
            a0 = f4fma(w.x, h, a0);
            a1 = f4fma(w.y, h, a1);
        }
        float4 h2a = tanh4b(a0, b1v[c0]);
        float4 h2b = tanh4b(a1, b1v[c1]);
        const int cblk = c0 >> 5, j0 = c0 & 7;
        const int lbase = ((c0 >> 3) & 3) << 4;
        float va[2][4] = {{h2a.x, h2a.y, h2a.z, h2a.w}, {h2b.x, h2b.y, h2b.z, h2b.w}};
        #pragma unroll
        for (int q = 0; q < 4; ++q) {
            int lb = ((s4f + q) & 15) | lbase;
            int base = (cblk * 64 + lb) * 8 + j0;
            unsigned short hi0, lo0, hi1, lo1;
            bf16split(va[0][q], hi0, lo0);
            bf16split(va[1][q], hi1, lo1);
            pH[base] = hi0; pH[base + 1] = hi1;
            pL[base] = lo0; pL[base + 1] = lo1;
        }
    }
    __syncthreads();

    const int wv = tid >> 6;
    const int l  = tid & 63;

    {
        const unsigned short* PC = (const unsigned short*)(ws + WS_FLOATS) + 2 * NPACK;
        const unsigned short* CH = PC;
        const unsigned short* CL = PC + NPACKC;
        f32x4 accc[4];
        #pragma unroll
        for (int t0 = 0; t0 < 4; ++t0) accc[t0] = (f32x4){0.f, 0.f, 0.f, 0.f};
        #pragma unroll 1
        for (int cb = 0; cb < 8; ++cb) {
            bf16x8 Ah = *(const bf16x8*)(sAhc + (cb * 64 + l) * 8);
            bf16x8 Al = *(const bf16x8*)(sAlc + (cb * 64 + l) * 8);
            #pragma unroll
            for (int t0 = 0; t0 < 4; ++t0) {
                int t = 4 * wv + t0;
                bf16x8 Bh = *(const bf16x8*)(CH + ((t * 8 + cb) * 64 + l) * 8);
                bf16x8 Bl = *(const bf16x8*)(CL + ((t * 8 + cb) * 64 + l) * 8);
                MFMA3(accc[t0], Ah, Al, Bh, Bl);
            }
        }
        #pragma unroll
        for (int t0 = 0; t0 < 4; ++t0) {
            int t = 4 * wv + t0;
            #pragma unroll
            for (int r = 0; r < 4; ++r)
                sC[((l >> 4) * 4 + r) * 1089 + t * 17 + (l & 15)] = accc[t0][r];
        }
    }

    f32x4 acc[16];
    #pragma unroll
    for (int t0 = 0; t0 < 16; ++t0) acc[t0] = (f32x4){0.f, 0.f, 0.f, 0.f};
    {
        const unsigned short* BH = (const unsigned short*)(ws + WS_FLOATS);
        const unsigned short* BL = BH + NPACK;
        #pragma unroll 1
        for (int cb = 0; cb < 8; ++cb) {
            bf16x8 Ah = *(const bf16x8*)(sAhb + (cb * 64 + l) * 8);
            bf16x8 Al = *(const bf16x8*)(sAlb + (cb * 64 + l) * 8);
            const unsigned short* bh = BH + ((wv * 16 * 8 + cb) * 64 + l) * 8;
            const unsigned short* bl = BL + ((wv * 16 * 8 + cb) * 64 + l) * 8;
            #pragma unroll
            for (int t0 = 0; t0 < 16; ++t0) {
                bf16x8 Bh = *(const bf16x8*)(bh + t0 * 4096);
                bf16x8 Bl = *(const bf16x8*)(bl + t0 * 4096);
                MFMA3(acc[t0], Ah, Al, Bh, Bl);
            }
        }
    }
    #pragma unroll
    for (int g = 0; g < 4; ++g) {
        float pd[4] = {0, 0, 0, 0}, ps[4] = {0, 0, 0, 0};
        #pragma unroll
        for (int tt = 0; tt < 4; ++tt) {
            int i = 16 * tt + (l & 15);
            #pragma unroll
            for (int r = 0; r < 4; ++r) {
                int s = (l >> 4) * 4 + r;
                float d = acc[g * 4 + tt][r];
                pd[r] = fmaf(d, sdE[s * 64 + i], pd[r]);
                ps[r] = fmaf(d, sdS[s * 64 + i], ps[r]);
            }
        }
        #pragma unroll
        for (int m = 1; m <= 8; m <<= 1) {
            #pragma unroll
            for (int r = 0; r < 4; ++r) {
                pd[r] += __shfl_xor(pd[r], m);
                ps[r] += __shfl_xor(ps[r], m);
            }
        }
        if ((l & 15) == 0) {
            int kpr = 4 * wv + g;
            #pragma unroll
            for (int r = 0; r < 4; ++r) {
                int s = (l >> 4) * 4 + r;
                sBdE[s * 64 + kpr] = pd[r];
                sBdS[s * 64 + kpr] = ps[r];
            }
        }
    }
    __syncthreads();

    {
        int s = tid >> 6;
        float beta = sScal[s * 4 + 1] / sScal[s * 4 + 0];
        sv[tid] = sBdS[tid] - beta * sBdE[tid];
    }
    __syncthreads();
    {
        int s = tid >> 6;
        unsafeAtomicAdd(&sScal[s * 4 + 2], sdE[tid] * sv[tid]);
    }
    __syncthreads();

    #pragma unroll
    for (int g = 0; g < 4; ++g) {
        float pq[4] = {0, 0, 0, 0};
        #pragma unroll
        for (int tt = 0; tt < 4; ++tt) {
            int i = 16 * tt + (l & 15);
            #pragma unroll
            for (int r = 0; r < 4; ++r) {
                int s = (l >> 4) * 4 + r;
                pq[r] = fmaf(acc[g * 4 + tt][r], sv[s * 64 + i], pq[r]);
            }
        }
        #pragma unroll
        for (int m = 1; m <= 8; m <<= 1) {
            #pragma unroll
            for (int r = 0; r < 4; ++r) pq[r] += __shfl_xor(pq[r], m);
        }
        if ((l & 15) == 0) {
            int kpr = 4 * wv + g;
            #pragma unroll
            for (int r = 0; r < 4; ++r) sq[((l >> 4) * 4 + r) * 64 + kpr] = pq[r];
        }
    }
    __syncthreads();

    if (tid < 256) {
        int s = tid >> 4, m = tid & 15;
        float gamma = sScal[s * 4 + 2] / sScal[s * 4 + 0];
        float r = 0.f;
        #pragma unroll 4
        for (int k = 0; k < 64; ++k) {
            float wvv = sq[s * 64 + k] - gamma * sBdE[s * 64 + k];
            r = fmaf(sC[s * 1089 + k * 17 + m], wvv, r);
        }
        sr[s * 16 + m] = r;
    }
    __syncthreads();
    {
        int s = tid >> 6, k = tid & 63;
        float o = 0.f;
        #pragma unroll
        for (int m2 = 0; m2 < 16; ++m2)
            o = fmaf(sC[s * 1089 + k * 17 + m2], sr[s * 16 + m2], o);
        int gi = sbase * 64 + tid;
        dout[gi] = dout[gi] + o;
    }
}

// ---------------- K3 v1 (fallback, fp32) ----------------
__global__ __launch_bounds__(1024, 4) void k3_friction_v1(
    const float* __restrict__ y, const float* __restrict__ ws,
    const float* __restrict__ b0C, const float* __restrict__ b1C,
    const float* __restrict__ b0B, const float* __restrict__ b1B,
    float* __restrict__ dout)
{
    extern __shared__ float smem[];
    float* sYT  = smem;
    float* sBTc = smem + 1024;
    float* sBTb = smem + 5120;
    float* sATc = smem + 9216;
    float* sATb = smem + 13312;
    float* sC   = smem + 9216;
    float* sdE  = smem + 26640;
    float* sdS  = sdE + 1024;
    float* sBdE = sdS + 1024;
    float* sBdS = sBdE + 1024;
    float* sv   = sBdS + 1024;
    float* sq   = sv + 1024;
    float* sScal = sq + 1024;
    float* sr   = sScal + 64;

    const int tid = threadIdx.x;
    const int sbase = blockIdx.x * SB;
    const float* gdE = ws + OFF_DE;
    const float* gdS = ws + OFF_DS;

    {
        int s = tid >> 6, i = tid & 63;
        sYT[i * 16 + s] = y[sbase * 64 + tid];
        sdE[tid] = gdE[sbase * 64 + tid];
        sdS[tid] = gdS[sbase * 64 + tid];
    }
    if (tid < 64) sScal[tid] = 0.f;
    __syncthreads();

    {
        int s = tid >> 6;
        float de = sdE[tid];
        unsafeAtomicAdd(&sScal[s * 4 + 0], de * de);
        unsafeAtomicAdd(&sScal[s * 4 + 1], de * sdS[tid]);
    }

    const int net = tid >> 9;
    const int t9  = tid & 511;
    const int sgf = t9 >> 7;
    const int s4f = sgf * 4;
    const int cp  = t9 & 127;
    const int c0 = 2 * cp, c1 = c0 + 1;
    const float* w0t = ws + OFF_W0T + (3 + net) * 16384;
    const float* w1t = ws + OFF_W1T + (3 + net) * 65536;
    const float* b0v = net ? b0B : b0C;
    const float* b1v = net ? b1B : b1C;
    float* sH1 = net ? sATb : sATc;
    float* sH2 = net ? sBTb : sBTc;

    {
        float4 a0 = {0, 0, 0, 0}, a1 = {0, 0, 0, 0};
        #pragma unroll 4
        for (int k = 0; k < 64; ++k) {
            float4 h = *(const float4*)(sYT + k * 16 + s4f);
            float2 w = *(const float2*)(w0t + k * 256 + c0);
            a0 = f4fma(w.x, h, a0);
            a1 = f4fma(w.y, h, a1);
        }
        *(float4*)(sH1 + c0 * 16 + s4f) = tanh4b(a0, b0v[c0]);
        *(float4*)(sH1 + c1 * 16 + s4f) = tanh4b(a1, b0v[c1]);
    }
    __syncthreads();

    {
        float4 a0 = {0, 0, 0, 0}, a1 = {0, 0, 0, 0};
        #pragma unroll 4
        for (int k = 0; k < 256; ++k) {
            float4 h = *(const float4*)(sH1 + k * 16 + s4f);
            float2 w = *(const float2*)(w1t + k * 256 + c0);
            a0 = f4fma(w.x, h, a0);
            a1 = f4fma(w.y, h, a1);
        }
        *(float4*)(sH2 + c0 * 16 + s4f) = tanh4b(a0, b1v[c0]);
        *(float4*)(sH2 + c1 * 16 + s4f) = tanh4b(a1, b1v[c1]);
    }
    __syncthreads();

    {
        const float* w2ct = ws + OFF_W2CT;
        float acc[16];
        #pragma unroll
        for (int s = 0; s < 16; ++s) acc[s] = 0.f;
        #pragma unroll 2
        for (int k = 0; k < 256; ++k) {
            float w = w2ct[k * 1024 + tid];
            float4 h0 = *(const float4*)(sBTc + k * 16);
            float4 h1 = *(const float4*)(sBTc + k * 16 + 4);
            float4 h2 = *(const float4*)(sBTc + k * 16 + 8);
            float4 h3 = *(const float4*)(sBTc + k * 16 + 12);
            float hs[16] = {h0.x, h0.y, h0.z, h0.w, h1.x, h1.y, h1.z, h1.w,
                            h2.x, h2.y, h2.z, h2.w, h3.x, h3.y, h3.z, h3.w};
            #pragma unroll
            for (int s = 0; s < 16; ++s) acc[s] = fmaf(hs[s], w, acc[s]);
        }
        const int kC = tid >> 4, mC = tid & 15;
        #pragma unroll
        for (int s = 0; s < 16; ++s) sC[s * 1089 + kC * 17 + mC] = acc[s];
    }
    __syncthreads();

    const int kp = tid >> 4;
    const int i0 = 4 * (tid & 15);
    float4 bm[16];
    #pragma unroll
    for (int s = 0; s < 16; ++s) bm[s] = make_float4(0.f, 0.f, 0.f, 0.f);
    {
        const float* wb = ws + OFF_W2BT + 4 * tid;
        float4 w = *(const float4*)(wb);
        float4 h0 = *(const float4*)(sBTb);
        float4 h1 = *(const float4*)(sBTb + 4);
        float4 h2 = *(const float4*)(sBTb + 8);
        float4 h3 = *(const float4*)(sBTb + 12);
        #pragma unroll 2
        for (int k = 0; k < 256; ++k) {
            float4 wn = *(const float4*)(wb + (k + 1) * 4096);
            float4 g0 = *(const float4*)(sBTb + (k + 1) * 16);
            float4 g1 = *(const float4*)(sBTb + (k + 1) * 16 + 4);
            float4 g2 = *(const float4*)(sBTb + (k + 1) * 16 + 8);
            float4 g3 = *(const float4*)(sBTb + (k + 1) * 16 + 12);
            float hs[16] = {h0.x, h0.y, h0.z, h0.w, h1.x, h1.y, h1.z, h1.w,
                            h2.x, h2.y, h2.z, h2.w, h3.x, h3.y, h3.z, h3.w};
            #pragma unroll
            for (int s = 0; s < 16; ++s) {
                bm[s].x = fmaf(hs[s], w.x, bm[s].x);
                bm[s].y = fmaf(hs[s], w.y, bm[s].y);
                bm[s].z = fmaf(hs[s], w.z, bm[s].z);
                bm[s].w = fmaf(hs[s], w.w, bm[s].w);
            }
            w = wn; h0 = g0; h1 = g1; h2 = g2; h3 = g3;
        }
    }
    #pragma unroll
    for (int s = 0; s < 16; ++s) {
        float4 de = *(const float4*)(sdE + s * 64 + i0);
        float4 dsv = *(const float4*)(sdS + s * 64 + i0);
        float pd = fmaf(bm[s].w, de.w, fmaf(bm[s].z, de.z, fmaf(bm[s].y, de.y, bm[s].x * de.x)));
        float ps = fmaf(bm[s].w, dsv.w, fmaf(bm[s].z, dsv.z, fmaf(bm[s].y, dsv.y, bm[s].x * dsv.x)));
        pd += __shfl_xor(pd, 1); ps += __shfl_xor(ps, 1);
        pd += __shfl_xor(pd, 2); ps += __shfl_xor(ps, 2);
        pd += __shfl_xor(pd, 4); ps += __shfl_xor(ps, 4);
        pd += __shfl_xor(pd, 8); ps += __shfl_xor(ps, 8);
        if ((tid & 15) == 0) {
            sBdE[s * 64 + kp] = pd;
            sBdS[s * 64 + kp] = ps;
        }
    }
    __syncthreads();

    {
        int s = tid >> 6;
        float beta = sScal[s * 4 + 1] / sScal[s * 4 + 0];
        sv[tid] = sBdS[tid] - beta * sBdE[tid];
    }
    __syncthreads();
    {
        int s = tid >> 6;
        unsafeAtomicAdd(&sScal[s * 4 + 2], sdE[tid] * sv[tid]);
    }
    __syncthreads();

    #pragma unroll
    for (int s = 0; s < 16; ++s) {
        float4 vv = *(const float4*)(sv + s * 64 + i0);
        float pq = fmaf(bm[s].w, vv.w, fmaf(bm[s].z, vv.z, fmaf(bm[s].y, vv.y, bm[s].x * vv.x)));
        pq += __shfl_xor(pq, 1);
        pq += __shfl_xor(pq, 2);
        pq += __shfl_xor(pq, 4);
        pq += __shfl_xor(pq, 8);
        if ((tid & 15) == 0) sq[s * 64 + kp] = pq;
    }
    __syncthreads();

    if (tid < 256) {
        int s = tid >> 4, m = tid & 15;
        float gamma = sScal[s * 4 + 2] / sScal[s * 4 + 0];
        float r = 0.f;
        #pragma unroll 4
        for (int k = 0; k < 64; ++k) {
            float wv = sq[s * 64 + k] - gamma * sBdE[s * 64 + k];
            r = fmaf(sC[s * 1089 + k * 17 + m], wv, r);
        }
        sr[s * 16 + m] = r;
    }
    __syncthreads();
    {
        int s = tid >> 6, k = tid & 63;
        float o = 0.f;
        #pragma unroll
        for (int m2 = 0; m2 < 16; ++m2)
            o = fmaf(sC[s * 1089 + k * 17 + m2], sr[s * 16 + m2], o);
        int gi = sbase * 64 + tid;
        dout[gi] = dout[gi] + o;
    }
}

extern "C" void kernel_launch(void* const* d_in, const int* in_sizes, int n_in,
                              void* d_out, int out_size, void* d_ws, size_t ws_size,
                              hipStream_t stream)
{
    (void)in_sizes; (void)n_in; (void)out_size;
    const float* y = (const float*)d_in[1];
    const float* W0[5]; const float* b0[5]; const float* W1[5]; const float* b1[5]; const float* W2[5];
    for (int m = 0; m < 5; ++m) {
        int base = 2 + m * 5;
        W0[m] = (const float*)d_in[base + 0];
        b0[m] = (const float*)d_in[base + 1];
        W1[m] = (const float*)d_in[base + 2];
        b1[m] = (const float*)d_in[base + 3];
        W2[m] = (const float*)d_in[base + 4];
    }
    float* ws = (float*)d_ws;
    float* dout = (float*)d_out;
    if (ws_size < (size_t)WS_FLOATS * sizeof(float)) return;
    const bool big_ws = ws_size >= (size_t)WS3_FLOATS * sizeof(float);
    const bool big2   = ws_size >= (size_t)WS4_FLOATS * sizeof(float);

    int ntr = 2236416;
    if (big_ws) ntr += NPACK + NPACKC + NPACKP;
    if (big2)   ntr += NK1;
    hipLaunchKernelGGL(k_transpose_all, dim3((ntr + 1023) / 1024), dim3(1024), 0, stream,
                       ws, big_ws ? 1 : 0,
                       W0[0], W0[1], W0[2], W0[3], W0[4],
                       W1[0], W1[1], W1[2], W1[3], W1[4],
                       W2[2], W2[3], W2[4]);

    if (big2) {
        hipLaunchKernelGGL(k1_grads_mf, dim3(1024), dim3(1024), 0, stream,
                           y, ws,
                           b0[0], b1[0], W2[0], b0[1], b1[1], W2[1],
                           ws + OFF_DE, ws + OFF_DS);
    } else {
        hipLaunchKernelGGL(k1_grads, dim3(1024), dim3(1024), 0, stream,
                           y, ws,
                           W0[0], b0[0], W1[0], b1[0], W2[0],
                           W0[1], b0[1], W1[1], b1[1], W2[1],
                           ws + OFF_DE, ws + OFF_DS);
    }

    const int k2_smem = 154112;
    const int k3_smem = 132416;
    if (big_ws) {
        hipFuncSetAttribute((const void*)k2_poisson_mf, hipFuncAttributeMaxDynamicSharedMemorySize, k2_smem);
        hipLaunchKernelGGL(k2_poisson_mf, dim3(1024), dim3(1024), k2_smem, stream,
                           y, ws, b0[2], b1[2], dout);
        hipFuncSetAttribute((const void*)k3_friction_mf2, hipFuncAttributeMaxDynamicSharedMemorySize, k3_smem);
        hipLaunchKernelGGL(k3_friction_mf2, dim3(1024), dim3(1024), k3_smem, stream,
                           y, ws, b0[3], b1[3], b0[4], b1[4], dout);
    } else {
        hipFuncSetAttribute((const void*)k2_poisson_v1, hipFuncAttributeMaxDynamicSharedMemorySize, k2_smem);
        hipLaunchKernelGGL(k2_poisson_v1, dim3(1024), dim3(1024), k2_smem, stream,
                           y, ws, b0[2], b1[2], dout);
        hipFuncSetAttribute((const void*)k3_friction_v1, hipFuncAttributeMaxDynamicSharedMemorySize, k3_smem);
        hipLaunchKernelGGL(k3_friction_v1, dim3(1024), dim3(1024), k3_smem, stream,
                           y, ws, b0[3], b1[3], b0[4], b1[4], dout);
    }
}

// Round 15
// 567.894 us; speedup vs baseline: 3.2553x; 1.2007x over previous
//
#include <hip/hip_runtime.h>
#include <math.h>

// Problem constants: B=16384 samples, DIM=64, WIDTH=256, DD=64, C2=16
#define SB 16      // samples per workgroup

// ws layout (float offsets)
#define OFF_W0T  0            // 5 x (64x256)
#define OFF_W1T  81920        // 5 x (256x256)
#define OFF_W2PT 409600       // 256x2016 (fallback only)
#define OFF_W2CT 925696       // 256x1024 (fallback only)
#define OFF_W2BT 1187840      // 256x4096 (fallback only)
#define OFF_DE   2236416      // 16384x64
#define OFF_DS   3284992      // 16384x64
#define WS_FLOATS 4337600     // ~17.35 MB (base)
// Packed bf16 fragments (hi block then lo block), after WS_FLOATS:
#define NPACK  1048576        // W2B
#define NPACKC 262144         // W2C
#define NPACKP 524288         // W2P padded to 2048 cols
#define WS3_FLOATS (WS_FLOATS + NPACK + NPACKC + NPACKP)
// k1 packs: per net [P0:16384 | P1:65536 | PU:65536 | PD:16384] x 2 nets
#define NK1 327680
#define WS4_FLOATS (WS3_FLOATS + NK1)
// k3 forward packs: per net (fC, fB) [P0:16384 | P1:65536]
#define NK3F 163840
#define WS5_FLOATS (WS4_FLOATS + NK3F)

typedef __attribute__((ext_vector_type(8))) short bf16x8;
typedef __attribute__((ext_vector_type(4))) float f32x4;

__device__ __forceinline__ float4 f4fma(float a, float4 w, float4 c) {
    c.x = fmaf(a, w.x, c.x); c.y = fmaf(a, w.y, c.y);
    c.z = fmaf(a, w.z, c.z); c.w = fmaf(a, w.w, c.w);
    return c;
}

__device__ __forceinline__ float4 tanh4b(float4 a, float b) {
    return make_float4(tanhf(a.x + b), tanhf(a.y + b), tanhf(a.z + b), tanhf(a.w + b));
}

// fp32 -> bf16 hi (RNE) + bf16 lo (RNE of remainder)
__device__ __forceinline__ void bf16split(float x, unsigned short& hi, unsigned short& lo) {
    unsigned b = __float_as_uint(x);
    unsigned h = (b + 0x7FFFu + ((b >> 16) & 1u)) >> 16;
    hi = (unsigned short)h;
    float r = x - __uint_as_float(h << 16);
    unsigned rb = __float_as_uint(r);
    lo = (unsigned short)((rb + 0x7FFFu + ((rb >> 16) & 1u)) >> 16);
}

#define MFMA3(acc, Ah, Al, Bh, Bl)                                            \
    acc = __builtin_amdgcn_mfma_f32_16x16x32_bf16(Ah, Bh, acc, 0, 0, 0);      \
    acc = __builtin_amdgcn_mfma_f32_16x16x32_bf16(Al, Bh, acc, 0, 0, 0);      \
    acc = __builtin_amdgcn_mfma_f32_16x16x32_bf16(Ah, Bl, acc, 0, 0, 0);

// ---------------- merged transpose + bf16 fragment packing ----------------
__global__ __launch_bounds__(1024) void k_transpose_all(
    float* __restrict__ ws, int skipmid,
    const float* __restrict__ W0a, const float* __restrict__ W0b, const float* __restrict__ W0c,
    const float* __restrict__ W0d, const float* __restrict__ W0e,
    const float* __restrict__ W1a, const float* __restrict__ W1b, const float* __restrict__ W1c,
    const float* __restrict__ W1d, const float* __restrict__ W1e,
    const float* __restrict__ W2p, const float* __restrict__ W2c, const float* __restrict__ W2b)
{
    int t = blockIdx.x * blockDim.x + threadIdx.x;
    if (t >= 2236416) {
        int e = t - 2236416;
        unsigned short* PK = (unsigned short*)(ws + WS_FLOATS);
        if (e < NPACK) {
            int j = e & 7, lane = (e >> 3) & 63, c = (e >> 9) & 7, tt = e >> 12;
            int k = c * 32 + ((lane >> 4) & 3) * 8 + j;
            int n = tt * 16 + (lane & 15);
            unsigned short hi, lo;
            bf16split(W2b[n * 256 + k], hi, lo);
            PK[e] = hi; PK[NPACK + e] = lo;
        } else if (e < NPACK + NPACKC) {
            int e2 = e - NPACK;
            unsigned short* PC = PK + 2 * NPACK;
            int j = e2 & 7, lane = (e2 >> 3) & 63, c = (e2 >> 9) & 7, tt = e2 >> 12;
            int k = c * 32 + ((lane >> 4) & 3) * 8 + j;
            int n = tt * 16 + (lane & 15);
            unsigned short hi, lo;
            bf16split(W2c[n * 256 + k], hi, lo);
            PC[e2] = hi; PC[NPACKC + e2] = lo;
        } else if (e < NPACK + NPACKC + NPACKP) {
            int e2 = e - NPACK - NPACKC;
            unsigned short* PP = PK + 2 * NPACK + 2 * NPACKC;
            int j = e2 & 7, lane = (e2 >> 3) & 63, c = (e2 >> 9) & 7, tt = e2 >> 12;
            int k = c * 32 + ((lane >> 4) & 3) * 8 + j;
            int n = tt * 16 + (lane & 15);
            float v = (n < 2016) ? W2p[n * 256 + k] : 0.f;
            unsigned short hi, lo;
            bf16split(v, hi, lo);
            PP[e2] = hi; PP[NPACKP + e2] = lo;
        } else if (e < NPACK + NPACKC + NPACKP + NK1) {
            int e2 = e - NPACK - NPACKC - NPACKP;
            unsigned short* PQ = PK + 2 * (NPACK + NPACKC + NPACKP);
            int net = e2 / 163840;
            int r = e2 - net * 163840;
            const float* W0m = net ? W0b : W0a;
            const float* W1m = net ? W1b : W1a;
            float v;
            if (r < 16384) {          // P0
                int j = r & 7, lane = (r >> 3) & 63, cb = (r >> 9) & 1, tt = r >> 10;
                int k = cb * 32 + ((lane >> 4) & 3) * 8 + j;
                int n = tt * 16 + (lane & 15);
                v = W0m[n * 64 + k];
            } else if (r < 81920) {   // P1
                int r2 = r - 16384;
                int j = r2 & 7, lane = (r2 >> 3) & 63, cb = (r2 >> 9) & 7, tt = r2 >> 12;
                int k = cb * 32 + ((lane >> 4) & 3) * 8 + j;
                int n = tt * 16 + (lane & 15);
                v = W1m[n * 256 + k];
            } else if (r < 147456) {  // PU
                int r2 = r - 81920;
                int j = r2 & 7, lane = (r2 >> 3) & 63, cb = (r2 >> 9) & 7, tt = r2 >> 12;
                int k = cb * 32 + ((lane >> 4) & 3) * 8 + j;
                int n = tt * 16 + (lane & 15);
                v = W1m[k * 256 + n];
            } else {                  // PD
                int r2 = r - 147456;
                int j = r2 & 7, lane = (r2 >> 3) & 63, cb = (r2 >> 9) & 7, tt = r2 >> 12;
                int k = cb * 32 + ((lane >> 4) & 3) * 8 + j;
                int n = tt * 16 + (lane & 15);
                v = W0m[k * 64 + n];
            }
            unsigned short hi, lo;
            bf16split(v, hi, lo);
            PQ[e2] = hi; PQ[NK1 + e2] = lo;
        } else if (e < NPACK + NPACKC + NPACKP + NK1 + NK3F) {
            // k3 forward packs: nets fC (W0d/W1d), fB (W0e/W1e)
            int e2 = e - NPACK - NPACKC - NPACKP - NK1;
            unsigned short* PQ = PK + 2 * (NPACK + NPACKC + NPACKP + NK1);
            int net = e2 / 81920;
            int r = e2 - net * 81920;
            const float* W0m = net ? W0e : W0d;
            const float* W1m = net ? W1e : W1d;
            float v;
            if (r < 16384) {          // P0: 16 tiles x 2 cb
                int j = r & 7, lane = (r >> 3) & 63, cb = (r >> 9) & 1, tt = r >> 10;
                int k = cb * 32 + ((lane >> 4) & 3) * 8 + j;
                int n = tt * 16 + (lane & 15);
                v = W0m[n * 64 + k];
            } else {                  // P1: 16 tiles x 8 cb
                int r2 = r - 16384;
                int j = r2 & 7, lane = (r2 >> 3) & 63, cb = (r2 >> 9) & 7, tt = r2 >> 12;
                int k = cb * 32 + ((lane >> 4) & 3) * 8 + j;
                int n = tt * 16 + (lane & 15);
                v = W1m[n * 256 + k];
            }
            unsigned short hi, lo;
            bf16split(v, hi, lo);
            PQ[e2] = hi; PQ[NK3F + e2] = lo;
        }
        return;
    }
    if (skipmid && t >= 409600) return;
    const float* in;
    int o, R, C;
    float* out;
    if (t < 81920) {
        int m = t >> 14; o = t & 16383;
        const float* W0s[5] = {W0a, W0b, W0c, W0d, W0e};
        in = W0s[m]; out = ws + OFF_W0T + m * 16384; R = 256; C = 64;
    } else if (t < 409600) {
        int t2 = t - 81920;
        int m = t2 >> 16; o = t2 & 65535;
        const float* W1s[5] = {W1a, W1b, W1c, W1d, W1e};
        in = W1s[m]; out = ws + OFF_W1T + m * 65536; R = 256; C = 256;
    } else if (t < 925696) {
        o = t - 409600; in = W2p; out = ws + OFF_W2PT; R = 2016; C = 256;
    } else if (t < 1187840) {
        o = t - 925696; in = W2c; out = ws + OFF_W2CT; R = 1024; C = 256;
    } else {
        o = t - 1187840; in = W2b; out = ws + OFF_W2BT; R = 4096; C = 256;
    }
    int c = o / R, r = o - c * R;
    out[o] = in[r * C + c];
}

// ---------------- K1 mf: all four GEMM passes via split-bf16 MFMA ----------------
__global__ __launch_bounds__(1024, 2) void k1_grads_mf(
    const float* __restrict__ y, const float* __restrict__ ws,
    const float* __restrict__ b0E, const float* __restrict__ b1E, const float* __restrict__ w2E,
    const float* __restrict__ b0S, const float* __restrict__ b1S, const float* __restrict__ w2S,
    float* __restrict__ odE, float* __restrict__ odS)
{
    __shared__ float sH1f[4352];                 // [256][17]
    __shared__ unsigned short yAh[1024], yAl[1024];
    __shared__ unsigned short bAh[4096], bAl[4096];
    __shared__ unsigned short bBh[4096], bBl[4096];
    __shared__ float sPart[4352];

    const int tid = threadIdx.x;
    const int sbase = blockIdx.x * SB;
    const int wv = tid >> 6, l = tid & 63;

    {
        int s = tid >> 6, k = tid & 63;
        unsigned short hi, lo;
        bf16split(y[sbase * 64 + tid], hi, lo);
        int addr = ((k >> 5) * 64 + (s | (((k >> 3) & 3) << 4))) * 8 + (k & 7);
        yAh[addr] = hi; yAl[addr] = lo;
    }
    __syncthreads();

    const unsigned short* K1H = (const unsigned short*)(ws + WS3_FLOATS);
    const unsigned short* K1L = K1H + NK1;

    for (int m = 0; m < 2; ++m) {
        const float* b0 = m ? b0S : b0E;
        const float* b1 = m ? b1S : b1E;
        const float* w2 = m ? w2S : w2E;
        float* outg = m ? odS : odE;
        const int pbase = m * 163840;

        {
            const unsigned short* PH = K1H + pbase;
            const unsigned short* PL = K1L + pbase;
            f32x4 acc = {0.f, 0.f, 0.f, 0.f};
            #pragma unroll
            for (int cb = 0; cb < 2; ++cb) {
                bf16x8 Ah = *(const bf16x8*)(yAh + (cb * 64 + l) * 8);
                bf16x8 Al = *(const bf16x8*)(yAl + (cb * 64 + l) * 8);
                bf16x8 Bh = *(const bf16x8*)(PH + ((wv * 2 + cb) * 64 + l) * 8);
                bf16x8 Bl = *(const bf16x8*)(PL + ((wv * 2 + cb) * 64 + l) * 8);
                MFMA3(acc, Ah, Al, Bh, Bl);
            }
            int c = 16 * wv + (l & 15);
            float bb = b0[c];
            const int cblk = c >> 5, j0 = c & 7;
            const int lb2 = ((c >> 3) & 3) << 4;
            #pragma unroll
            for (int r = 0; r < 4; ++r) {
                int s = (l >> 4) * 4 + r;
                float h1 = tanhf(acc[r] + bb);
                sH1f[c * 17 + s] = h1;
                unsigned short hi, lo;
                bf16split(h1, hi, lo);
                int base = (cblk * 64 + (s | lb2)) * 8 + j0;
                bBh[base] = hi; bBl[base] = lo;
            }
        }
        __syncthreads();

        {
            const unsigned short* PH = K1H + pbase + 16384;
            const unsigned short* PL = K1L + pbase + 16384;
            f32x4 acc = {0.f, 0.f, 0.f, 0.f};
            #pragma unroll 1
            for (int cb = 0; cb < 8; ++cb) {
                bf16x8 Ah = *(const bf16x8*)(bBh + (cb * 64 + l) * 8);
                bf16x8 Al = *(const bf16x8*)(bBl + (cb * 64 + l) * 8);
                bf16x8 Bh = *(const bf16x8*)(PH + ((wv * 8 + cb) * 64 + l) * 8);
                bf16x8 Bl = *(const bf16x8*)(PL + ((wv * 8 + cb) * 64 + l) * 8);
                MFMA3(acc, Ah, Al, Bh, Bl);
            }
            int c = 16 * wv + (l & 15);
            float bb = b1[c], wvv = w2[c];
            const int cblk = c >> 5, j0 = c & 7;
            const int lb2 = ((c >> 3) & 3) << 4;
            #pragma unroll
            for (int r = 0; r < 4; ++r) {
                int s = (l >> 4) * 4 + r;
                float h2 = tanhf(acc[r] + bb);
                float g2 = (1.f - h2 * h2) * wvv;
                unsigned short hi, lo;
                bf16split(g2, hi, lo);
                int base = (cblk * 64 + (s | lb2)) * 8 + j0;
                bAh[base] = hi; bAl[base] = lo;
            }
        }
        __syncthreads();

        {
            const unsigned short* PH = K1H + pbase + 81920;
            const unsigned short* PL = K1L + pbase + 81920;
            f32x4 acc = {0.f, 0.f, 0.f, 0.f};
            #pragma unroll 1
            for (int cb = 0; cb < 8; ++cb) {
                bf16x8 Ah = *(const bf16x8*)(bAh + (cb * 64 + l) * 8);
                bf16x8 Al = *(const bf16x8*)(bAl + (cb * 64 + l) * 8);
                bf16x8 Bh = *(const bf16x8*)(PH + ((wv * 8 + cb) * 64 + l) * 8);
                bf16x8 Bl = *(const bf16x8*)(PL + ((wv * 8 + cb) * 64 + l) * 8);
                MFMA3(acc, Ah, Al, Bh, Bl);
            }
            int c = 16 * wv + (l & 15);
            const int cblk = c >> 5, j0 = c & 7;
            const int lb2 = ((c >> 3) & 3) << 4;
            #pragma unroll
            for (int r = 0; r < 4; ++r) {
                int s = (l >> 4) * 4 + r;
                float h1 = sH1f[c * 17 + s];
                float g1 = (1.f - h1 * h1) * acc[r];
                unsigned short hi, lo;
                bf16split(g1, hi, lo);
                int base = (cblk * 64 + (s | lb2)) * 8 + j0;
                bBh[base] = hi; bBl[base] = lo;
            }
        }
        __syncthreads();

        {
            const unsigned short* PH = K1H + pbase + 147456;
            const unsigned short* PL = K1L + pbase + 147456;
            const int t = wv & 3, kh = wv >> 2;
            f32x4 acc = {0.f, 0.f, 0.f, 0.f};
            #pragma unroll
            for (int q = 0; q < 2; ++q) {
                int cb = 2 * kh + q;
                bf16x8 Ah = *(const bf16x8*)(bBh + (cb * 64 + l) * 8);
                bf16x8 Al = *(const bf16x8*)(bBl + (cb * 64 + l) * 8);
                bf16x8 Bh = *(const bf16x8*)(PH + ((t * 8 + cb) * 64 + l) * 8);
                bf16x8 Bl = *(const bf16x8*)(PL + ((t * 8 + cb) * 64 + l) * 8);
                MFMA3(acc, Ah, Al, Bh, Bl);
            }
            #pragma unroll
            for (int r = 0; r < 4; ++r)
                sPart[(kh * 4 + t) * 272 + (l & 15) * 17 + ((l >> 4) * 4 + r)] = acc[r];
        }
        __syncthreads();
        {
            int s = tid >> 6, i = tid & 63;
            float v = 0.f;
            #pragma unroll
            for (int kh = 0; kh < 4; ++kh)
                v += sPart[(kh * 4 + (i >> 4)) * 272 + (i & 15) * 17 + s];
            outg[sbase * 64 + tid] = v;
        }
        __syncthreads();
    }
}

// ---------------- K2 mf: a-GEMM via split-bf16 MFMA (forwards fp32) ----------------
__global__ __launch_bounds__(1024, 4) void k2_poisson_mf(
    const float* __restrict__ y, const float* __restrict__ ws,
    const float* __restrict__ b0P, const float* __restrict__ b1P,
    float* __restrict__ dout)
{
    extern __shared__ float smem[];
    float* sa   = smem;                                   // 16 x 2024
    unsigned short* sAh = (unsigned short*)(smem + 32384);
    unsigned short* sAl = (unsigned short*)(smem + 34432);
    float* sdE  = smem + 36480;
    float* sdS  = sdE + 1024;
    float* sH1T = sa;
    float* syT  = sa + 4096;

    const int tid = threadIdx.x;
    const int sbase = blockIdx.x * SB;
    const float* gdE = ws + OFF_DE;
    const float* gdS = ws + OFF_DS;

    {
        int s = tid >> 6, i = tid & 63;
        syT[i * 16 + s] = y[sbase * 64 + tid];
        sdE[tid] = gdE[sbase * 64 + tid];
        sdS[tid] = gdS[sbase * 64 + tid];
    }
    __syncthreads();

    const int c  = tid & 255;
    const int sg = tid >> 8;
    const int s4 = sg * 4;

    {
        const float* w0t = ws + OFF_W0T + 2 * 16384;
        float4 acc = {0, 0, 0, 0};
        #pragma unroll 4
        for (int k = 0; k < 64; ++k) {
            float w = w0t[k * 256 + c];
            float4 yv = *(const float4*)(syT + k * 16 + s4);
            acc = f4fma(w, yv, acc);
        }
        *(float4*)(sH1T + c * 16 + s4) = tanh4b(acc, b0P[c]);
    }
    __syncthreads();

    {
        const float* w1t = ws + OFF_W1T + 2 * 65536;
        float4 acc = {0, 0, 0, 0};
        #pragma unroll 4
        for (int k = 0; k < 256; ++k) {
            float w = w1t[k * 256 + c];
            float4 hv = *(const float4*)(sH1T + k * 16 + s4);
            acc = f4fma(w, hv, acc);
        }
        float4 h2 = tanh4b(acc, b1P[c]);
        const int cblk = c >> 5, j0 = c & 7;
        const int lbase = ((c >> 3) & 3) << 4;
        float va[4] = {h2.x, h2.y, h2.z, h2.w};
        #pragma unroll
        for (int q = 0; q < 4; ++q) {
            int lb = ((s4 + q) & 15) | lbase;
            int base = (cblk * 64 + lb) * 8 + j0;
            unsigned short hi, lo;
            bf16split(va[q], hi, lo);
            sAh[base] = hi;
            sAl[base] = lo;
        }
    }
    __syncthreads();

    {
        const unsigned short* PP = (const unsigned short*)(ws + WS_FLOATS) + 2 * NPACK + 2 * NPACKC;
        const unsigned short* PH = PP;
        const unsigned short* PL = PP + NPACKP;
        const int wv = tid >> 6, l = tid & 63;
        f32x4 accp[8];
        #pragma unroll
        for (int t0 = 0; t0 < 8; ++t0) accp[t0] = (f32x4){0.f, 0.f, 0.f, 0.f};
        #pragma unroll 1
        for (int cb = 0; cb < 8; ++cb) {
            bf16x8 Ah = *(const bf16x8*)(sAh + (cb * 64 + l) * 8);
            bf16x8 Al = *(const bf16x8*)(sAl + (cb * 64 + l) * 8);
            #pragma unroll
            for (int t0 = 0; t0 < 8; ++t0) {
                int t = 8 * wv + t0;
                bf16x8 Bh = *(const bf16x8*)(PH + ((t * 8 + cb) * 64 + l) * 8);
                bf16x8 Bl = *(const bf16x8*)(PL + ((t * 8 + cb) * 64 + l) * 8);
                MFMA3(accp[t0], Ah, Al, Bh, Bl);
            }
        }
        #pragma unroll
        for (int t0 = 0; t0 < 8; ++t0) {
            int n = (8 * wv + t0) * 16 + (l & 15);
            if (n < 2016) {
                #pragma unroll
                for (int r = 0; r < 4; ++r)
                    sa[((l >> 4) * 4 + r) * 2024 + n] = accp[t0][r];
            }
        }
    }
    __syncthreads();

    {
        const int s = tid >> 6;
        const int i = tid & 63;
        const int ib = i * (i - 1) / 2;
        const float* ap = sa + s * 2024;
        const float* dep = sdE + s * 64;
        const float* dsp = sdS + s * 64;

        float adE = 0.f, adS = 0.f;
        int trij = 0;
        #pragma unroll 4
        for (int j = 0; j < 64; ++j) {
            int t = (j < i) ? (ib + j) : (trij + i);
            float sel = (j < i) ? 1.f : ((j == i) ? 0.f : -1.f);
            float cc = sel * ap[t];
            adE = fmaf(cc, dep[j], adE);
            adS = fmaf(cc, dsp[j], adS);
            trij += j;
        }

        float de = dep[i], dsv = dsp[i];
        float p0 = de * adS;
        float p1 = de * dsv;
        float p2 = dsv * dsv;
        #pragma unroll
        for (int m = 1; m <= 32; m <<= 1) {
            p0 += __shfl_xor(p0, m);
            p1 += __shfl_xor(p1, m);
            p2 += __shfl_xor(p2, m);
        }
        float inv = 1.f / p2;
        dout[sbase * 64 + tid] = adE + (p0 * dsv - p1 * adS) * inv;
    }
}

// ---------------- K3 mf3: forwards AND C AND Bm via split-bf16 MFMA ----------------
// LDS: yA-packs @0..1024 | H2 A-packs @1024..9216 | union{H1-packs @9216..17408, sC @9216..26640}
//      sdE@26640 sdS@27664 sBdE@28688 sBdS@29712 sv@30736 sq@31760 sScal@32784 sr@32848 (33104 f)
__global__ __launch_bounds__(1024, 4) void k3_friction_mf3(
    const float* __restrict__ y, const float* __restrict__ ws,
    const float* __restrict__ b0C, const float* __restrict__ b1C,
    const float* __restrict__ b0B, const float* __restrict__ b1B,
    float* __restrict__ dout)
{
    extern __shared__ float smem[];
    unsigned short* yAh = (unsigned short*)(smem);          // 1024 us
    unsigned short* yAl = (unsigned short*)(smem + 512);    // 1024 us
    unsigned short* sAhc = (unsigned short*)(smem + 1024);  // H2 packs (fC)
    unsigned short* sAlc = (unsigned short*)(smem + 3072);
    unsigned short* sAhb = (unsigned short*)(smem + 5120);  // H2 packs (fB)
    unsigned short* sAlb = (unsigned short*)(smem + 7168);
    unsigned short* h1ch = (unsigned short*)(smem + 9216);  // H1 packs (die after L1)
    unsigned short* h1cl = (unsigned short*)(smem + 11264);
    unsigned short* h1bh = (unsigned short*)(smem + 13312);
    unsigned short* h1bl = (unsigned short*)(smem + 15360);
    float* sC   = smem + 9216;                              // overlaps H1 packs
    float* sdE  = smem + 26640;
    float* sdS  = smem + 27664;
    float* sBdE = smem + 28688;
    float* sBdS = smem + 29712;
    float* sv   = smem + 30736;
    float* sq   = smem + 31760;
    float* sScal= smem + 32784;
    float* sr   = smem + 32848;

    const int tid = threadIdx.x;
    const int sbase = blockIdx.x * SB;
    const float* gdE = ws + OFF_DE;
    const float* gdS = ws + OFF_DS;

    {
        int s = tid >> 6, k = tid & 63;
        unsigned short hi, lo;
        bf16split(y[sbase * 64 + tid], hi, lo);
        int addr = ((k >> 5) * 64 + (s | (((k >> 3) & 3) << 4))) * 8 + (k & 7);
        yAh[addr] = hi; yAl[addr] = lo;
        sdE[tid] = gdE[sbase * 64 + tid];
        sdS[tid] = gdS[sbase * 64 + tid];
    }
    if (tid < 64) sScal[tid] = 0.f;
    __syncthreads();

    {
        int s = tid >> 6;
        float de = sdE[tid];
        unsafeAtomicAdd(&sScal[s * 4 + 0], de * de);
        unsafeAtomicAdd(&sScal[s * 4 + 1], de * sdS[tid]);
    }

    const int wv = tid >> 6;          // wave 0..15
    const int l  = tid & 63;          // lane
    const int netw = wv >> 3;         // 0=fC, 1=fB (forwards)
    const int tb   = wv & 7;
    const float* b0v = netw ? b0B : b0C;
    const float* b1v = netw ? b1B : b1C;
    unsigned short* h1H = netw ? h1bh : h1ch;
    unsigned short* h1L = netw ? h1bl : h1cl;
    unsigned short* h2H = netw ? sAhb : sAhc;
    unsigned short* h2L = netw ? sAlb : sAlc;

    const unsigned short* F3H = (const unsigned short*)(ws + WS4_FLOATS);
    const unsigned short* F3L = F3H + NK3F;

    // ---- L0 (MFMA): H1 = tanh(y @ W0^T + b0); 2 tiles/wave ----
    #pragma unroll
    for (int jj = 0; jj < 2; ++jj) {
        int t = tb + 8 * jj;
        f32x4 acc = {0.f, 0.f, 0.f, 0.f};
        #pragma unroll
        for (int cb = 0; cb < 2; ++cb) {
            bf16x8 Ah = *(const bf16x8*)(yAh + (cb * 64 + l) * 8);
            bf16x8 Al = *(const bf16x8*)(yAl + (cb * 64 + l) * 8);
            const unsigned short* bh = F3H + netw * 81920 + ((t * 2 + cb) * 64 + l) * 8;
            const unsigned short* bl = F3L + netw * 81920 + ((t * 2 + cb) * 64 + l) * 8;
            bf16x8 Bh = *(const bf16x8*)(bh);
            bf16x8 Bl = *(const bf16x8*)(bl);
            MFMA3(acc, Ah, Al, Bh, Bl);
        }
        int c = 16 * t + (l & 15);
        float bb = b0v[c];
        const int cblk = c >> 5, j0 = c & 7;
        const int lb2 = ((c >> 3) & 3) << 4;
        #pragma unroll
        for (int r = 0; r < 4; ++r) {
            int s = (l >> 4) * 4 + r;
            float h1 = tanhf(acc[r] + bb);
            unsigned short hi, lo;
            bf16split(h1, hi, lo);
            int base = (cblk * 64 + (s | lb2)) * 8 + j0;
            h1H[base] = hi; h1L[base] = lo;
        }
    }
    __syncthreads();

    // ---- L1 (MFMA): H2 = tanh(H1 @ W1^T + b1) -> H2 A-packs ----
    #pragma unroll
    for (int jj = 0; jj < 2; ++jj) {
        int t = tb + 8 * jj;
        f32x4 acc = {0.f, 0.f, 0.f, 0.f};
        #pragma unroll 1
        for (int cb = 0; cb < 8; ++cb) {
            bf16x8 Ah = *(const bf16x8*)(h1H + (cb * 64 + l) * 8);
            bf16x8 Al = *(const bf16x8*)(h1L + (cb * 64 + l) * 8);
            const unsigned short* bh = F3H + netw * 81920 + 16384 + ((t * 8 + cb) * 64 + l) * 8;
            const unsigned short* bl = F3L + netw * 81920 + 16384 + ((t * 8 + cb) * 64 + l) * 8;
            bf16x8 Bh = *(const bf16x8*)(bh);
            bf16x8 Bl = *(const bf16x8*)(bl);
            MFMA3(acc, Ah, Al, Bh, Bl);
        }
        int c = 16 * t + (l & 15);
        float bb = b1v[c];
        const int cblk = c >> 5, j0 = c & 7;
        const int lb2 = ((c >> 3) & 3) << 4;
        #pragma unroll
        for (int r = 0; r < 4; ++r) {
            int s = (l >> 4) * 4 + r;
            float h2 = tanhf(acc[r] + bb);
            unsigned short hi, lo;
            bf16split(h2, hi, lo);
            int base = (cblk * 64 + (s | lb2)) * 8 + j0;
            h2H[base] = hi; h2L[base] = lo;
        }
    }
    __syncthreads();   // H1 packs dead; sC writable

    // ===== C head via MFMA: wave owns n-tiles 4wv..4wv+3 =====
    {
        const unsigned short* PC = (const unsigned short*)(ws + WS_FLOATS) + 2 * NPACK;
        const unsigned short* CH = PC;
        const unsigned short* CL = PC + NPACKC;
        f32x4 accc[4];
        #pragma unroll
        for (int t0 = 0; t0 < 4; ++t0) accc[t0] = (f32x4){0.f, 0.f, 0.f, 0.f};
        #pragma unroll 1
        for (int cb = 0; cb < 8; ++cb) {
            bf16x8 Ah = *(const bf16x8*)(sAhc + (cb * 64 + l) * 8);
            bf16x8 Al = *(const bf16x8*)(sAlc + (cb * 64 + l) * 8);
            #pragma unroll
            for (int t0 = 0; t0 < 4; ++t0) {
                int t = 4 * wv + t0;
                bf16x8 Bh = *(const bf16x8*)(CH + ((t * 8 + cb) * 64 + l) * 8);
                bf16x8 Bl = *(const bf16x8*)(CL + ((t * 8 + cb) * 64 + l) * 8);
                MFMA3(accc[t0], Ah, Al, Bh, Bl);
            }
        }
        #pragma unroll
        for (int t0 = 0; t0 < 4; ++t0) {
            int t = 4 * wv + t0;
            #pragma unroll
            for (int r = 0; r < 4; ++r)
                sC[((l >> 4) * 4 + r) * 1089 + t * 17 + (l & 15)] = accc[t0][r];
        }
    }

    // ===== Bm via MFMA: wave owns n-tiles 16wv..16wv+15 =====
    f32x4 acc[16];
    #pragma unroll
    for (int t0 = 0; t0 < 16; ++t0) acc[t0] = (f32x4){0.f, 0.f, 0.f, 0.f};
    {
        const unsigned short* BH = (const unsigned short*)(ws + WS_FLOATS);
        const unsigned short* BL = BH + NPACK;
        #pragma unroll 1
        for (int cb = 0; cb < 8; ++cb) {
            bf16x8 Ah = *(const bf16x8*)(sAhb + (cb * 64 + l) * 8);
            bf16x8 Al = *(const bf16x8*)(sAlb + (cb * 64 + l) * 8);
            const unsigned short* bh = BH + ((wv * 16 * 8 + cb) * 64 + l) * 8;
            const unsigned short* bl = BL + ((wv * 16 * 8 + cb) * 64 + l) * 8;
            #pragma unroll
            for (int t0 = 0; t0 < 16; ++t0) {
                bf16x8 Bh = *(const bf16x8*)(bh + t0 * 4096);
                bf16x8 Bl = *(const bf16x8*)(bl + t0 * 4096);
                MFMA3(acc[t0], Ah, Al, Bh, Bl);
            }
        }
    }
    // dots
    #pragma unroll
    for (int g = 0; g < 4; ++g) {
        float pd[4] = {0, 0, 0, 0}, ps[4] = {0, 0, 0, 0};
        #pragma unroll
        for (int tt = 0; tt < 4; ++tt) {
            int i = 16 * tt + (l & 15);
            #pragma unroll
            for (int r = 0; r < 4; ++r) {
                int s = (l >> 4) * 4 + r;
                float d = acc[g * 4 + tt][r];
                pd[r] = fmaf(d, sdE[s * 64 + i], pd[r]);
                ps[r] = fmaf(d, sdS[s * 64 + i], ps[r]);
            }
        }
        #pragma unroll
        for (int m = 1; m <= 8; m <<= 1) {
            #pragma unroll
            for (int r = 0; r < 4; ++r) {
                pd[r] += __shfl_xor(pd[r], m);
                ps[r] += __shfl_xor(ps[r], m);
            }
        }
        if ((l & 15) == 0) {
            int kpr = 4 * wv + g;
            #pragma unroll
            for (int r = 0; r < 4; ++r) {
                int s = (l >> 4) * 4 + r;
                sBdE[s * 64 + kpr] = pd[r];
                sBdS[s * 64 + kpr] = ps[r];
            }
        }
    }
    __syncthreads();

    {
        int s = tid >> 6;
        float beta = sScal[s * 4 + 1] / sScal[s * 4 + 0];
        sv[tid] = sBdS[tid] - beta * sBdE[tid];
    }
    __syncthreads();
    {
        int s = tid >> 6;
        unsafeAtomicAdd(&sScal[s * 4 + 2], sdE[tid] * sv[tid]);
    }
    __syncthreads();

    // pass2: q = Bm @ v from acc registers
    #pragma unroll
    for (int g = 0; g < 4; ++g) {
        float pq[4] = {0, 0, 0, 0};
        #pragma unroll
        for (int tt = 0; tt < 4; ++tt) {
            int i = 16 * tt + (l & 15);
            #pragma unroll
            for (int r = 0; r < 4; ++r) {
                int s = (l >> 4) * 4 + r;
                pq[r] = fmaf(acc[g * 4 + tt][r], sv[s * 64 + i], pq[r]);
            }
        }
        #pragma unroll
        for (int m = 1; m <= 8; m <<= 1) {
            #pragma unroll
            for (int r = 0; r < 4; ++r) pq[r] += __shfl_xor(pq[r], m);
        }
        if ((l & 15) == 0) {
            int kpr = 4 * wv + g;
            #pragma unroll
            for (int r = 0; r < 4; ++r) sq[((l >> 4) * 4 + r) * 64 + kpr] = pq[r];
        }
    }
    __syncthreads();

    if (tid < 256) {
        int s = tid >> 4, m = tid & 15;
        float gamma = sScal[s * 4 + 2] / sScal[s * 4 + 0];
        float r = 0.f;
        #pragma unroll 4
        for (int k = 0; k < 64; ++k) {
            float wvv = sq[s * 64 + k] - gamma * sBdE[s * 64 + k];
            r = fmaf(sC[s * 1089 + k * 17 + m], wvv, r);
        }
        sr[s * 16 + m] = r;
    }
    __syncthreads();
    {
        int s = tid >> 6, k = tid & 63;
        float o = 0.f;
        #pragma unroll
        for (int m2 = 0; m2 < 16; ++m2)
            o = fmaf(sC[s * 1089 + k * 17 + m2], sr[s * 16 + m2], o);
        int gi = sbase * 64 + tid;
        dout[gi] = dout[gi] + o;
    }
}

// ---------------- K3 mf2: R14 proven fallback (forwards fp32) ----------------
__global__ __launch_bounds__(1024, 4) void k3_friction_mf2(
    const float* __restrict__ y, const float* __restrict__ ws,
    const float* __restrict__ b0C, const float* __restrict__ b1C,
    const float* __restrict__ b0B, const float* __restrict__ b1B,
    float* __restrict__ dout)
{
    extern __shared__ float smem[];
    float* sYT = smem;
    unsigned short* sAhc = (unsigned short*)(smem + 1024);
    unsigned short* sAlc = (unsigned short*)(smem + 3072);
    unsigned short* sAhb = (unsigned short*)(smem + 5120);
    unsigned short* sAlb = (unsigned short*)(smem + 7168);
    float* sATc = smem + 9216;
    float* sATb = smem + 13312;
    float* sC   = smem + 9216;
    float* sdE  = smem + 26640;
    float* sdS  = sdE + 1024;
    float* sBdE = sdS + 1024;
    float* sBdS = sBdE + 1024;
    float* sv   = sBdS + 1024;
    float* sq   = sv + 1024;
    float* sScal = sq + 1024;
    float* sr   = sScal + 64;

    const int tid = threadIdx.x;
    const int sbase = blockIdx.x * SB;
    const float* gdE = ws + OFF_DE;
    const float* gdS = ws + OFF_DS;

    {
        int s = tid >> 6, i = tid & 63;
        sYT[i * 16 + s] = y[sbase * 64 + tid];
        sdE[tid] = gdE[sbase * 64 + tid];
        sdS[tid] = gdS[sbase * 64 + tid];
    }
    if (tid < 64) sScal[tid] = 0.f;
    __syncthreads();

    {
        int s = tid >> 6;
        float de = sdE[tid];
        unsafeAtomicAdd(&sScal[s * 4 + 0], de * de);
        unsafeAtomicAdd(&sScal[s * 4 + 1], de * sdS[tid]);
    }

    const int net = tid >> 9;
    const int t9  = tid & 511;
    const int sgf = t9 >> 7;
    const int s4f = sgf * 4;
    const int cp  = t9 & 127;
    const int c0 = 2 * cp, c1 = c0 + 1;
    const float* w0t = ws + OFF_W0T + (3 + net) * 16384;
    const float* w1t = ws + OFF_W1T + (3 + net) * 65536;
    const float* b0v = net ? b0B : b0C;
    const float* b1v = net ? b1B : b1C;
    float* sH1 = net ? sATb : sATc;
    unsigned short* pH = net ? sAhb : sAhc;
    unsigned short* pL = net ? sAlb : sAlc;

    {
        float4 a0 = {0, 0, 0, 0}, a1 = {0, 0, 0, 0};
        #pragma unroll 4
        for (int k = 0; k < 64; ++k) {
            float4 h = *(const float4*)(sYT + k * 16 + s4f);
            float2 w = *(const float2*)(w0t + k * 256 + c0);
            a0 = f4fma(w.x, h, a0);
            a1 = f4fma(w.y, h, a1);
        }
        *(float4*)(sH1 + c0 * 16 + s4f) = tanh4b(a0, b0v[c0]);
        *(float4*)(sH1 + c1 * 16 + s4f) = tanh4b(a1, b0v[c1]);
    }
    __syncthreads();

    {
        float4 a0 = {0, 0, 0, 0}, a1 = {0, 0, 0, 0};
        #pragma unroll 4
        for (int k = 0; k < 256; ++k) {
            float4 h = *(const float4*)(sH1 + k * 16 + s4f);
            float2 w = *(const float2*)(w1t + k * 256 + c0);
            a0 = f4fma(w.x, h, a0);
            a1 = f4fma(w.y, h, a1);
        }
        float4 h2a = tanh4b(a0, b1v[c0]);
        float4 h2b = tanh4b(a1, b1v[c1]);
        const int cblk = c0 >> 5, j0 = c0 & 7;
        const int lbase = ((c0 >> 3) & 3) << 4;
        float va[2][4] = {{h2a.x, h2a.y, h2a.z, h2a.w}, {h2b.x, h2b.y, h2b.z, h2b.w}};
        #pragma unroll
        for (int q = 0; q < 4; ++q) {
            int lb = ((s4f + q) & 15) | lbase;
            int base = (cblk * 64 + lb) * 8 + j0;
            unsigned short hi0, lo0, hi1, lo1;
            bf16split(va[0][q], hi0, lo0);
            bf16split(va[1][q], hi1, lo1);
            pH[base] = hi0; pH[base + 1] = hi1;
            pL[base] = lo0; pL[base + 1] = lo1;
        }
    }
    __syncthreads();

    const int wv = tid >> 6;
    const int l  = tid & 63;

    {
        const unsigned short* PC = (const unsigned short*)(ws + WS_FLOATS) + 2 * NPACK;
        const unsigned short* CH = PC;
        const unsigned short* CL = PC + NPACKC;
        f32x4 accc[4];
        #pragma unroll
        for (int t0 = 0; t0 < 4; ++t0) accc[t0] = (f32x4){0.f, 0.f, 0.f, 0.f};
        #pragma unroll 1
        for (int cb = 0; cb < 8; ++cb) {
            bf16x8 Ah = *(const bf16x8*)(sAhc + (cb * 64 + l) * 8);
            bf16x8 Al = *(const bf16x8*)(sAlc + (cb * 64 + l) * 8);
            #pragma unroll
            for (int t0 = 0; t0 < 4; ++t0) {
                int t = 4 * wv + t0;
                bf16x8 Bh = *(const bf16x8*)(CH + ((t * 8 + cb) * 64 + l) * 8);
                bf16x8 Bl = *(const bf16x8*)(CL + ((t * 8 + cb) * 64 + l) * 8);
                MFMA3(accc[t0], Ah, Al, Bh, Bl);
            }
        }
        #pragma unroll
        for (int t0 = 0; t0 < 4; ++t0) {
            int t = 4 * wv + t0;
            #pragma unroll
            for (int r = 0; r < 4; ++r)
                sC[((l >> 4) * 4 + r) * 1089 + t * 17 + (l & 15)] = accc[t0][r];
        }
    }

    f32x4 acc[16];
    #pragma unroll
    for (int t0 = 0; t0 < 16; ++t0) acc[t0] = (f32x4){0.f, 0.f, 0.f, 0.f};
    {
        const unsigned short* BH = (const unsigned short*)(ws + WS_FLOATS);
        const unsigned short* BL = BH + NPACK;
        #pragma unroll 1
        for (int cb = 0; cb < 8; ++cb) {
            bf16x8 Ah = *(const bf16x8*)(sAhb + (cb * 64 + l) * 8);
            bf16x8 Al = *(const bf16x8*)(sAlb + (cb * 64 + l) * 8);
            const unsigned short* bh = BH + ((wv * 16 * 8 + cb) * 64 + l) * 8;
            const unsigned short* bl = BL + ((wv * 16 * 8 + cb) * 64 + l) * 8;
            #pragma unroll
            for (int t0 = 0; t0 < 16; ++t0) {
                bf16x8 Bh = *(const bf16x8*)(bh + t0 * 4096);
                bf16x8 Bl = *(const bf16x8*)(bl + t0 * 4096);
                MFMA3(acc[t0], Ah, Al, Bh, Bl);
            }
        }
    }
    #pragma unroll
    for (int g = 0; g < 4; ++g) {
        float pd[4] = {0, 0, 0, 0}, ps[4] = {0, 0, 0, 0};
        #pragma unroll
        for (int tt = 0; tt < 4; ++tt) {
            int i = 16 * tt + (l & 15);
            #pragma unroll
            for (int r = 0; r < 4; ++r) {
                int s = (l >> 4) * 4 + r;
                float d = acc[g * 4 + tt][r];
                pd[r] = fmaf(d, sdE[s * 64 + i], pd[r]);
                ps[r] = fmaf(d, sdS[s * 64 + i], ps[r]);
            }
        }
        #pragma unroll
        for (int m = 1; m <= 8; m <<= 1) {
            #pragma unroll
            for (int r = 0; r < 4; ++r) {
                pd[r] += __shfl_xor(pd[r], m);
                ps[r] += __shfl_xor(ps[r], m);
            }
        }
        if ((l & 15) == 0) {
            int kpr = 4 * wv + g;
            #pragma unroll
            for (int r = 0; r < 4; ++r) {
                int s = (l >> 4) * 4 + r;
                sBdE[s * 64 + kpr] = pd[r];
                sBdS[s * 64 + kpr] = ps[r];
            }
        }
    }
    __syncthreads();

    {
        int s = tid >> 6;
        float beta = sScal[s * 4 + 1] / sScal[s * 4 + 0];
        sv[tid] = sBdS[tid] - beta * sBdE[tid];
    }
    __syncthreads();
    {
        int s = tid >> 6;
        unsafeAtomicAdd(&sScal[s * 4 + 2], sdE[tid] * sv[tid]);
    }
    __syncthreads();

    #pragma unroll
    for (int g = 0; g < 4; ++g) {
        float pq[4] = {0, 0, 0, 0};
        #pragma unroll
        for (int tt = 0; tt < 4; ++tt) {
            int i = 16 * tt + (l & 15);
            #pragma unroll
            for (int r = 0; r < 4; ++r) {
                int s = (l >> 4) * 4 + r;
                pq[r] = fmaf(acc[g * 4 + tt][r], sv[s * 64 + i], pq[r]);
            }
        }
        #pragma unroll
        for (int m = 1; m <= 8; m <<= 1) {
            #pragma unroll
            for (int r = 0; r < 4; ++r) pq[r] += __shfl_xor(pq[r], m);
        }
        if ((l & 15) == 0) {
            int kpr = 4 * wv + g;
            #pragma unroll
            for (int r = 0; r < 4; ++r) sq[((l >> 4) * 4 + r) * 64 + kpr] = pq[r];
        }
    }
    __syncthreads();

    if (tid < 256) {
        int s = tid >> 4, m = tid & 15;
        float gamma = sScal[s * 4 + 2] / sScal[s * 4 + 0];
        float r = 0.f;
        #pragma unroll 4
        for (int k = 0; k < 64; ++k) {
            float wvv = sq[s * 64 + k] - gamma * sBdE[s * 64 + k];
            r = fmaf(sC[s * 1089 + k * 17 + m], wvv, r);
        }
        sr[s * 16 + m] = r;
    }
    __syncthreads();
    {
        int s = tid >> 6, k = tid & 63;
        float o = 0.f;
        #pragma unroll
        for (int m2 = 0; m2 < 16; ++m2)
            o = fmaf(sC[s * 1089 + k * 17 + m2], sr[s * 16 + m2], o);
        int gi = sbase * 64 + tid;
        dout[gi] = dout[gi] + o;
    }
}

extern "C" void kernel_launch(void* const* d_in, const int* in_sizes, int n_in,
                              void* d_out, int out_size, void* d_ws, size_t ws_size,
                              hipStream_t stream)
{
    (void)in_sizes; (void)n_in; (void)out_size;
    const float* y = (const float*)d_in[1];
    const float* W0[5]; const float* b0[5]; const float* W1[5]; const float* b1[5]; const float* W2[5];
    for (int m = 0; m < 5; ++m) {
        int base = 2 + m * 5;
        W0[m] = (const float*)d_in[base + 0];
        b0[m] = (const float*)d_in[base + 1];
        W1[m] = (const float*)d_in[base + 2];
        b1[m] = (const float*)d_in[base + 3];
        W2[m] = (const float*)d_in[base + 4];
    }
    float* ws = (float*)d_ws;
    float* dout = (float*)d_out;
    if (ws_size < (size_t)WS4_FLOATS * sizeof(float)) return;   // WS4 proven available (R13/R14)
    const bool big3 = ws_size >= (size_t)WS5_FLOATS * sizeof(float);

    int ntr = 2236416 + NPACK + NPACKC + NPACKP + NK1;
    if (big3) ntr += NK3F;
    hipLaunchKernelGGL(k_transpose_all, dim3((ntr + 1023) / 1024), dim3(1024), 0, stream,
                       ws, 1,
                       W0[0], W0[1], W0[2], W0[3], W0[4],
                       W1[0], W1[1], W1[2], W1[3], W1[4],
                       W2[2], W2[3], W2[4]);

    hipLaunchKernelGGL(k1_grads_mf, dim3(1024), dim3(1024), 0, stream,
                       y, ws,
                       b0[0], b1[0], W2[0], b0[1], b1[1], W2[1],
                       ws + OFF_DE, ws + OFF_DS);

    const int k2_smem = 154112;
    const int k3_smem = 132416;
    hipFuncSetAttribute((const void*)k2_poisson_mf, hipFuncAttributeMaxDynamicSharedMemorySize, k2_smem);
    hipLaunchKernelGGL(k2_poisson_mf, dim3(1024), dim3(1024), k2_smem, stream,
                       y, ws, b0[2], b1[2], dout);

    if (big3) {
        hipFuncSetAttribute((const void*)k3_friction_mf3, hipFuncAttributeMaxDynamicSharedMemorySize, k3_smem);
        hipLaunchKernelGGL(k3_friction_mf3, dim3(1024), dim3(1024), k3_smem, stream,
                           y, ws, b0[3], b1[3], b0[4], b1[4], dout);
    } else {
        hipFuncSetAttribute((const void*)k3_friction_mf2, hipFuncAttributeMaxDynamicSharedMemorySize, k3_smem);
        hipLaunchKernelGGL(k3_friction_mf2, dim3(1024), dim3(1024), k3_smem, stream,
                           y, ws, b0[3], b1[3], b0[4], b1[4], dout);
    }
}

// Round 16
// 522.832 us; speedup vs baseline: 3.5358x; 1.0862x over previous
//
#include <hip/hip_runtime.h>
#include <math.h>

// Problem constants: B=16384 samples, DIM=64, WIDTH=256, DD=64, C2=16
#define SB 16      // samples per workgroup

// ws layout (float offsets)
#define OFF_W0T  0            // 5 x (64x256)
#define OFF_W1T  81920        // 5 x (256x256)
#define OFF_W2PT 409600       // (fallback only)
#define OFF_W2CT 925696       // (fallback only)
#define OFF_W2BT 1187840      // (fallback only)
#define OFF_DE   2236416      // 16384x64
#define OFF_DS   3284992      // 16384x64
#define WS_FLOATS 4337600
#define NPACK  1048576        // W2B packs
#define NPACKC 262144         // W2C packs
#define NPACKP 524288         // W2P packs (padded 2048)
#define WS3_FLOATS (WS_FLOATS + NPACK + NPACKC + NPACKP)
#define NK1 327680            // k1 packs
#define WS4_FLOATS (WS3_FLOATS + NK1)
#define NK3F 163840           // k3 forward packs (fC, fB)
#define WS5_FLOATS (WS4_FLOATS + NK3F)
#define NK2F 81920            // k2 forward packs (pA)
#define WS6_FLOATS (WS5_FLOATS + NK2F)

typedef __attribute__((ext_vector_type(8))) short bf16x8;
typedef __attribute__((ext_vector_type(4))) float f32x4;

__device__ __forceinline__ float4 f4fma(float a, float4 w, float4 c) {
    c.x = fmaf(a, w.x, c.x); c.y = fmaf(a, w.y, c.y);
    c.z = fmaf(a, w.z, c.z); c.w = fmaf(a, w.w, c.w);
    return c;
}

__device__ __forceinline__ float4 tanh4b(float4 a, float b) {
    return make_float4(tanhf(a.x + b), tanhf(a.y + b), tanhf(a.z + b), tanhf(a.w + b));
}

// fp32 -> bf16 hi (RNE) + bf16 lo (RNE of remainder)
__device__ __forceinline__ void bf16split(float x, unsigned short& hi, unsigned short& lo) {
    unsigned b = __float_as_uint(x);
    unsigned h = (b + 0x7FFFu + ((b >> 16) & 1u)) >> 16;
    hi = (unsigned short)h;
    float r = x - __uint_as_float(h << 16);
    unsigned rb = __float_as_uint(r);
    lo = (unsigned short)((rb + 0x7FFFu + ((rb >> 16) & 1u)) >> 16);
}

#define MFMA3(acc, Ah, Al, Bh, Bl)                                            \
    acc = __builtin_amdgcn_mfma_f32_16x16x32_bf16(Ah, Bh, acc, 0, 0, 0);      \
    acc = __builtin_amdgcn_mfma_f32_16x16x32_bf16(Al, Bh, acc, 0, 0, 0);      \
    acc = __builtin_amdgcn_mfma_f32_16x16x32_bf16(Ah, Bl, acc, 0, 0, 0);

// ---------------- merged transpose + bf16 fragment packing ----------------
__global__ __launch_bounds__(1024) void k_transpose_all(
    float* __restrict__ ws, int skipmid,
    const float* __restrict__ W0a, const float* __restrict__ W0b, const float* __restrict__ W0c,
    const float* __restrict__ W0d, const float* __restrict__ W0e,
    const float* __restrict__ W1a, const float* __restrict__ W1b, const float* __restrict__ W1c,
    const float* __restrict__ W1d, const float* __restrict__ W1e,
    const float* __restrict__ W2p, const float* __restrict__ W2c, const float* __restrict__ W2b)
{
    int t = blockIdx.x * blockDim.x + threadIdx.x;
    if (t >= 2236416) {
        int e = t - 2236416;
        unsigned short* PK = (unsigned short*)(ws + WS_FLOATS);
        if (e < NPACK) {
            int j = e & 7, lane = (e >> 3) & 63, c = (e >> 9) & 7, tt = e >> 12;
            int k = c * 32 + ((lane >> 4) & 3) * 8 + j;
            int n = tt * 16 + (lane & 15);
            unsigned short hi, lo;
            bf16split(W2b[n * 256 + k], hi, lo);
            PK[e] = hi; PK[NPACK + e] = lo;
        } else if (e < NPACK + NPACKC) {
            int e2 = e - NPACK;
            unsigned short* PC = PK + 2 * NPACK;
            int j = e2 & 7, lane = (e2 >> 3) & 63, c = (e2 >> 9) & 7, tt = e2 >> 12;
            int k = c * 32 + ((lane >> 4) & 3) * 8 + j;
            int n = tt * 16 + (lane & 15);
            unsigned short hi, lo;
            bf16split(W2c[n * 256 + k], hi, lo);
            PC[e2] = hi; PC[NPACKC + e2] = lo;
        } else if (e < NPACK + NPACKC + NPACKP) {
            int e2 = e - NPACK - NPACKC;
            unsigned short* PP = PK + 2 * NPACK + 2 * NPACKC;
            int j = e2 & 7, lane = (e2 >> 3) & 63, c = (e2 >> 9) & 7, tt = e2 >> 12;
            int k = c * 32 + ((lane >> 4) & 3) * 8 + j;
            int n = tt * 16 + (lane & 15);
            float v = (n < 2016) ? W2p[n * 256 + k] : 0.f;
            unsigned short hi, lo;
            bf16split(v, hi, lo);
            PP[e2] = hi; PP[NPACKP + e2] = lo;
        } else if (e < NPACK + NPACKC + NPACKP + NK1) {
            int e2 = e - NPACK - NPACKC - NPACKP;
            unsigned short* PQ = PK + 2 * (NPACK + NPACKC + NPACKP);
            int net = e2 / 163840;
            int r = e2 - net * 163840;
            const float* W0m = net ? W0b : W0a;
            const float* W1m = net ? W1b : W1a;
            float v;
            if (r < 16384) {
                int j = r & 7, lane = (r >> 3) & 63, cb = (r >> 9) & 1, tt = r >> 10;
                int k = cb * 32 + ((lane >> 4) & 3) * 8 + j;
                int n = tt * 16 + (lane & 15);
                v = W0m[n * 64 + k];
            } else if (r < 81920) {
                int r2 = r - 16384;
                int j = r2 & 7, lane = (r2 >> 3) & 63, cb = (r2 >> 9) & 7, tt = r2 >> 12;
                int k = cb * 32 + ((lane >> 4) & 3) * 8 + j;
                int n = tt * 16 + (lane & 15);
                v = W1m[n * 256 + k];
            } else if (r < 147456) {
                int r2 = r - 81920;
                int j = r2 & 7, lane = (r2 >> 3) & 63, cb = (r2 >> 9) & 7, tt = r2 >> 12;
                int k = cb * 32 + ((lane >> 4) & 3) * 8 + j;
                int n = tt * 16 + (lane & 15);
                v = W1m[k * 256 + n];
            } else {
                int r2 = r - 147456;
                int j = r2 & 7, lane = (r2 >> 3) & 63, cb = (r2 >> 9) & 7, tt = r2 >> 12;
                int k = cb * 32 + ((lane >> 4) & 3) * 8 + j;
                int n = tt * 16 + (lane & 15);
                v = W0m[k * 64 + n];
            }
            unsigned short hi, lo;
            bf16split(v, hi, lo);
            PQ[e2] = hi; PQ[NK1 + e2] = lo;
        } else if (e < NPACK + NPACKC + NPACKP + NK1 + NK3F) {
            int e2 = e - NPACK - NPACKC - NPACKP - NK1;
            unsigned short* PQ = PK + 2 * (NPACK + NPACKC + NPACKP + NK1);
            int net = e2 / 81920;
            int r = e2 - net * 81920;
            const float* W0m = net ? W0e : W0d;
            const float* W1m = net ? W1e : W1d;
            float v;
            if (r < 16384) {
                int j = r & 7, lane = (r >> 3) & 63, cb = (r >> 9) & 1, tt = r >> 10;
                int k = cb * 32 + ((lane >> 4) & 3) * 8 + j;
                int n = tt * 16 + (lane & 15);
                v = W0m[n * 64 + k];
            } else {
                int r2 = r - 16384;
                int j = r2 & 7, lane = (r2 >> 3) & 63, cb = (r2 >> 9) & 7, tt = r2 >> 12;
                int k = cb * 32 + ((lane >> 4) & 3) * 8 + j;
                int n = tt * 16 + (lane & 15);
                v = W1m[n * 256 + k];
            }
            unsigned short hi, lo;
            bf16split(v, hi, lo);
            PQ[e2] = hi; PQ[NK3F + e2] = lo;
        } else if (e < NPACK + NPACKC + NPACKP + NK1 + NK3F + NK2F) {
            // k2 forward packs (pA net: W0c/W1c)
            int r = e - NPACK - NPACKC - NPACKP - NK1 - NK3F;
            unsigned short* PQ = PK + 2 * (NPACK + NPACKC + NPACKP + NK1 + NK3F);
            float v;
            if (r < 16384) {
                int j = r & 7, lane = (r >> 3) & 63, cb = (r >> 9) & 1, tt = r >> 10;
                int k = cb * 32 + ((lane >> 4) & 3) * 8 + j;
                int n = tt * 16 + (lane & 15);
                v = W0c[n * 64 + k];
            } else {
                int r2 = r - 16384;
                int j = r2 & 7, lane = (r2 >> 3) & 63, cb = (r2 >> 9) & 7, tt = r2 >> 12;
                int k = cb * 32 + ((lane >> 4) & 3) * 8 + j;
                int n = tt * 16 + (lane & 15);
                v = W1c[n * 256 + k];
            }
            unsigned short hi, lo;
            bf16split(v, hi, lo);
            PQ[r] = hi; PQ[NK2F + r] = lo;
        }
        return;
    }
    if (skipmid && t >= 409600) return;
    const float* in;
    int o, R, C;
    float* out;
    if (t < 81920) {
        int m = t >> 14; o = t & 16383;
        const float* W0s[5] = {W0a, W0b, W0c, W0d, W0e};
        in = W0s[m]; out = ws + OFF_W0T + m * 16384; R = 256; C = 64;
    } else if (t < 409600) {
        int t2 = t - 81920;
        int m = t2 >> 16; o = t2 & 65535;
        const float* W1s[5] = {W1a, W1b, W1c, W1d, W1e};
        in = W1s[m]; out = ws + OFF_W1T + m * 65536; R = 256; C = 256;
    } else if (t < 925696) {
        o = t - 409600; in = W2p; out = ws + OFF_W2PT; R = 2016; C = 256;
    } else if (t < 1187840) {
        o = t - 925696; in = W2c; out = ws + OFF_W2CT; R = 1024; C = 256;
    } else {
        o = t - 1187840; in = W2b; out = ws + OFF_W2BT; R = 4096; C = 256;
    }
    int c = o / R, r = o - c * R;
    out[o] = in[r * C + c];
}

// ---------------- K1 mf: all four GEMM passes via split-bf16 MFMA ----------------
__global__ __launch_bounds__(1024, 2) void k1_grads_mf(
    const float* __restrict__ y, const float* __restrict__ ws,
    const float* __restrict__ b0E, const float* __restrict__ b1E, const float* __restrict__ w2E,
    const float* __restrict__ b0S, const float* __restrict__ b1S, const float* __restrict__ w2S,
    float* __restrict__ odE, float* __restrict__ odS)
{
    __shared__ float sH1f[4352];
    __shared__ unsigned short yAh[1024], yAl[1024];
    __shared__ unsigned short bAh[4096], bAl[4096];
    __shared__ unsigned short bBh[4096], bBl[4096];
    __shared__ float sPart[4352];

    const int tid = threadIdx.x;
    const int sbase = blockIdx.x * SB;
    const int wv = tid >> 6, l = tid & 63;

    {
        int s = tid >> 6, k = tid & 63;
        unsigned short hi, lo;
        bf16split(y[sbase * 64 + tid], hi, lo);
        int addr = ((k >> 5) * 64 + (s | (((k >> 3) & 3) << 4))) * 8 + (k & 7);
        yAh[addr] = hi; yAl[addr] = lo;
    }
    __syncthreads();

    const unsigned short* K1H = (const unsigned short*)(ws + WS3_FLOATS);
    const unsigned short* K1L = K1H + NK1;

    for (int m = 0; m < 2; ++m) {
        const float* b0 = m ? b0S : b0E;
        const float* b1 = m ? b1S : b1E;
        const float* w2 = m ? w2S : w2E;
        float* outg = m ? odS : odE;
        const int pbase = m * 163840;

        {
            const unsigned short* PH = K1H + pbase;
            const unsigned short* PL = K1L + pbase;
            f32x4 acc = {0.f, 0.f, 0.f, 0.f};
            #pragma unroll
            for (int cb = 0; cb < 2; ++cb) {
                bf16x8 Ah = *(const bf16x8*)(yAh + (cb * 64 + l) * 8);
                bf16x8 Al = *(const bf16x8*)(yAl + (cb * 64 + l) * 8);
                bf16x8 Bh = *(const bf16x8*)(PH + ((wv * 2 + cb) * 64 + l) * 8);
                bf16x8 Bl = *(const bf16x8*)(PL + ((wv * 2 + cb) * 64 + l) * 8);
                MFMA3(acc, Ah, Al, Bh, Bl);
            }
            int c = 16 * wv + (l & 15);
            float bb = b0[c];
            const int cblk = c >> 5, j0 = c & 7;
            const int lb2 = ((c >> 3) & 3) << 4;
            #pragma unroll
            for (int r = 0; r < 4; ++r) {
                int s = (l >> 4) * 4 + r;
                float h1 = tanhf(acc[r] + bb);
                sH1f[c * 17 + s] = h1;
                unsigned short hi, lo;
                bf16split(h1, hi, lo);
                int base = (cblk * 64 + (s | lb2)) * 8 + j0;
                bBh[base] = hi; bBl[base] = lo;
            }
        }
        __syncthreads();

        {
            const unsigned short* PH = K1H + pbase + 16384;
            const unsigned short* PL = K1L + pbase + 16384;
            f32x4 acc = {0.f, 0.f, 0.f, 0.f};
            #pragma unroll 1
            for (int cb = 0; cb < 8; ++cb) {
                bf16x8 Ah = *(const bf16x8*)(bBh + (cb * 64 + l) * 8);
                bf16x8 Al = *(const bf16x8*)(bBl + (cb * 64 + l) * 8);
                bf16x8 Bh = *(const bf16x8*)(PH + ((wv * 8 + cb) * 64 + l) * 8);
                bf16x8 Bl = *(const bf16x8*)(PL + ((wv * 8 + cb) * 64 + l) * 8);
                MFMA3(acc, Ah, Al, Bh, Bl);
            }
            int c = 16 * wv + (l & 15);
            float bb = b1[c], wvv = w2[c];
            const int cblk = c >> 5, j0 = c & 7;
            const int lb2 = ((c >> 3) & 3) << 4;
            #pragma unroll
            for (int r = 0; r < 4; ++r) {
                int s = (l >> 4) * 4 + r;
                float h2 = tanhf(acc[r] + bb);
                float g2 = (1.f - h2 * h2) * wvv;
                unsigned short hi, lo;
                bf16split(g2, hi, lo);
                int base = (cblk * 64 + (s | lb2)) * 8 + j0;
                bAh[base] = hi; bAl[base] = lo;
            }
        }
        __syncthreads();

        {
            const unsigned short* PH = K1H + pbase + 81920;
            const unsigned short* PL = K1L + pbase + 81920;
            f32x4 acc = {0.f, 0.f, 0.f, 0.f};
            #pragma unroll 1
            for (int cb = 0; cb < 8; ++cb) {
                bf16x8 Ah = *(const bf16x8*)(bAh + (cb * 64 + l) * 8);
                bf16x8 Al = *(const bf16x8*)(bAl + (cb * 64 + l) * 8);
                bf16x8 Bh = *(const bf16x8*)(PH + ((wv * 8 + cb) * 64 + l) * 8);
                bf16x8 Bl = *(const bf16x8*)(PL + ((wv * 8 + cb) * 64 + l) * 8);
                MFMA3(acc, Ah, Al, Bh, Bl);
            }
            int c = 16 * wv + (l & 15);
            const int cblk = c >> 5, j0 = c & 7;
            const int lb2 = ((c >> 3) & 3) << 4;
            #pragma unroll
            for (int r = 0; r < 4; ++r) {
                int s = (l >> 4) * 4 + r;
                float h1 = sH1f[c * 17 + s];
                float g1 = (1.f - h1 * h1) * acc[r];
                unsigned short hi, lo;
                bf16split(g1, hi, lo);
                int base = (cblk * 64 + (s | lb2)) * 8 + j0;
                bBh[base] = hi; bBl[base] = lo;
            }
        }
        __syncthreads();

        {
            const unsigned short* PH = K1H + pbase + 147456;
            const unsigned short* PL = K1L + pbase + 147456;
            const int t = wv & 3, kh = wv >> 2;
            f32x4 acc = {0.f, 0.f, 0.f, 0.f};
            #pragma unroll
            for (int q = 0; q < 2; ++q) {
                int cb = 2 * kh + q;
                bf16x8 Ah = *(const bf16x8*)(bBh + (cb * 64 + l) * 8);
                bf16x8 Al = *(const bf16x8*)(bBl + (cb * 64 + l) * 8);
                bf16x8 Bh = *(const bf16x8*)(PH + ((t * 8 + cb) * 64 + l) * 8);
                bf16x8 Bl = *(const bf16x8*)(PL + ((t * 8 + cb) * 64 + l) * 8);
                MFMA3(acc, Ah, Al, Bh, Bl);
            }
            #pragma unroll
            for (int r = 0; r < 4; ++r)
                sPart[(kh * 4 + t) * 272 + (l & 15) * 17 + ((l >> 4) * 4 + r)] = acc[r];
        }
        __syncthreads();
        {
            int s = tid >> 6, i = tid & 63;
            float v = 0.f;
            #pragma unroll
            for (int kh = 0; kh < 4; ++kh)
                v += sPart[(kh * 4 + (i >> 4)) * 272 + (i & 15) * 17 + s];
            outg[sbase * 64 + tid] = v;
        }
        __syncthreads();
    }
}

// ---------------- K2 mf (fallback): forwards fp32, a-GEMM MFMA ----------------
__global__ __launch_bounds__(1024, 4) void k2_poisson_mf(
    const float* __restrict__ y, const float* __restrict__ ws,
    const float* __restrict__ b0P, const float* __restrict__ b1P,
    float* __restrict__ dout)
{
    extern __shared__ float smem[];
    float* sa   = smem;
    unsigned short* sAh = (unsigned short*)(smem + 32384);
    unsigned short* sAl = (unsigned short*)(smem + 34432);
    float* sdE  = smem + 36480;
    float* sdS  = sdE + 1024;
    float* sH1T = sa;
    float* syT  = sa + 4096;

    const int tid = threadIdx.x;
    const int sbase = blockIdx.x * SB;
    const float* gdE = ws + OFF_DE;
    const float* gdS = ws + OFF_DS;

    {
        int s = tid >> 6, i = tid & 63;
        syT[i * 16 + s] = y[sbase * 64 + tid];
        sdE[tid] = gdE[sbase * 64 + tid];
        sdS[tid] = gdS[sbase * 64 + tid];
    }
    __syncthreads();

    const int c  = tid & 255;
    const int sg = tid >> 8;
    const int s4 = sg * 4;

    {
        const float* w0t = ws + OFF_W0T + 2 * 16384;
        float4 acc = {0, 0, 0, 0};
        #pragma unroll 4
        for (int k = 0; k < 64; ++k) {
            float w = w0t[k * 256 + c];
            float4 yv = *(const float4*)(syT + k * 16 + s4);
            acc = f4fma(w, yv, acc);
        }
        *(float4*)(sH1T + c * 16 + s4) = tanh4b(acc, b0P[c]);
    }
    __syncthreads();

    {
        const float* w1t = ws + OFF_W1T + 2 * 65536;
        float4 acc = {0, 0, 0, 0};
        #pragma unroll 4
        for (int k = 0; k < 256; ++k) {
            float w = w1t[k * 256 + c];
            float4 hv = *(const float4*)(sH1T + k * 16 + s4);
            acc = f4fma(w, hv, acc);
        }
        float4 h2 = tanh4b(acc, b1P[c]);
        const int cblk = c >> 5, j0 = c & 7;
        const int lbase = ((c >> 3) & 3) << 4;
        float va[4] = {h2.x, h2.y, h2.z, h2.w};
        #pragma unroll
        for (int q = 0; q < 4; ++q) {
            int lb = ((s4 + q) & 15) | lbase;
            int base = (cblk * 64 + lb) * 8 + j0;
            unsigned short hi, lo;
            bf16split(va[q], hi, lo);
            sAh[base] = hi;
            sAl[base] = lo;
        }
    }
    __syncthreads();

    {
        const unsigned short* PP = (const unsigned short*)(ws + WS_FLOATS) + 2 * NPACK + 2 * NPACKC;
        const unsigned short* PH = PP;
        const unsigned short* PL = PP + NPACKP;
        const int wv = tid >> 6, l = tid & 63;
        f32x4 accp[8];
        #pragma unroll
        for (int t0 = 0; t0 < 8; ++t0) accp[t0] = (f32x4){0.f, 0.f, 0.f, 0.f};
        #pragma unroll 1
        for (int cb = 0; cb < 8; ++cb) {
            bf16x8 Ah = *(const bf16x8*)(sAh + (cb * 64 + l) * 8);
            bf16x8 Al = *(const bf16x8*)(sAl + (cb * 64 + l) * 8);
            #pragma unroll
            for (int t0 = 0; t0 < 8; ++t0) {
                int t = 8 * wv + t0;
                bf16x8 Bh = *(const bf16x8*)(PH + ((t * 8 + cb) * 64 + l) * 8);
                bf16x8 Bl = *(const bf16x8*)(PL + ((t * 8 + cb) * 64 + l) * 8);
                MFMA3(accp[t0], Ah, Al, Bh, Bl);
            }
        }
        #pragma unroll
        for (int t0 = 0; t0 < 8; ++t0) {
            int n = (8 * wv + t0) * 16 + (l & 15);
            if (n < 2016) {
                #pragma unroll
                for (int r = 0; r < 4; ++r)
                    sa[((l >> 4) * 4 + r) * 2024 + n] = accp[t0][r];
            }
        }
    }
    __syncthreads();

    {
        const int s = tid >> 6;
        const int i = tid & 63;
        const int ib = i * (i - 1) / 2;
        const float* ap = sa + s * 2024;
        const float* dep = sdE + s * 64;
        const float* dsp = sdS + s * 64;

        float adE = 0.f, adS = 0.f;
        int trij = 0;
        #pragma unroll 4
        for (int j = 0; j < 64; ++j) {
            int t = (j < i) ? (ib + j) : (trij + i);
            float sel = (j < i) ? 1.f : ((j == i) ? 0.f : -1.f);
            float cc = sel * ap[t];
            adE = fmaf(cc, dep[j], adE);
            adS = fmaf(cc, dsp[j], adS);
            trij += j;
        }

        float de = dep[i], dsv = dsp[i];
        float p0 = de * adS;
        float p1 = de * dsv;
        float p2 = dsv * dsv;
        #pragma unroll
        for (int m = 1; m <= 32; m <<= 1) {
            p0 += __shfl_xor(p0, m);
            p1 += __shfl_xor(p1, m);
            p2 += __shfl_xor(p2, m);
        }
        float inv = 1.f / p2;
        dout[sbase * 64 + tid] = adE + (p0 * dsv - p1 * adS) * inv;
    }
}

// ---------------- K2 mf2: forwards AND a-GEMM via split-bf16 MFMA ----------------
// sa region [0..32384) aliased during forwards: yA packs @0..1024f, H1 packs @1024..5120f
__global__ __launch_bounds__(1024, 4) void k2_poisson_mf2(
    const float* __restrict__ y, const float* __restrict__ ws,
    const float* __restrict__ b0P, const float* __restrict__ b1P,
    float* __restrict__ dout)
{
    extern __shared__ float smem[];
    float* sa   = smem;                                   // 16 x 2024
    unsigned short* yAh = (unsigned short*)(smem);        // 1024 us
    unsigned short* yAl = (unsigned short*)(smem + 512);
    unsigned short* h1H = (unsigned short*)(smem + 1024); // 4096 us
    unsigned short* h1L = (unsigned short*)(smem + 3072);
    unsigned short* sAh = (unsigned short*)(smem + 32384);
    unsigned short* sAl = (unsigned short*)(smem + 34432);
    float* sdE  = smem + 36480;
    float* sdS  = sdE + 1024;

    const int tid = threadIdx.x;
    const int sbase = blockIdx.x * SB;
    const float* gdE = ws + OFF_DE;
    const float* gdS = ws + OFF_DS;

    {
        int s = tid >> 6, k = tid & 63;
        unsigned short hi, lo;
        bf16split(y[sbase * 64 + tid], hi, lo);
        int addr = ((k >> 5) * 64 + (s | (((k >> 3) & 3) << 4))) * 8 + (k & 7);
        yAh[addr] = hi; yAl[addr] = lo;
        sdE[tid] = gdE[sbase * 64 + tid];
        sdS[tid] = gdS[sbase * 64 + tid];
    }
    __syncthreads();

    const int wv = tid >> 6, l = tid & 63;
    const unsigned short* F2H = (const unsigned short*)(ws + WS5_FLOATS);
    const unsigned short* F2L = F2H + NK2F;

    // L0 (MFMA): wave owns tile wv
    {
        f32x4 acc = {0.f, 0.f, 0.f, 0.f};
        #pragma unroll
        for (int cb = 0; cb < 2; ++cb) {
            bf16x8 Ah = *(const bf16x8*)(yAh + (cb * 64 + l) * 8);
            bf16x8 Al = *(const bf16x8*)(yAl + (cb * 64 + l) * 8);
            bf16x8 Bh = *(const bf16x8*)(F2H + ((wv * 2 + cb) * 64 + l) * 8);
            bf16x8 Bl = *(const bf16x8*)(F2L + ((wv * 2 + cb) * 64 + l) * 8);
            MFMA3(acc, Ah, Al, Bh, Bl);
        }
        int c = 16 * wv + (l & 15);
        float bb = b0P[c];
        const int cblk = c >> 5, j0 = c & 7;
        const int lb2 = ((c >> 3) & 3) << 4;
        #pragma unroll
        for (int r = 0; r < 4; ++r) {
            int s = (l >> 4) * 4 + r;
            float h1 = tanhf(acc[r] + bb);
            unsigned short hi, lo;
            bf16split(h1, hi, lo);
            int base = (cblk * 64 + (s | lb2)) * 8 + j0;
            h1H[base] = hi; h1L[base] = lo;
        }
    }
    __syncthreads();

    // L1 (MFMA): wave owns tile wv; H2 -> A-packs
    {
        f32x4 acc = {0.f, 0.f, 0.f, 0.f};
        #pragma unroll 1
        for (int cb = 0; cb < 8; ++cb) {
            bf16x8 Ah = *(const bf16x8*)(h1H + (cb * 64 + l) * 8);
            bf16x8 Al = *(const bf16x8*)(h1L + (cb * 64 + l) * 8);
            bf16x8 Bh = *(const bf16x8*)(F2H + 16384 + ((wv * 8 + cb) * 64 + l) * 8);
            bf16x8 Bl = *(const bf16x8*)(F2L + 16384 + ((wv * 8 + cb) * 64 + l) * 8);
            MFMA3(acc, Ah, Al, Bh, Bl);
        }
        int c = 16 * wv + (l & 15);
        float bb = b1P[c];
        const int cblk = c >> 5, j0 = c & 7;
        const int lb2 = ((c >> 3) & 3) << 4;
        #pragma unroll
        for (int r = 0; r < 4; ++r) {
            int s = (l >> 4) * 4 + r;
            float h2 = tanhf(acc[r] + bb);
            unsigned short hi, lo;
            bf16split(h2, hi, lo);
            int base = (cblk * 64 + (s | lb2)) * 8 + j0;
            sAh[base] = hi; sAl[base] = lo;
        }
    }
    __syncthreads();   // y/H1 packs dead; sa writable

    // P3: a-GEMM via MFMA
    {
        const unsigned short* PP = (const unsigned short*)(ws + WS_FLOATS) + 2 * NPACK + 2 * NPACKC;
        const unsigned short* PH = PP;
        const unsigned short* PL = PP + NPACKP;
        f32x4 accp[8];
        #pragma unroll
        for (int t0 = 0; t0 < 8; ++t0) accp[t0] = (f32x4){0.f, 0.f, 0.f, 0.f};
        #pragma unroll 1
        for (int cb = 0; cb < 8; ++cb) {
            bf16x8 Ah = *(const bf16x8*)(sAh + (cb * 64 + l) * 8);
            bf16x8 Al = *(const bf16x8*)(sAl + (cb * 64 + l) * 8);
            #pragma unroll
            for (int t0 = 0; t0 < 8; ++t0) {
                int t = 8 * wv + t0;
                bf16x8 Bh = *(const bf16x8*)(PH + ((t * 8 + cb) * 64 + l) * 8);
                bf16x8 Bl = *(const bf16x8*)(PL + ((t * 8 + cb) * 64 + l) * 8);
                MFMA3(accp[t0], Ah, Al, Bh, Bl);
            }
        }
        #pragma unroll
        for (int t0 = 0; t0 < 8; ++t0) {
            int n = (8 * wv + t0) * 16 + (l & 15);
            if (n < 2016) {
                #pragma unroll
                for (int r = 0; r < 4; ++r)
                    sa[((l >> 4) * 4 + r) * 2024 + n] = accp[t0][r];
            }
        }
    }
    __syncthreads();

    // P4: gather
    {
        const int s = tid >> 6;
        const int i = tid & 63;
        const int ib = i * (i - 1) / 2;
        const float* ap = sa + s * 2024;
        const float* dep = sdE + s * 64;
        const float* dsp = sdS + s * 64;

        float adE = 0.f, adS = 0.f;
        int trij = 0;
        #pragma unroll 4
        for (int j = 0; j < 64; ++j) {
            int t = (j < i) ? (ib + j) : (trij + i);
            float sel = (j < i) ? 1.f : ((j == i) ? 0.f : -1.f);
            float cc = sel * ap[t];
            adE = fmaf(cc, dep[j], adE);
            adS = fmaf(cc, dsp[j], adS);
            trij += j;
        }

        float de = dep[i], dsv = dsp[i];
        float p0 = de * adS;
        float p1 = de * dsv;
        float p2 = dsv * dsv;
        #pragma unroll
        for (int m = 1; m <= 32; m <<= 1) {
            p0 += __shfl_xor(p0, m);
            p1 += __shfl_xor(p1, m);
            p2 += __shfl_xor(p2, m);
        }
        float inv = 1.f / p2;
        dout[sbase * 64 + tid] = adE + (p0 * dsv - p1 * adS) * inv;
    }
}

// ---------------- K3 mf3: forwards AND C AND Bm via split-bf16 MFMA ----------------
__global__ __launch_bounds__(1024, 4) void k3_friction_mf3(
    const float* __restrict__ y, const float* __restrict__ ws,
    const float* __restrict__ b0C, const float* __restrict__ b1C,
    const float* __restrict__ b0B, const float* __restrict__ b1B,
    float* __restrict__ dout)
{
    extern __shared__ float smem[];
    unsigned short* yAh = (unsigned short*)(smem);
    unsigned short* yAl = (unsigned short*)(smem + 512);
    unsigned short* sAhc = (unsigned short*)(smem + 1024);
    unsigned short* sAlc = (unsigned short*)(smem + 3072);
    unsigned short* sAhb = (unsigned short*)(smem + 5120);
    unsigned short* sAlb = (unsigned short*)(smem + 7168);
    unsigned short* h1ch = (unsigned short*)(smem + 9216);
    unsigned short* h1cl = (unsigned short*)(smem + 11264);
    unsigned short* h1bh = (unsigned short*)(smem + 13312);
    unsigned short* h1bl = (unsigned short*)(smem + 15360);
    float* sC   = smem + 9216;
    float* sdE  = smem + 26640;
    float* sdS  = smem + 27664;
    float* sBdE = smem + 28688;
    float* sBdS = smem + 29712;
    float* sv   = smem + 30736;
    float* sq   = smem + 31760;
    float* sScal= smem + 32784;
    float* sr   = smem + 32848;

    const int tid = threadIdx.x;
    const int sbase = blockIdx.x * SB;
    const float* gdE = ws + OFF_DE;
    const float* gdS = ws + OFF_DS;

    {
        int s = tid >> 6, k = tid & 63;
        unsigned short hi, lo;
        bf16split(y[sbase * 64 + tid], hi, lo);
        int addr = ((k >> 5) * 64 + (s | (((k >> 3) & 3) << 4))) * 8 + (k & 7);
        yAh[addr] = hi; yAl[addr] = lo;
        sdE[tid] = gdE[sbase * 64 + tid];
        sdS[tid] = gdS[sbase * 64 + tid];
    }
    if (tid < 64) sScal[tid] = 0.f;
    __syncthreads();

    {
        int s = tid >> 6;
        float de = sdE[tid];
        unsafeAtomicAdd(&sScal[s * 4 + 0], de * de);
        unsafeAtomicAdd(&sScal[s * 4 + 1], de * sdS[tid]);
    }

    const int wv = tid >> 6;
    const int l  = tid & 63;
    const int netw = wv >> 3;
    const int tb   = wv & 7;
    const float* b0v = netw ? b0B : b0C;
    const float* b1v = netw ? b1B : b1C;
    unsigned short* h1H = netw ? h1bh : h1ch;
    unsigned short* h1L = netw ? h1bl : h1cl;
    unsigned short* h2H = netw ? sAhb : sAhc;
    unsigned short* h2L = netw ? sAlb : sAlc;

    const unsigned short* F3H = (const unsigned short*)(ws + WS4_FLOATS);
    const unsigned short* F3L = F3H + NK3F;

    #pragma unroll
    for (int jj = 0; jj < 2; ++jj) {
        int t = tb + 8 * jj;
        f32x4 acc = {0.f, 0.f, 0.f, 0.f};
        #pragma unroll
        for (int cb = 0; cb < 2; ++cb) {
            bf16x8 Ah = *(const bf16x8*)(yAh + (cb * 64 + l) * 8);
            bf16x8 Al = *(const bf16x8*)(yAl + (cb * 64 + l) * 8);
            const unsigned short* bh = F3H + netw * 81920 + ((t * 2 + cb) * 64 + l) * 8;
            const unsigned short* bl = F3L + netw * 81920 + ((t * 2 + cb) * 64 + l) * 8;
            bf16x8 Bh = *(const bf16x8*)(bh);
            bf16x8 Bl = *(const bf16x8*)(bl);
            MFMA3(acc, Ah, Al, Bh, Bl);
        }
        int c = 16 * t + (l & 15);
        float bb = b0v[c];
        const int cblk = c >> 5, j0 = c & 7;
        const int lb2 = ((c >> 3) & 3) << 4;
        #pragma unroll
        for (int r = 0; r < 4; ++r) {
            int s = (l >> 4) * 4 + r;
            float h1 = tanhf(acc[r] + bb);
            unsigned short hi, lo;
            bf16split(h1, hi, lo);
            int base = (cblk * 64 + (s | lb2)) * 8 + j0;
            h1H[base] = hi; h1L[base] = lo;
        }
    }
    __syncthreads();

    #pragma unroll
    for (int jj = 0; jj < 2; ++jj) {
        int t = tb + 8 * jj;
        f32x4 acc = {0.f, 0.f, 0.f, 0.f};
        #pragma unroll 1
        for (int cb = 0; cb < 8; ++cb) {
            bf16x8 Ah = *(const bf16x8*)(h1H + (cb * 64 + l) * 8);
            bf16x8 Al = *(const bf16x8*)(h1L + (cb * 64 + l) * 8);
            const unsigned short* bh = F3H + netw * 81920 + 16384 + ((t * 8 + cb) * 64 + l) * 8;
            const unsigned short* bl = F3L + netw * 81920 + 16384 + ((t * 8 + cb) * 64 + l) * 8;
            bf16x8 Bh = *(const bf16x8*)(bh);
            bf16x8 Bl = *(const bf16x8*)(bl);
            MFMA3(acc, Ah, Al, Bh, Bl);
        }
        int c = 16 * t + (l & 15);
        float bb = b1v[c];
        const int cblk = c >> 5, j0 = c & 7;
        const int lb2 = ((c >> 3) & 3) << 4;
        #pragma unroll
        for (int r = 0; r < 4; ++r) {
            int s = (l >> 4) * 4 + r;
            float h2 = tanhf(acc[r] + bb);
            unsigned short hi, lo;
            bf16split(h2, hi, lo);
            int base = (cblk * 64 + (s | lb2)) * 8 + j0;
            h2H[base] = hi; h2L[base] = lo;
        }
    }
    __syncthreads();

    {
        const unsigned short* PC = (const unsigned short*)(ws + WS_FLOATS) + 2 * NPACK;
        const unsigned short* CH = PC;
        const unsigned short* CL = PC + NPACKC;
        f32x4 accc[4];
        #pragma unroll
        for (int t0 = 0; t0 < 4; ++t0) accc[t0] = (f32x4){0.f, 0.f, 0.f, 0.f};
        #pragma unroll 1
        for (int cb = 0; cb < 8; ++cb) {
            bf16x8 Ah = *(const bf16x8*)(sAhc + (cb * 64 + l) * 8);
            bf16x8 Al = *(const bf16x8*)(sAlc + (cb * 64 + l) * 8);
            #pragma unroll
            for (int t0 = 0; t0 < 4; ++t0) {
                int t = 4 * wv + t0;
                bf16x8 Bh = *(const bf16x8*)(CH + ((t * 8 + cb) * 64 + l) * 8);
                bf16x8 Bl = *(const bf16x8*)(CL + ((t * 8 + cb) * 64 + l) * 8);
                MFMA3(accc[t0], Ah, Al, Bh, Bl);
            }
        }
        #pragma unroll
        for (int t0 = 0; t0 < 4; ++t0) {
            int t = 4 * wv + t0;
            #pragma unroll
            for (int r = 0; r < 4; ++r)
                sC[((l >> 4) * 4 + r) * 1089 + t * 17 + (l & 15)] = accc[t0][r];
        }
    }

    f32x4 acc[16];
    #pragma unroll
    for (int t0 = 0; t0 < 16; ++t0) acc[t0] = (f32x4){0.f, 0.f, 0.f, 0.f};
    {
        const unsigned short* BH = (const unsigned short*)(ws + WS_FLOATS);
        const unsigned short* BL = BH + NPACK;
        #pragma unroll 1
        for (int cb = 0; cb < 8; ++cb) {
            bf16x8 Ah = *(const bf16x8*)(sAhb + (cb * 64 + l) * 8);
            bf16x8 Al = *(const bf16x8*)(sAlb + (cb * 64 + l) * 8);
            const unsigned short* bh = BH + ((wv * 16 * 8 + cb) * 64 + l) * 8;
            const unsigned short* bl = BL + ((wv * 16 * 8 + cb) * 64 + l) * 8;
            #pragma unroll
            for (int t0 = 0; t0 < 16; ++t0) {
                bf16x8 Bh = *(const bf16x8*)(bh + t0 * 4096);
                bf16x8 Bl = *(const bf16x8*)(bl + t0 * 4096);
                MFMA3(acc[t0], Ah, Al, Bh, Bl);
            }
        }
    }
    #pragma unroll
    for (int g = 0; g < 4; ++g) {
        float pd[4] = {0, 0, 0, 0}, ps[4] = {0, 0, 0, 0};
        #pragma unroll
        for (int tt = 0; tt < 4; ++tt) {
            int i = 16 * tt + (l & 15);
            #pragma unroll
            for (int r = 0; r < 4; ++r) {
                int s = (l >> 4) * 4 + r;
                float d = acc[g * 4 + tt][r];
                pd[r] = fmaf(d, sdE[s * 64 + i], pd[r]);
                ps[r] = fmaf(d, sdS[s * 64 + i], ps[r]);
            }
        }
        #pragma unroll
        for (int m = 1; m <= 8; m <<= 1) {
            #pragma unroll
            for (int r = 0; r < 4; ++r) {
                pd[r] += __shfl_xor(pd[r], m);
                ps[r] += __shfl_xor(ps[r], m);
            }
        }
        if ((l & 15) == 0) {
            int kpr = 4 * wv + g;
            #pragma unroll
            for (int r = 0; r < 4; ++r) {
                int s = (l >> 4) * 4 + r;
                sBdE[s * 64 + kpr] = pd[r];
                sBdS[s * 64 + kpr] = ps[r];
            }
        }
    }
    __syncthreads();

    {
        int s = tid >> 6;
        float beta = sScal[s * 4 + 1] / sScal[s * 4 + 0];
        sv[tid] = sBdS[tid] - beta * sBdE[tid];
    }
    __syncthreads();
    {
        int s = tid >> 6;
        unsafeAtomicAdd(&sScal[s * 4 + 2], sdE[tid] * sv[tid]);
    }
    __syncthreads();

    #pragma unroll
    for (int g = 0; g < 4; ++g) {
        float pq[4] = {0, 0, 0, 0};
        #pragma unroll
        for (int tt = 0; tt < 4; ++tt) {
            int i = 16 * tt + (l & 15);
            #pragma unroll
            for (int r = 0; r < 4; ++r) {
                int s = (l >> 4) * 4 + r;
                pq[r] = fmaf(acc[g * 4 + tt][r], sv[s * 64 + i], pq[r]);
            }
        }
        #pragma unroll
        for (int m = 1; m <= 8; m <<= 1) {
            #pragma unroll
            for (int r = 0; r < 4; ++r) pq[r] += __shfl_xor(pq[r], m);
        }
        if ((l & 15) == 0) {
            int kpr = 4 * wv + g;
            #pragma unroll
            for (int r = 0; r < 4; ++r) sq[((l >> 4) * 4 + r) * 64 + kpr] = pq[r];
        }
    }
    __syncthreads();

    if (tid < 256) {
        int s = tid >> 4, m = tid & 15;
        float gamma = sScal[s * 4 + 2] / sScal[s * 4 + 0];
        float r = 0.f;
        #pragma unroll 4
        for (int k = 0; k < 64; ++k) {
            float wvv = sq[s * 64 + k] - gamma * sBdE[s * 64 + k];
            r = fmaf(sC[s * 1089 + k * 17 + m], wvv, r);
        }
        sr[s * 16 + m] = r;
    }
    __syncthreads();
    {
        int s = tid >> 6, k = tid & 63;
        float o = 0.f;
        #pragma unroll
        for (int m2 = 0; m2 < 16; ++m2)
            o = fmaf(sC[s * 1089 + k * 17 + m2], sr[s * 16 + m2], o);
        int gi = sbase * 64 + tid;
        dout[gi] = dout[gi] + o;
    }
}

extern "C" void kernel_launch(void* const* d_in, const int* in_sizes, int n_in,
                              void* d_out, int out_size, void* d_ws, size_t ws_size,
                              hipStream_t stream)
{
    (void)in_sizes; (void)n_in; (void)out_size;
    const float* y = (const float*)d_in[1];
    const float* W0[5]; const float* b0[5]; const float* W1[5]; const float* b1[5]; const float* W2[5];
    for (int m = 0; m < 5; ++m) {
        int base = 2 + m * 5;
        W0[m] = (const float*)d_in[base + 0];
        b0[m] = (const float*)d_in[base + 1];
        W1[m] = (const float*)d_in[base + 2];
        b1[m] = (const float*)d_in[base + 3];
        W2[m] = (const float*)d_in[base + 4];
    }
    float* ws = (float*)d_ws;
    float* dout = (float*)d_out;
    if (ws_size < (size_t)WS5_FLOATS * sizeof(float)) return;  // WS5 proven available (R15)
    const bool big4 = ws_size >= (size_t)WS6_FLOATS * sizeof(float);

    int ntr = 2236416 + NPACK + NPACKC + NPACKP + NK1 + NK3F;
    if (big4) ntr += NK2F;
    hipLaunchKernelGGL(k_transpose_all, dim3((ntr + 1023) / 1024), dim3(1024), 0, stream,
                       ws, 1,
                       W0[0], W0[1], W0[2], W0[3], W0[4],
                       W1[0], W1[1], W1[2], W1[3], W1[4],
                       W2[2], W2[3], W2[4]);

    hipLaunchKernelGGL(k1_grads_mf, dim3(1024), dim3(1024), 0, stream,
                       y, ws,
                       b0[0], b1[0], W2[0], b0[1], b1[1], W2[1],
                       ws + OFF_DE, ws + OFF_DS);

    const int k2_smem = 154112;
    const int k3_smem = 132416;
    if (big4) {
        hipFuncSetAttribute((const void*)k2_poisson_mf2, hipFuncAttributeMaxDynamicSharedMemorySize, k2_smem);
        hipLaunchKernelGGL(k2_poisson_mf2, dim3(1024), dim3(1024), k2_smem, stream,
                           y, ws, b0[2], b1[2], dout);
    } else {
        hipFuncSetAttribute((const void*)k2_poisson_mf, hipFuncAttributeMaxDynamicSharedMemorySize, k2_smem);
        hipLaunchKernelGGL(k2_poisson_mf, dim3(1024), dim3(1024), k2_smem, stream,
                           y, ws, b0[2], b1[2], dout);
    }

    hipFuncSetAttribute((const void*)k3_friction_mf3, hipFuncAttributeMaxDynamicSharedMemorySize, k3_smem);
    hipLaunchKernelGGL(k3_friction_mf3, dim3(1024), dim3(1024), k3_smem, stream,
                       y, ws, b0[3], b1[3], b0[4], b1[4], dout);
}